// Round 12
// baseline (10155.333 us; speedup 1.0000x reference)
//
#include <hip/hip_runtime.h>
#include <math.h>

#define B_ 32
#define T_ 256
#define N_ 256
#define L_ 64
#define R_ 16
#define H_ 256
#define NS_ 8
#define SEG 32
#define NSEG 8
#define ST 65    // stride for scalar LDS matrices (conflict-free b32)
#define STM 67   // stride for gains solve matrix with 2 extra RHS columns
#define STF 68   // fp32 stride (16B-aligned float4 rows)
#define SBF 72   // bf16 stride (144B rows)
#define SU 20    // stride filter U/K fp32
#define SU2 21   // stride for fcompose 64x16 arrays
#define PKN 2080
#define PIDX(i,j) ((((i)*((i)+1))>>1) + (j))

using f32x4  = __attribute__((ext_vector_type(4))) float;
using bf16x8 = __attribute__((ext_vector_type(8))) short;
using s16x4  = __attribute__((ext_vector_type(4))) short;

__device__ __forceinline__ float softplus_f(float x) { return log1pf(expf(x)); }

__device__ __forceinline__ void splitbf(float x, short& h, short& l)
{
  unsigned u = __float_as_uint(x);
  unsigned hu = (u + 0x7FFFu + ((u>>16)&1u)) & 0xFFFF0000u;
  float hf = __uint_as_float(hu);
  float r = x - hf;
  unsigned ur = __float_as_uint(r);
  unsigned lu = (ur + 0x7FFFu + ((ur>>16)&1u)) >> 16;
  h = (short)(hu>>16); l = (short)lu;
}
__device__ __forceinline__ void splitbf4(const float4& v, s16x4& h4, s16x4& l4)
{
  short h, l;
  splitbf(v.x, h, l); h4[0] = h; l4[0] = l;
  splitbf(v.y, h, l); h4[1] = h; l4[1] = l;
  splitbf(v.z, h, l); h4[2] = h; l4[2] = l;
  splitbf(v.w, h, l); h4[3] = h; l4[3] = l;
}
__device__ __forceinline__ float bf2f(short s)
{ return __uint_as_float(((unsigned)(unsigned short)s)<<16); }

template<int SB>
__device__ __forceinline__ void mfma_mm64(const short* Ah, const short* Al,
                                          const short* Bh, const short* Bl,
                                          int w, int l, f32x4 acc[4])
{
  const int lr = l & 15, lg = l >> 4;
  const int arow = (w*16+lr)*SB;
#pragma unroll
  for (int ks = 0; ks < 2; ++ks) {
    const int ko = ks*32 + lg*8;
    bf16x8 ah = *(const bf16x8*)&Ah[arow + ko];
    bf16x8 al = *(const bf16x8*)&Al[arow + ko];
#pragma unroll
    for (int ct = 0; ct < 4; ++ct) {
      bf16x8 bh = *(const bf16x8*)&Bh[(ct*16+lr)*SB + ko];
      bf16x8 bl = *(const bf16x8*)&Bl[(ct*16+lr)*SB + ko];
      acc[ct] = __builtin_amdgcn_mfma_f32_16x16x32_bf16(ah, bh, acc[ct], 0,0,0);
      acc[ct] = __builtin_amdgcn_mfma_f32_16x16x32_bf16(ah, bl, acc[ct], 0,0,0);
      acc[ct] = __builtin_amdgcn_mfma_f32_16x16x32_bf16(al, bh, acc[ct], 0,0,0);
    }
  }
}

// C = A@B (TB: A@B^T), 64x64 scalar, 256 threads.
template<int LDA, int LDB, int LDC, bool TB>
__device__ __forceinline__ void mm64f(const float* A, const float* Bm, float* C, int tid)
{
  const int rg = tid >> 4, cg = tid & 15;
  float acc[4][4] = {{0.f}};
#pragma unroll 2
  for (int k = 0; k < 64; ++k) {
    float a[4], bb[4];
#pragma unroll
    for (int i = 0; i < 4; ++i) a[i] = A[(rg*4+i)*LDA + k];
#pragma unroll
    for (int j = 0; j < 4; ++j) bb[j] = TB ? Bm[(cg*4+j)*LDB + k] : Bm[k*LDB + (cg*4+j)];
#pragma unroll
    for (int i = 0; i < 4; ++i)
#pragma unroll
      for (int j = 0; j < 4; ++j) acc[i][j] += a[i]*bb[j];
  }
#pragma unroll
  for (int i = 0; i < 4; ++i)
#pragma unroll
    for (int j = 0; j < 4; ++j) C[(rg*4+i)*LDC + (cg*4+j)] = acc[i][j];
}

template<int SA>
__device__ __forceinline__ void chol64_blk(float* A, float* rdiag, float* dg, int tid)
{
#pragma unroll
  for (int kb = 0; kb < 4; ++kb) {
    const int o = kb*16;
    if (tid < 16) {
      const int ln = tid;
      float s[16];
#pragma unroll
      for (int j = 0; j < 16; ++j) s[j] = A[(o+ln)*SA + o + j];
#pragma unroll
      for (int k = 0; k < 16; ++k) {
        const float dk = fmaxf(__shfl(s[k], k, 64), 1e-30f);
        const float d = sqrtf(dk);
        const float rd = 1.f/d;
        const float lik = s[k]*rd;
        if (ln == k) { rdiag[o+k] = rd; if (dg) dg[o+k] = d; }
#pragma unroll
        for (int j = 0; j < 16; ++j) {
          const float ljk = __shfl(lik, j, 64);
          if (j > k && j <= ln) s[j] -= lik*ljk;
        }
        if (ln > k) s[k] = lik;
        else if (ln == k) s[k] = dk;
      }
#pragma unroll
      for (int j = 0; j < 16; ++j) A[(o+ln)*SA + o + j] = s[j];
    }
    __syncthreads();
    const int nr = 48 - o;
    if (nr > 0) {
      if (tid < nr) {
        const int r = o + 16 + tid;
        float x[16];
#pragma unroll
        for (int q = 0; q < 16; ++q) x[q] = A[r*SA + o + q];
#pragma unroll
        for (int j = 0; j < 16; ++j) {
          x[j] *= rdiag[o+j];
#pragma unroll
          for (int i2 = j+1; i2 < 16; ++i2) x[i2] -= A[(o+i2)*SA + o + j] * x[j];
        }
#pragma unroll
        for (int q = 0; q < 16; ++q) A[r*SA + o + q] = x[q];
      }
      __syncthreads();
      const int tot = nr*nr;
      for (int idx = tid; idx < tot; idx += 256) {
        const int i = o + 16 + idx / nr, j = o + 16 + idx % nr;
        float acc = A[i*SA + j];
#pragma unroll
        for (int k = 0; k < 16; ++k) acc -= A[i*SA + o + k] * A[j*SA + o + k];
        A[i*SA + j] = acc;
      }
      __syncthreads();
    }
  }
}

__device__ __forceinline__ void fwd16(float* x, const float* sS, const float* sSd)
{
#pragma unroll
  for (int a = 0; a < 16; ++a) {
    x[a] *= sSd[a];
#pragma unroll
    for (int i = a+1; i < 16; ++i) x[i] -= sS[i*17+a]*x[a];
  }
}
__device__ __forceinline__ void solve16(float* x, const float* sS, const float* sSd)
{
#pragma unroll
  for (int a = 0; a < 16; ++a) {
    x[a] *= sSd[a];
#pragma unroll
    for (int i = a+1; i < 16; ++i) x[i] -= sS[i*17+a]*x[a];
  }
#pragma unroll
  for (int a = 15; a >= 0; --a) {
    x[a] *= sSd[a];
#pragma unroll
    for (int i = 0; i < a; ++i) x[i] -= sS[a*17+i]*x[a];
  }
}
__device__ __forceinline__ void chol16_sh(float* sS, float* sSd, int tid)
{
  if (tid < 16) {
    const int ln = tid;
    float s[16];
#pragma unroll
    for (int j = 0; j < 16; ++j) s[j] = sS[ln*17+j];
#pragma unroll
    for (int k = 0; k < 16; ++k) {
      const float dk = fmaxf(__shfl(s[k], k, 64), 1e-30f);
      const float d = sqrtf(dk);
      const float rd = 1.f/d;
      const float lik = s[k]*rd;
      if (ln == k) sSd[k] = rd;
#pragma unroll
      for (int j = 0; j < 16; ++j) {
        const float ljk = __shfl(lik, j, 64);
        if (j > k && j <= ln) s[j] -= lik*ljk;
      }
      if (ln > k) s[k] = lik;
      else if (ln == k) s[k] = d;
    }
#pragma unroll
    for (int j = 0; j < 16; ++j) sS[ln*17+j] = s[j];
  }
}

// ---------------- K1: tiled fp32 GEMM ----------------
template<bool TANH, bool SPLIT>
__global__ __launch_bounds__(256) void gemm_kernel(
    const float* __restrict__ A, const float* __restrict__ Bw,
    const float* __restrict__ bias, float* __restrict__ C1,
    float* __restrict__ C2, int M, int Nn, int Kk)
{
  __shared__ float As[16][65];
  __shared__ float Bs[16][64];
  const int bm = blockIdx.y * 64, bn = blockIdx.x * 64;
  const int tid = threadIdx.x;
  const int rg = tid >> 4, cg = tid & 15;
  float acc[4][4] = {{0.f}};
  for (int k0 = 0; k0 < Kk; k0 += 16) {
    {
      const int kk = tid & 15, r0 = tid >> 4;
#pragma unroll
      for (int rr = 0; rr < 4; ++rr)
        As[kk][r0 + 16*rr] = A[(size_t)(bm + r0 + 16*rr) * Kk + k0 + kk];
    }
    {
      const int cc = tid & 63, kk = tid >> 6;
#pragma unroll
      for (int kr = 0; kr < 4; ++kr)
        Bs[kk + 4*kr][cc] = Bw[(size_t)(k0 + kk + 4*kr) * Nn + bn + cc];
    }
    __syncthreads();
#pragma unroll
    for (int k = 0; k < 16; ++k) {
      float a[4], bb[4];
#pragma unroll
      for (int i = 0; i < 4; ++i) a[i] = As[k][rg*4+i];
#pragma unroll
      for (int j = 0; j < 4; ++j) bb[j] = Bs[k][cg*4+j];
#pragma unroll
      for (int i = 0; i < 4; ++i)
#pragma unroll
        for (int j = 0; j < 4; ++j) acc[i][j] += a[i]*bb[j];
    }
    __syncthreads();
  }
#pragma unroll
  for (int i = 0; i < 4; ++i) {
    const int row = bm + rg*4 + i;
#pragma unroll
    for (int j = 0; j < 4; ++j) {
      const int col = bn + cg*4 + j;
      float v = acc[i][j] + bias[col];
      if (TANH) v = tanhf(v);
      if (SPLIT) {
        if (col < 64) C1[(size_t)row*64 + col] = v;
        else          C2[(size_t)row*1024 + (col-64)] = v;
      } else {
        C1[(size_t)row*Nn + col] = v;
      }
    }
  }
}

// ---------------- K2: Kalman filter (round-8 proven sequential MFMA) ----------------
__global__ __launch_bounds__(256, 1) void filter_kernel(
    const float* __restrict__ kyg, const float* __restrict__ Kxg,
    const float* __restrict__ Fg, const float* __restrict__ logQ,
    const float* __restrict__ logQ0, const float* __restrict__ m0g,
    float* __restrict__ mf_g, float* __restrict__ mp_g,
    float* __restrict__ Pf_g, float* __restrict__ dpart_g,
    float* __restrict__ mfT_g)
{
  __shared__ float sB[64*STF];
  __shared__ __align__(16) char sPool[18432];
  __shared__ short sFh[64*SBF], sFl[64*SBF];
  __shared__ float sS[16*17], sSd[16];
  __shared__ float sQ[64], sQ0[64], skv[64], smf[64], smp[64], sv[16], sw[16];
  __shared__ float sldv;
  __shared__ f32x4 sRed4[256];
  float* sRed = (float*)sRed4;
  short* sXh = (short*)sPool;
  short* sXl = (short*)(sPool + 9216);
  float* sU  = (float*)sPool;
  float* sK  = (float*)(sPool + 5120);

  const int b = blockIdx.x, tid = threadIdx.x;
  const int w = tid >> 6, l = tid & 63;

#pragma unroll
  for (int q = 0; q < 4; ++q) {
    const int idx = q*1024 + tid*4;
    const int row = idx>>6, col = idx&63;
    float4 v = *(const float4*)&Fg[idx];
    s16x4 h4, l4;
    splitbf4(v, h4, l4);
    *(s16x4*)&sFh[row*SBF+col] = h4;
    *(s16x4*)&sFl[row*SBF+col] = l4;
  }
  if (tid < 64) {
    sQ[tid]  = softplus_f(logQ[tid]);
    sQ0[tid] = softplus_f(logQ0[tid]);
    smf[tid] = m0g[tid];
  }
  __syncthreads();

  for (int t = 0; t < T_; ++t) {
    const size_t bt = (size_t)b*T_ + t;
    if (t == 0) {
      for (int i = tid; i < 4096; i += 256) {
        const int r = i>>6, c = i&63;
        sB[r*STF+c] = (r==c) ? sQ0[r] : 0.f;
      }
      const float4 kreg = ((const float4*)(Kxg + bt*1024))[tid];
      *(float4*)&sK[(tid>>2)*SU + (tid&3)*4] = kreg;
      if (tid < 64) { smp[tid] = smf[tid]; skv[tid] = kyg[bt*64 + tid]; mp_g[bt*64+tid] = smp[tid]; }
      __syncthreads();
    } else {
#pragma unroll
      for (int q = 0; q < 4; ++q) {
        const int idx = q*1024 + tid*4;
        const int row = idx>>6, col = idx&63;
        float4 v = *(const float4*)&sB[row*STF+col];
        s16x4 h4, l4;
        splitbf4(v, h4, l4);
        *(s16x4*)&sXh[row*SBF+col] = h4;
        *(s16x4*)&sXl[row*SBF+col] = l4;
      }
      __syncthreads();
      const float4 kreg = ((const float4*)(Kxg + bt*1024))[tid];
      float kvreg = 0.f;
      if (tid < 64) kvreg = kyg[bt*64 + tid];
      f32x4 acc[4];
#pragma unroll
      for (int ct = 0; ct < 4; ++ct) acc[ct] = (f32x4){0.f,0.f,0.f,0.f};
      mfma_mm64<SBF>(sFh, sFl, sXh, sXl, w, l, acc);
      {
        const int i = tid & 63, jb = tid >> 6;
        float s = 0.f;
#pragma unroll
        for (int hq = 0; hq < 2; ++hq) {
          bf16x8 fh = *(const bf16x8*)&sFh[i*SBF + jb*16 + hq*8];
          bf16x8 fl = *(const bf16x8*)&sFl[i*SBF + jb*16 + hq*8];
#pragma unroll
          for (int j = 0; j < 8; ++j)
            s += (bf2f(fh[j]) + bf2f(fl[j])) * smf[jb*16 + hq*8 + j];
        }
        sRed[tid] = s;
      }
      __syncthreads();
      {
        const int lr = l & 15, lg = l >> 4;
#pragma unroll
        for (int ct = 0; ct < 4; ++ct)
#pragma unroll
          for (int r = 0; r < 4; ++r) {
            short hh, ll;
            splitbf(acc[ct][r], hh, ll);
            const int row = w*16 + lg*4 + r, col = ct*16 + lr;
            sXh[row*SBF+col] = hh; sXl[row*SBF+col] = ll;
          }
      }
      if (tid < 64) {
        const float mpv = sRed[tid] + sRed[tid+64] + sRed[tid+128] + sRed[tid+192];
        smp[tid] = mpv; mp_g[bt*64+tid] = mpv;
      }
      __syncthreads();
#pragma unroll
      for (int ct = 0; ct < 4; ++ct) acc[ct] = (f32x4){0.f,0.f,0.f,0.f};
      mfma_mm64<SBF>(sXh, sXl, sFh, sFl, w, l, acc);
      __syncthreads();
      {
        const int lr = l & 15, lg = l >> 4;
#pragma unroll
        for (int ct = 0; ct < 4; ++ct)
#pragma unroll
          for (int r = 0; r < 4; ++r) {
            const int row = w*16 + lg*4 + r, col = ct*16 + lr;
            sB[row*STF+col] = acc[ct][r] + ((row==col) ? sQ[row] : 0.f);
          }
      }
      *(float4*)&sK[(tid>>2)*SU + (tid&3)*4] = kreg;
      if (tid < 64) skv[tid] = kvreg;
      __syncthreads();
    }
    {
      const int i = tid & 63, rq = tid >> 6;
      float4 u = {0.f,0.f,0.f,0.f};
      for (int jb = 0; jb < 16; ++jb) {
        const float4 p4 = *(const float4*)&sB[i*STF + jb*4];
#pragma unroll
        for (int dj = 0; dj < 4; ++dj) {
          const float4 k4 = *(const float4*)&sK[(jb*4+dj)*SU + rq*4];
          const float pv = (dj==0) ? p4.x : (dj==1) ? p4.y : (dj==2) ? p4.z : p4.w;
          u.x += pv*k4.x; u.y += pv*k4.y; u.z += pv*k4.z; u.w += pv*k4.w;
        }
      }
      *(float4*)&sU[i*SU + rq*4] = u;
    }
    __syncthreads();
    {
      const int ib = tid >> 6, r1 = (tid >> 2) & 15, r2b = tid & 3;
      float4 part = {0.f,0.f,0.f,0.f};
      for (int ii = 0; ii < 16; ++ii) {
        const int i = ib*16 + ii;
        const float kv = sK[i*SU + r1];
        const float4 u4 = *(const float4*)&sU[i*SU + r2b*4];
        part.x += kv*u4.x; part.y += kv*u4.y; part.z += kv*u4.z; part.w += kv*u4.w;
      }
      sRed4[tid] = (f32x4){part.x, part.y, part.z, part.w};
    }
    __syncthreads();
    if (tid < 64) {
      const int r1 = tid >> 2, r2b = tid & 3;
      f32x4 s4 = sRed4[tid];
      s4 += sRed4[tid+64]; s4 += sRed4[tid+128]; s4 += sRed4[tid+192];
#pragma unroll
      for (int dj = 0; dj < 4; ++dj)
        sS[r1*17 + r2b*4 + dj] = s4[dj] + ((r1 == r2b*4+dj) ? 1.f : 0.f);
    }
    __syncthreads();
    if (tid < 16) {
      const int ln = tid;
      float s[16];
#pragma unroll
      for (int j = 0; j < 16; ++j) s[j] = sS[ln*17+j];
      float pd = 1.f;
#pragma unroll
      for (int k = 0; k < 16; ++k) {
        const float dk = fmaxf(__shfl(s[k], k, 64), 1e-30f);
        const float d = sqrtf(dk);
        const float rd = 1.f/d;
        pd *= dk;
        const float lik = s[k]*rd;
        if (ln == k) sSd[k] = rd;
#pragma unroll
        for (int j = 0; j < 16; ++j) {
          const float ljk = __shfl(lik, j, 64);
          if (j > k && j <= ln) s[j] -= lik*ljk;
        }
        if (ln > k) s[k] = lik;
        else if (ln == k) s[k] = d;
      }
#pragma unroll
      for (int j = 0; j < 16; ++j) sS[ln*17+j] = s[j];
      if (ln == 0) sldv = logf(pd);
    } else if (tid >= 64 && tid < 80) {
      const int r = tid - 64;
      float a = 0.f;
      for (int i = 0; i < 64; ++i) a += sK[i*SU+r] * smp[i];
      sv[r] = a;
    }
    __syncthreads();
    if (tid < 64) {
      float x[16];
#pragma unroll
      for (int q = 0; q < 4; ++q) {
        const float4 u4 = *(const float4*)&sU[tid*SU + q*4];
        x[q*4+0]=u4.x; x[q*4+1]=u4.y; x[q*4+2]=u4.z; x[q*4+3]=u4.w;
      }
      fwd16(x, sS, sSd);
#pragma unroll
      for (int q = 0; q < 4; ++q) {
        float4 u4 = {x[q*4+0], x[q*4+1], x[q*4+2], x[q*4+3]};
        *(float4*)&sU[tid*SU + q*4] = u4;
      }
    } else if (tid == 64) {
      float x[16];
#pragma unroll
      for (int r = 0; r < 16; ++r) x[r] = sv[r];
      fwd16(x, sS, sSd);
#pragma unroll
      for (int r = 0; r < 16; ++r) sw[r] = x[r];
    }
    __syncthreads();
    {
      const int rg = tid >> 4, cg = tid & 15;
      float acc2[4][4] = {{0.f}};
#pragma unroll
      for (int rb = 0; rb < 4; ++rb) {
        float4 a4[4], b4[4];
#pragma unroll
        for (int i = 0; i < 4; ++i) a4[i] = *(const float4*)&sU[(rg*4+i)*SU + rb*4];
#pragma unroll
        for (int jj = 0; jj < 4; ++jj) b4[jj] = *(const float4*)&sU[(cg+16*jj)*SU + rb*4];
#pragma unroll
        for (int i = 0; i < 4; ++i)
#pragma unroll
          for (int jj = 0; jj < 4; ++jj)
            acc2[i][jj] += a4[i].x*b4[jj].x + a4[i].y*b4[jj].y
                         + a4[i].z*b4[jj].z + a4[i].w*b4[jj].w;
      }
#pragma unroll
      for (int i = 0; i < 4; ++i)
#pragma unroll
        for (int jj = 0; jj < 4; ++jj) {
          const int r = rg*4+i, c = cg+16*jj;
          sB[r*STF+c] -= acc2[i][jj];
        }
    }
    __syncthreads();
    {
      const int i = tid & 63, jb = tid >> 6;
      float s = 0.f;
#pragma unroll
      for (int q = 0; q < 4; ++q) {
        const float4 p4 = *(const float4*)&sB[i*STF + jb*16 + q*4];
        s += p4.x*skv[jb*16+q*4+0] + p4.y*skv[jb*16+q*4+1]
           + p4.z*skv[jb*16+q*4+2] + p4.w*skv[jb*16+q*4+3];
      }
      sRed[tid] = s;
    }
    for (int i2 = tid; i2 < 4096; i2 += 256)
      Pf_g[bt*4096+i2] = sB[(i2>>6)*STF+(i2&63)];
    __syncthreads();
    if (tid < 64) {
      float a = smp[tid];
#pragma unroll
      for (int q = 0; q < 4; ++q) {
        const float4 u4 = *(const float4*)&sU[tid*SU + q*4];
        a -= u4.x*sw[q*4+0] + u4.y*sw[q*4+1] + u4.z*sw[q*4+2] + u4.w*sw[q*4+3];
      }
      a += sRed[tid] + sRed[tid+64] + sRed[tid+128] + sRed[tid+192];
      smf[tid] = a;
      mf_g[bt*64+tid] = a;
      if (t == T_-1) mfT_g[b*64+tid] = a;
    }
    __syncthreads();
    if (tid < 16) {
      float a = 0.f;
      for (int i = 0; i < 64; ++i) a += sK[i*SU+tid]*smf[i];
      float aa = a*a;
      aa += __shfl_xor(aa, 1, 64);
      aa += __shfl_xor(aa, 2, 64);
      aa += __shfl_xor(aa, 4, 64);
      aa += __shfl_xor(aa, 8, 64);
      if (tid == 0) {
        float dp = aa - sldv;
        if (t == 0) {
          float d1 = 0.f, d2 = 0.f;
          for (int i = 0; i < 64; ++i) {
            d1 += smf[i]*smf[i]/sQ0[i];
            d2 += smp[i]*smp[i]/sQ0[i];
          }
          dp = 0.5f*(d1 - d2 + dp);
        }
        dpart_g[bt] = dp;
      }
    }
    __syncthreads();
  }
}

// ============ Parallel-filter scan (DIAGNOSTIC ONLY this round) ============
#define FC_LDS 132096
__global__ __launch_bounds__(256, 1) void fcompose_kernel(
    const float* __restrict__ kyg, const float* __restrict__ Kxg,
    const float* __restrict__ Fg, const float* __restrict__ logQ,
    const float* __restrict__ logQ0, const float* __restrict__ m0g,
    float* __restrict__ Aseg, float* __restrict__ Cseg, float* __restrict__ Jseg,
    float* __restrict__ bseg, float* __restrict__ etaseg,
    float* __restrict__ BPm, float* __restrict__ BPC)
{
  const int blk = blockIdx.x, tid = threadIdx.x;
  const int b = blk >> 3, s = blk & 7;
  if (s == 7) return;

  extern __shared__ __align__(16) char fcm[];
  float* F_  = (float*)fcm;
  float* mA  = F_  + 64*ST;
  float* mC  = mA  + 64*ST;
  float* mJ  = mC  + 64*ST;
  float* mT  = mJ  + 64*ST;
  float* sKf = mT  + 64*ST;
  float* sW  = sKf + 64*SU2;
  float* sP  = sW  + 64*SU2;
  float* sTb = sP  + 64*SU2;
  float* sK2 = sTb + 64*SU2;
  float* sR  = sK2 + 64*SU2;
  float* sZW = sR  + 64*SU2;
  float* sG  = sZW + 64*SU2;
  float* sS2 = sG  + 16*68;
  float* sS3 = sS2 + 16*17;
  float* sSd2= sS3 + 16*17;
  float* sSd3= sSd2 + 16;
  float* vq  = sSd3 + 16;
  float* vb  = vq  + 64;
  float* veta= vb  + 64;
  float* vk  = veta+ 64;
  float* vz1 = vk  + 64;
  float* vt1 = vz1 + 64;
  float* vt2 = vt1 + 64;
  float* vu  = vt2 + 64;
  float* vg  = vu  + 64;
  float* vhg = vg  + 64;
  float* vmu = vhg + 64;
  float* vg2 = vmu + 64;
  float* vet3= vg2 + 64;
  float* vb2 = vet3+ 64;
  float* vmp = vb2 + 64;
  float* v16 = vmp + 64;

  for (int i = tid; i < 4096; i += 256) F_[(i>>6)*ST + (i&63)] = Fg[i];
  if (tid < 64) vq[tid] = softplus_f(logQ[tid]);
  __syncthreads();

#define STAGE_K(bt)                                                        \
  { float4 k4 = ((const float4*)(Kxg + (bt)*1024))[tid];                   \
    const int row = tid>>2, c0 = (tid&3)*4;                                \
    sKf[row*SU2+c0+0]=k4.x; sKf[row*SU2+c0+1]=k4.y;                        \
    sKf[row*SU2+c0+2]=k4.z; sKf[row*SU2+c0+3]=k4.w;                        \
    if (tid < 64) { vk[tid] = kyg[(bt)*64+tid]; vz1[tid]=vq[tid]*vk[tid]; } }

  if (s == 0) {
    if (tid < 64) { vmp[tid] = m0g[tid]; vt1[tid] = softplus_f(logQ0[tid]); }
    __syncthreads();
    for (int t = 0; t < SEG; ++t) {
      const size_t bt = (size_t)b*T_ + t;
      if (t == 0) {
        for (int i = tid; i < 4096; i += 256) {
          const int r = i>>6, c = i&63;
          mC[r*ST+c] = (r==c) ? vt1[r] : 0.f;
        }
      } else {
        mm64f<ST,ST,ST,false>(F_, mC, mT, tid);
        __syncthreads();
        mm64f<ST,ST,ST,true>(mT, F_, mC, tid);
        if (tid < 64) {
          float a = 0.f;
          for (int j = 0; j < 64; ++j) a += F_[tid*ST+j]*vb[j];
          vmp[tid] = a;
        }
        __syncthreads();
        if (tid < 64) mC[tid*ST+tid] += vq[tid];
      }
      STAGE_K(bt);
      __syncthreads();
      { const int i6 = tid & 63, rq = tid >> 6;
        float u[4] = {0,0,0,0};
        for (int j = 0; j < 64; ++j) {
          const float p = mC[i6*ST+j];
#pragma unroll
          for (int r = 0; r < 4; ++r) u[r] += p*sKf[j*SU2+rq*4+r];
        }
#pragma unroll
        for (int r = 0; r < 4; ++r) sP[i6*SU2+rq*4+r] = u[r];
      }
      __syncthreads();
      { const int a = tid>>4, c = tid&15;
        float sv = (a==c) ? 1.f : 0.f;
        for (int i = 0; i < 64; ++i) sv += sKf[i*SU2+a]*sP[i*SU2+c];
        sS2[a*17+c] = sv;
      }
      __syncthreads();
      chol16_sh(sS2, sSd2, tid);
      if (tid >= 64 && tid < 80) {
        const int r = tid-64;
        float a = 0.f;
        for (int i = 0; i < 64; ++i) a += sKf[i*SU2+r]*vmp[i];
        v16[r] = a;
      }
      __syncthreads();
      if (tid < 64) {
        float x[16];
#pragma unroll
        for (int r = 0; r < 16; ++r) x[r] = sP[tid*SU2+r];
        fwd16(x, sS2, sSd2);
#pragma unroll
        for (int r = 0; r < 16; ++r) sTb[tid*SU2+r] = x[r];
      } else if (tid == 64) {
        float x[16];
#pragma unroll
        for (int r = 0; r < 16; ++r) x[r] = v16[r];
        fwd16(x, sS2, sSd2);
#pragma unroll
        for (int r = 0; r < 16; ++r) v16[r] = x[r];
      }
      __syncthreads();
      for (int idx = tid; idx < 4096; idx += 256) {
        const int i = idx>>6, j = idx&63;
        float a = mC[i*ST+j];
#pragma unroll
        for (int r = 0; r < 16; ++r) a -= sTb[i*SU2+r]*sTb[j*SU2+r];
        mC[i*ST+j] = a;
      }
      __syncthreads();
      if (tid < 64) {
        float a = vmp[tid];
#pragma unroll
        for (int r = 0; r < 16; ++r) a -= sTb[tid*SU2+r]*v16[r];
        for (int j = 0; j < 64; ++j) a += mC[tid*ST+j]*vk[j];
        vb[tid] = a;
      }
      __syncthreads();
    }
    if (tid < 64) BPm[((size_t)b*NSEG + 1)*64 + tid] = vb[tid];
    for (int i = tid; i < 4096; i += 256)
      BPC[((size_t)b*NSEG + 1)*4096 + i] = mC[(i>>6)*ST + (i&63)];
    return;
  }

  const int t0 = s*SEG;
  {
    const size_t bt = (size_t)b*T_ + t0;
    STAGE_K(bt);
    __syncthreads();
    { const int a = tid>>4, c = tid&15;
      float sv = (a==c) ? 1.f : 0.f;
      for (int j = 0; j < 64; ++j) sv += sKf[j*SU2+a]*vq[j]*sKf[j*SU2+c];
      sS2[a*17+c] = sv;
    }
    { const int i6 = tid & 63, rq = tid >> 6;
      float u[4] = {0,0,0,0};
      for (int j = 0; j < 64; ++j) {
        const float fv = F_[j*ST+i6];
#pragma unroll
        for (int r = 0; r < 4; ++r) u[r] += fv*sKf[j*SU2+rq*4+r];
      }
#pragma unroll
      for (int r = 0; r < 4; ++r) sW[i6*SU2+rq*4+r] = u[r];
    }
    __syncthreads();
    chol16_sh(sS2, sSd2, tid);
    __syncthreads();
    if (tid < 64) {
      float x[16];
#pragma unroll
      for (int r = 0; r < 16; ++r) x[r] = vq[tid]*sKf[tid*SU2+r];
      fwd16(x, sS2, sSd2);
#pragma unroll
      for (int r = 0; r < 16; ++r) sK2[tid*SU2+r] = x[r];
    } else if (tid < 128) {
      const int i = tid-64;
      float x[16];
#pragma unroll
      for (int r = 0; r < 16; ++r) x[r] = sW[i*SU2+r];
      fwd16(x, sS2, sSd2);
#pragma unroll
      for (int r = 0; r < 16; ++r) sR[i*SU2+r] = x[r];
    } else if (tid < 192) {
      const int i = tid-128;
      float x[16];
#pragma unroll
      for (int r = 0; r < 16; ++r) x[r] = sW[i*SU2+r];
      solve16(x, sS2, sSd2);
#pragma unroll
      for (int r = 0; r < 16; ++r) sTb[i*SU2+r] = x[r];
    } else if (tid < 208) {
      const int r = tid-192;
      float a = 0.f;
      for (int i = 0; i < 64; ++i) a += sKf[i*SU2+r]*vz1[i];
      v16[r] = a;
    }
    __syncthreads();
    for (int idx = tid; idx < 4096; idx += 256) {
      const int i = idx>>6, j = idx&63;
      float a1 = F_[i*ST+j];
      float a2 = (i==j) ? vq[i] : 0.f;
      float a3 = 0.f;
#pragma unroll
      for (int r = 0; r < 16; ++r) {
        a1 -= vq[i]*sKf[i*SU2+r]*sTb[j*SU2+r];
        a2 -= sK2[i*SU2+r]*sK2[j*SU2+r];
        a3 += sR[i*SU2+r]*sR[j*SU2+r];
      }
      mA[i*ST+j] = a1; mC[i*ST+j] = a2; mJ[i*ST+j] = a3;
    }
    if (tid == 0) {
      float x[16];
#pragma unroll
      for (int r = 0; r < 16; ++r) x[r] = v16[r];
      solve16(x, sS2, sSd2);
#pragma unroll
      for (int r = 0; r < 16; ++r) v16[r] = x[r];
    }
    __syncthreads();
    if (tid >= 64 && tid < 80) {
      const int r = tid-64;
      float a = 0.f;
      for (int i = 0; i < 64; ++i) a += sK2[i*SU2+r]*vk[i];
      v16[16+r] = a;
    }
    if (tid < 64) {
      float t = vk[tid];
#pragma unroll
      for (int r = 0; r < 16; ++r) t -= sKf[tid*SU2+r]*v16[r];
      vt1[tid] = t;
    }
    __syncthreads();
    if (tid < 64) {
      float e = 0.f;
      for (int i = 0; i < 64; ++i) e += F_[i*ST+tid]*vt1[i];
      veta[tid] = e;
      float bb = vz1[tid];
#pragma unroll
      for (int r = 0; r < 16; ++r) bb -= sK2[tid*SU2+r]*v16[16+r];
      vb[tid] = bb;
    }
    __syncthreads();
  }

  for (int tt = t0+1; tt < t0+SEG; ++tt) {
    const size_t bt = (size_t)b*T_ + tt;
    STAGE_K(bt);
    __syncthreads();
    { const int a = tid>>4, c = tid&15;
      float sv = (a==c) ? 1.f : 0.f;
      for (int j = 0; j < 64; ++j) sv += sKf[j*SU2+a]*vq[j]*sKf[j*SU2+c];
      sS2[a*17+c] = sv; sS3[a*17+c] = sv;
    }
    __syncthreads();
    { const int i6 = tid & 63, rq = tid >> 6;
      float u[4] = {0,0,0,0};
      for (int j = 0; j < 64; ++j) {
        const float fv = F_[j*ST+i6];
#pragma unroll
        for (int r = 0; r < 4; ++r) u[r] += fv*sKf[j*SU2+rq*4+r];
      }
#pragma unroll
      for (int r = 0; r < 4; ++r) sW[i6*SU2+rq*4+r] = u[r];
    }
    __syncthreads();
    chol16_sh(sS2, sSd2, tid);
    if (tid >= 64 && tid < 80) {
      const int r = tid-64;
      float a = 0.f;
      for (int i = 0; i < 64; ++i) a += sKf[i*SU2+r]*vz1[i];
      v16[r] = a;
    } else if (tid >= 80 && tid < 96) {
      const int r = tid-80;
      float a = 0.f;
      for (int i = 0; i < 64; ++i) a += sW[i*SU2+r]*vb[i];
      v16[16+r] = a;
    }
    __syncthreads();
    if (tid < 64) {
      float x[16];
#pragma unroll
      for (int r = 0; r < 16; ++r) x[r] = vq[tid]*sKf[tid*SU2+r];
      fwd16(x, sS2, sSd2);
#pragma unroll
      for (int r = 0; r < 16; ++r) sK2[tid*SU2+r] = x[r];
    } else if (tid == 64) {
      float x[16];
#pragma unroll
      for (int r = 0; r < 16; ++r) x[r] = v16[r];
      solve16(x, sS2, sSd2);
#pragma unroll
      for (int r = 0; r < 16; ++r) v16[r] = x[r];
    } else if (tid == 65) {
      float x[16];
#pragma unroll
      for (int r = 0; r < 16; ++r) x[r] = v16[16+r];
      solve16(x, sS2, sSd2);
#pragma unroll
      for (int r = 0; r < 16; ++r) v16[16+r] = x[r];
    }
    __syncthreads();
    { const int i6 = tid & 63, rq = tid >> 6;
      float u[4] = {0,0,0,0};
      for (int j = 0; j < 64; ++j) {
        const float p = mC[i6*ST+j];
#pragma unroll
        for (int r = 0; r < 4; ++r) u[r] += p*sW[j*SU2+rq*4+r];
      }
#pragma unroll
      for (int r = 0; r < 4; ++r) sP[i6*SU2+rq*4+r] = u[r];
    }
    __syncthreads();
    { const int i6 = tid & 63, rq = tid >> 6;
      float u[4] = {0,0,0,0};
      for (int i = 0; i < 64; ++i) {
        const float av = mA[i*ST+i6];
#pragma unroll
        for (int r = 0; r < 4; ++r) u[r] += av*sW[i*SU2+rq*4+r];
      }
#pragma unroll
      for (int r = 0; r < 4; ++r) sR[i6*SU2+rq*4+r] = u[r];
    }
    __syncthreads();
    { const int a = tid>>4, c = tid&15;
      float sv = 0.f;
      for (int i = 0; i < 64; ++i) sv += sW[i*SU2+a]*sP[i*SU2+c];
      sS3[a*17+c] += sv;
    }
    __syncthreads();
    chol16_sh(sS3, sSd3, tid);
    if (tid >= 64 && tid < 128) {
      const int i = tid-64;
      float t = vk[i];
#pragma unroll
      for (int r = 0; r < 16; ++r) t -= sKf[i*SU2+r]*v16[r];
      vt1[i] = t;
    } else if (tid >= 128 && tid < 144) {
      const int r = tid-128;
      float a = 0.f;
      for (int i = 0; i < 64; ++i) a += sK2[i*SU2+r]*vk[i];
      v16[32+r] = a;
    }
    __syncthreads();
    if (tid < 64) {
      float e = 0.f;
      for (int i = 0; i < 64; ++i) e += F_[i*ST+tid]*vt1[i];
      vt2[tid] = e;
    } else if (tid < 128) {
      const int i = tid-64;
      float bb = vz1[i];
#pragma unroll
      for (int r = 0; r < 16; ++r) bb -= sK2[i*SU2+r]*v16[32+r];
      vb2[i] = bb;
    }
    __syncthreads();
    if (tid < 64) {
      float a = vb[tid];
      for (int j = 0; j < 64; ++j) a += mC[tid*ST+j]*vt2[j];
      vu[tid] = a;
    } else if (tid < 128) {
      const int i = tid-64;
      float a = vt2[i];
#pragma unroll
      for (int r = 0; r < 16; ++r) a -= sW[i*SU2+r]*v16[16+r];
      vg[i] = a;
    }
    __syncthreads();
    if (tid < 64) {
      float a = 0.f;
      for (int j = 0; j < 64; ++j) a += mC[tid*ST+j]*vg[j];
      vhg[tid] = a;
    } else if (tid < 128) {
      const int i = tid-64;
      float x[16];
#pragma unroll
      for (int r = 0; r < 16; ++r) x[r] = sP[i*SU2+r];
      fwd16(x, sS3, sSd3);
#pragma unroll
      for (int r = 0; r < 16; ++r) sTb[i*SU2+r] = x[r];
    } else if (tid < 192) {
      const int i = tid-128;
      float x[16];
#pragma unroll
      for (int r = 0; r < 16; ++r) x[r] = sR[i*SU2+r];
      fwd16(x, sS3, sSd3);
#pragma unroll
      for (int r = 0; r < 16; ++r) sR[i*SU2+r] = x[r];
    } else if (tid < 208) {
      const int r = tid-192;
      float a = 0.f;
      for (int i = 0; i < 64; ++i) a += sW[i*SU2+r]*vu[i];
      v16[48+r] = a;
    }
    __syncthreads();
    if (tid == 0) {
      float x[16];
#pragma unroll
      for (int r = 0; r < 16; ++r) x[r] = v16[48+r];
      solve16(x, sS3, sSd3);
#pragma unroll
      for (int r = 0; r < 16; ++r) v16[48+r] = x[r];
    } else if (tid >= 64 && tid < 80) {
      const int r = tid-64;
      float a = 0.f;
      for (int i = 0; i < 64; ++i) a += sW[i*SU2+r]*vhg[i];
      v16[64+r] = a;
    }
    __syncthreads();
    if (tid == 0) {
      float x[16];
#pragma unroll
      for (int r = 0; r < 16; ++r) x[r] = v16[64+r];
      solve16(x, sS3, sSd3);
#pragma unroll
      for (int r = 0; r < 16; ++r) v16[64+r] = x[r];
    } else if (tid >= 64 && tid < 128) {
      const int i = tid-64;
      float a = vu[i];
#pragma unroll
      for (int r = 0; r < 16; ++r) a -= sP[i*SU2+r]*v16[48+r];
      vmu[i] = a;
    }
    __syncthreads();
    if (tid < 64) {
      float a = vg[tid];
#pragma unroll
      for (int r = 0; r < 16; ++r) a -= sW[tid*SU2+r]*v16[64+r];
      vg2[tid] = a;
    } else if (tid < 80) {
      const int r = tid-64;
      float a = 0.f;
      for (int i = 0; i < 64; ++i) a += sW[i*SU2+r]*vmu[i];
      v16[80+r] = a;
    }
    __syncthreads();
    if (tid < 64) {
      float a = veta[tid];
      for (int i = 0; i < 64; ++i) a += mA[i*ST+tid]*vg2[i];
      vet3[tid] = a;
    } else if (tid == 64) {
      float x[16];
#pragma unroll
      for (int r = 0; r < 16; ++r) x[r] = v16[80+r];
      solve16(x, sS2, sSd2);
#pragma unroll
      for (int r = 0; r < 16; ++r) v16[80+r] = x[r];
    }
    __syncthreads();
    if (tid < 64) {
      float a = vb2[tid];
      for (int j = 0; j < 64; ++j) a += F_[tid*ST+j]*vmu[j];
#pragma unroll
      for (int r = 0; r < 16; ++r) a -= vq[tid]*sKf[tid*SU2+r]*v16[80+r];
      vb[tid] = a;
    } else if (tid < 128) {
      veta[tid-64] = vet3[tid-64];
    }
    __syncthreads();
    for (int idx = tid; idx < 4096; idx += 256) {
      const int i = idx>>6, j = idx&63;
      float aj = 0.f, ac = 0.f;
#pragma unroll
      for (int r = 0; r < 16; ++r) {
        aj += sR[i*SU2+r]*sR[j*SU2+r];
        ac += sTb[i*SU2+r]*sTb[j*SU2+r];
      }
      mJ[i*ST+j] += aj;
      mC[i*ST+j] -= ac;
    }
    __syncthreads();
    for (int idx = tid; idx < 4096; idx += 256) {
      const int i = idx>>6, j = idx&63;
      float a = mA[i*ST+j];
#pragma unroll
      for (int r = 0; r < 16; ++r) a -= sTb[i*SU2+r]*sR[j*SU2+r];
      mA[i*ST+j] = a;
    }
    __syncthreads();
    mm64f<ST,ST,ST,false>(F_, mA, mT, tid);
    __syncthreads();
    { for (int e = 0; e < 4; ++e) {
        const int r = tid & 15, j = (tid>>4)*4 + e;
        float a = 0.f;
        for (int i = 0; i < 64; ++i) a += sW[i*SU2+r]*mA[i*ST+j];
        sG[r*68+j] = a;
      } }
    __syncthreads();
    if (tid < 64) {
      float x[16];
#pragma unroll
      for (int r = 0; r < 16; ++r) x[r] = sG[r*68+tid];
      solve16(x, sS2, sSd2);
#pragma unroll
      for (int r = 0; r < 16; ++r) sG[r*68+tid] = x[r];
    }
    __syncthreads();
    for (int idx = tid; idx < 4096; idx += 256) {
      const int i = idx>>6, j = idx&63;
      float a = mT[i*ST+j];
#pragma unroll
      for (int r = 0; r < 16; ++r) a -= vq[i]*sKf[i*SU2+r]*sG[r*68+j];
      mA[i*ST+j] = a;
    }
    __syncthreads();
    { for (int e = 0; e < 4; ++e) {
        const int r = tid & 15, j = (tid>>4)*4 + e;
        float a = 0.f;
        for (int i = 0; i < 64; ++i) a += sW[i*SU2+r]*mC[i*ST+j];
        sG[r*68+j] = a;
      } }
    __syncthreads();
    if (tid < 64) {
      float x[16];
#pragma unroll
      for (int r = 0; r < 16; ++r) x[r] = sG[r*68+tid];
      solve16(x, sS2, sSd2);
#pragma unroll
      for (int r = 0; r < 16; ++r) sG[r*68+tid] = x[r];
    }
    __syncthreads();
    mm64f<ST,ST,ST,false>(F_, mC, mT, tid);
    __syncthreads();
    for (int idx = tid; idx < 4096; idx += 256) {
      const int i = idx>>6, j = idx&63;
      float a = mT[i*ST+j];
#pragma unroll
      for (int r = 0; r < 16; ++r) a -= vq[i]*sKf[i*SU2+r]*sG[r*68+j];
      mT[i*ST+j] = a;
    }
    __syncthreads();
    mm64f<ST,ST,ST,true>(mT, F_, mC, tid);
    __syncthreads();
    { const int i6 = tid & 63, rq = tid >> 6;
      float u[4] = {0,0,0,0};
      for (int j = 0; j < 64; ++j) {
        const float z = mT[i6*ST+j];
#pragma unroll
        for (int r = 0; r < 4; ++r) u[r] += z*sW[j*SU2+rq*4+r];
      }
#pragma unroll
      for (int r = 0; r < 4; ++r) sZW[i6*SU2+rq*4+r] = u[r];
    }
    __syncthreads();
    if (tid < 64) {
      float x[16];
#pragma unroll
      for (int r = 0; r < 16; ++r) x[r] = sZW[tid*SU2+r];
      solve16(x, sS2, sSd2);
#pragma unroll
      for (int r = 0; r < 16; ++r) sZW[tid*SU2+r] = x[r];
    }
    __syncthreads();
    for (int idx = tid; idx < 4096; idx += 256) {
      const int i = idx>>6, j = idx&63;
      float a = mC[i*ST+j] + ((i==j) ? vq[i] : 0.f);
#pragma unroll
      for (int r = 0; r < 16; ++r) {
        a -= sZW[i*SU2+r]*vq[j]*sKf[j*SU2+r];
        a -= sK2[i*SU2+r]*sK2[j*SU2+r];
      }
      mC[i*ST+j] = a;
    }
    __syncthreads();
  }
  const size_t so = (size_t)b*NSEG + s;
  for (int i = tid; i < 4096; i += 256) {
    const int r = i>>6, c = i&63;
    Aseg[so*4096+i] = mA[r*ST+c];
    Cseg[so*4096+i] = mC[r*ST+c];
    Jseg[so*4096+i] = mJ[r*ST+c];
  }
  if (tid < 64) { bseg[so*64+tid] = vb[tid]; etaseg[so*64+tid] = veta[tid]; }
#undef STAGE_K
}

#define FB_LDS 103424
__global__ __launch_bounds__(256, 1) void fboundary_kernel(
    const float* __restrict__ Aseg, const float* __restrict__ Cseg,
    const float* __restrict__ Jseg, const float* __restrict__ bseg,
    const float* __restrict__ etaseg,
    float* __restrict__ BPm, float* __restrict__ BPC)
{
  const int b = blockIdx.x, tid = threadIdx.x;
  extern __shared__ __align__(16) char fbm[];
  float* mC1  = (float*)fbm;
  float* mJ2  = mC1 + 64*ST;
  float* mA2  = mJ2 + 64*ST;
  float* mP2T = mA2 + 64*ST;
  float* mS   = mP2T + 64*ST;
  float* mT1  = mS  + 64*ST;
  float* vb1  = mT1 + 64*ST;
  float* vb2  = vb1 + 64;
  float* vet2 = vb2 + 64;
  float* vu2  = vet2 + 64;
  float* zv   = vu2 + 64;
  float* vmu  = zv  + 64;
  float* sDi  = vmu + 64;
  float* vdg  = sDi + 64;
  float* sRed = vdg + 64;

  for (int i = tid; i < 4096; i += 256)
    mC1[(i>>6)*ST + (i&63)] = BPC[((size_t)b*NSEG + 1)*4096 + i];
  if (tid < 64) vb1[tid] = BPm[((size_t)b*NSEG + 1)*64 + tid];
  __syncthreads();

  for (int s = 1; s <= 6; ++s) {
    const size_t so = (size_t)b*NSEG + s;
    for (int i = tid; i < 4096; i += 256) {
      const int r = i>>6, c = i&63;
      mJ2[r*ST+c] = Jseg[so*4096+i];
      mA2[r*ST+c] = Aseg[so*4096+i];
    }
    if (tid < 64) { vb2[tid] = bseg[so*64+tid]; vet2[tid] = etaseg[so*64+tid]; }
    __syncthreads();
    if (tid < 64) {
      float a = vb1[tid];
      for (int j = 0; j < 64; ++j) a += mC1[tid*ST+j]*vet2[j];
      vu2[tid] = a;
      sRed[tid] = mJ2[tid*ST+tid];
    }
    __syncthreads();
    if (tid == 0) {
      float m = 0.f;
      for (int i = 0; i < 64; ++i) m = fmaxf(m, sRed[i]);
      sRed[0] = m;
    }
    __syncthreads();
    if (tid < 64) mJ2[tid*ST+tid] += 1e-5f*sRed[0] + 1e-20f;
    __syncthreads();
    chol64_blk<ST>(mJ2, sDi, vdg, tid);
    for (int idx = tid; idx < 4096; idx += 256) {
      const int i = idx>>6, j = idx&63;
      if (i < j) mJ2[i*ST+j] = 0.f;
      else if (i == j) mJ2[i*ST+i] = vdg[i];
    }
    __syncthreads();
    mm64f<ST,ST,ST,false>(mC1, mJ2, mT1, tid);
    __syncthreads();
    for (int idx = tid; idx < 4096; idx += 256) {
      const int i = idx>>6, j = idx&63;
      mP2T[j*ST+i] = mT1[i*ST+j];
    }
    __syncthreads();
    mm64f<ST,ST,ST,false>(mP2T, mJ2, mS, tid);
    __syncthreads();
    if (tid < 64) {
      mS[tid*ST+tid] += 1.f;
      float a = 0.f;
      for (int i = 0; i < 64; ++i) a += mJ2[i*ST+tid]*vu2[i];
      zv[tid] = a;
    }
    __syncthreads();
    chol64_blk<ST>(mS, sDi, (float*)nullptr, tid);
#pragma unroll
    for (int jb = 0; jb < 4; ++jb) {
      const int o = jb*16;
      if (tid < 64) {
        const int c = tid;
        float x[16];
#pragma unroll
        for (int q = 0; q < 16; ++q) x[q] = mP2T[(o+q)*ST + c];
#pragma unroll
        for (int j = 0; j < 16; ++j) {
          x[j] *= sDi[o+j];
#pragma unroll
          for (int i = j+1; i < 16; ++i) x[i] -= mS[(o+i)*ST + o+j] * x[j];
        }
#pragma unroll
        for (int q = 0; q < 16; ++q) mP2T[(o+q)*ST + c] = x[q];
      }
      __syncthreads();
      const int nr = 48 - o;
      if (nr > 0) {
        for (int idx = tid; idx < nr*64; idx += 256) {
          const int r = o + 16 + idx/64, c = idx%64;
          float acc = mP2T[r*ST + c];
#pragma unroll
          for (int k = 0; k < 16; ++k) acc -= mS[r*ST + o+k] * mP2T[(o+k)*ST + c];
          mP2T[r*ST + c] = acc;
        }
        __syncthreads();
      }
    }
    for (int idx = tid; idx < 4096; idx += 256) {
      const int i = idx>>6, j = idx&63;
      float a = mC1[i*ST+j];
      for (int k = 0; k < 64; ++k) a -= mP2T[k*ST+i]*mP2T[k*ST+j];
      mC1[i*ST+j] = a;
    }
    __syncthreads();
    if (tid == 0) {
      for (int k = 0; k < 64; ++k) {
        zv[k] *= sDi[k];
        for (int i = k+1; i < 64; ++i) zv[i] -= mS[i*ST+k]*zv[k];
      }
      for (int k = 63; k >= 0; --k) {
        zv[k] *= sDi[k];
        for (int i = 0; i < k; ++i) zv[i] -= mS[k*ST+i]*zv[k];
      }
    }
    __syncthreads();
    if (tid < 64) {
      float a = vu2[tid];
      for (int k = 0; k < 64; ++k) a -= mT1[tid*ST+k]*zv[k];
      vmu[tid] = a;
    }
    __syncthreads();
    mm64f<ST,ST,ST,false>(mA2, mC1, mT1, tid);
    __syncthreads();
    mm64f<ST,ST,ST,true>(mT1, mA2, mC1, tid);
    __syncthreads();
    for (int i = tid; i < 4096; i += 256)
      mC1[(i>>6)*ST + (i&63)] += Cseg[so*4096+i];
    if (tid < 64) {
      float a = vb2[tid];
      for (int j = 0; j < 64; ++j) a += mA2[tid*ST+j]*vmu[j];
      sRed[tid] = a;
    }
    __syncthreads();
    if (tid < 64) vb1[tid] = sRed[tid];
    __syncthreads();
    if (tid < 64) BPm[((size_t)b*NSEG + s + 1)*64 + tid] = vb1[tid];
    for (int i = tid; i < 4096; i += 256)
      BPC[((size_t)b*NSEG + s + 1)*4096 + i] = mC1[(i>>6)*ST + (i&63)];
    __syncthreads();
  }
}

// Diagnostic: compare scan BP vs sequential filter at t=63 (slot2) and t=223 (slot7).
__global__ __launch_bounds__(256) void fdiag_kernel(
    const float* __restrict__ BPm, const float* __restrict__ BPC,
    const float* __restrict__ mf_g, const float* __restrict__ Pf_g,
    float* __restrict__ diagv)
{
  __shared__ float red[256];
  const int tid = threadIdx.x;
  float e2 = 0.f, e7 = 0.f;
  for (int b = 0; b < B_; ++b) {
    for (int i = tid; i < 64; i += 256) {
      float d2 = BPm[((size_t)b*NSEG+2)*64+i] - mf_g[((size_t)b*T_+63)*64+i];
      float d7 = BPm[((size_t)b*NSEG+7)*64+i] - mf_g[((size_t)b*T_+223)*64+i];
      e2 = isfinite(d2) ? fmaxf(e2, fabsf(d2)) : 1e9f;
      e7 = isfinite(d7) ? fmaxf(e7, fabsf(d7)) : 1e9f;
    }
    for (int i = tid; i < 4096; i += 256) {
      float d2 = BPC[((size_t)b*NSEG+2)*4096+i] - Pf_g[((size_t)b*T_+63)*4096+i];
      float d7 = BPC[((size_t)b*NSEG+7)*4096+i] - Pf_g[((size_t)b*T_+223)*4096+i];
      e2 = isfinite(d2) ? fmaxf(e2, fabsf(d2)) : 1e9f;
      e7 = isfinite(d7) ? fmaxf(e7, fabsf(d7)) : 1e9f;
    }
  }
  red[tid] = e2;
  __syncthreads();
  for (int s = 128; s > 0; s >>= 1) { if (tid < s) red[tid] = fmaxf(red[tid], red[tid+s]); __syncthreads(); }
  const float E2 = red[0];
  __syncthreads();
  red[tid] = e7;
  __syncthreads();
  for (int s = 128; s > 0; s >>= 1) { if (tid < s) red[tid] = fmaxf(red[tid], red[tid+s]); __syncthreads(); }
  const float E7 = red[0];
  if (tid == 0) {
    const float tol = 0.03f;
    float d = 0.f;
    if (E2 >= tol) d = 2048.f;
    else if (E7 >= tol) d = 1024.f;
    diagv[0] = d;
  }
}

// ---------------- K3: gains (round-8) ----------------
__global__ __launch_bounds__(256) void gains_kernel(
    const float* __restrict__ Fg, const float* __restrict__ logQ,
    const float* __restrict__ mf_g, const float* __restrict__ mp_g,
    float* __restrict__ PfG_g, float* __restrict__ Cpk,
    float* __restrict__ d_g, float* __restrict__ dpart_g)
{
  const int blk = blockIdx.x;
  const int b = blk / (T_-1);
  const int n = 1 + (blk % (T_-1));
  const size_t btn = (size_t)b*T_ + n;
  const size_t btm = btn - 1;
  const int tid = threadIdx.x;
  const int rg = tid >> 4, cg = tid & 15;
  __shared__ float sA[64*ST];
  __shared__ float sM[64*STM];
  __shared__ float sPp[64*ST];
  __shared__ float sDi[64], sQd[64];
  __shared__ float smf1[64], smp[64];
  __shared__ float sd1d2[2];

  for (int i = tid; i < 4096; i += 256) sA[(i>>6)*ST + (i&63)] = PfG_g[btm*4096+i];
  if (tid < 64) {
    sM[tid*STM+64] = mf_g[btn*64+tid];
    sM[tid*STM+65] = mp_g[btn*64+tid];
    smf1[tid] = mf_g[btm*64+tid];
    smp[tid]  = mp_g[btn*64+tid];
    sQd[tid]  = softplus_f(logQ[tid]);
  }
  __syncthreads();
  {
    float acc[4][4] = {{0.f}};
#pragma unroll 4
    for (int k = 0; k < 64; ++k) {
      float a[4], bb[4];
#pragma unroll
      for (int i = 0; i < 4; ++i) a[i] = Fg[(rg*4+i)*64 + k];
#pragma unroll
      for (int j = 0; j < 4; ++j) bb[j] = sA[k*ST + cg*4+j];
#pragma unroll
      for (int i = 0; i < 4; ++i)
#pragma unroll
        for (int j = 0; j < 4; ++j) acc[i][j] += a[i]*bb[j];
    }
#pragma unroll
    for (int i = 0; i < 4; ++i)
#pragma unroll
      for (int j = 0; j < 4; ++j) sM[(rg*4+i)*STM + cg*4+j] = acc[i][j];
  }
  __syncthreads();
  {
    float acc[4][4] = {{0.f}};
#pragma unroll 4
    for (int k = 0; k < 64; ++k) {
      float a[4], bb[4];
#pragma unroll
      for (int i = 0; i < 4; ++i) a[i] = sM[(rg*4+i)*STM + k];
#pragma unroll
      for (int j = 0; j < 4; ++j) bb[j] = Fg[(cg*4+j)*64 + k];
#pragma unroll
      for (int i = 0; i < 4; ++i)
#pragma unroll
        for (int j = 0; j < 4; ++j) acc[i][j] += a[i]*bb[j];
    }
#pragma unroll
    for (int i = 0; i < 4; ++i)
#pragma unroll
      for (int j = 0; j < 4; ++j) {
        const int r = rg*4+i, c = cg*4+j;
        sPp[r*ST+c] = acc[i][j] + ((r==c) ? sQd[r] : 0.f);
      }
  }
  __syncthreads();
  chol64_blk<ST>(sPp, sDi, (float*)nullptr, tid);
#pragma unroll
  for (int jb = 0; jb < 4; ++jb) {
    const int o = jb*16;
    if (tid < 66) {
      const int c = tid;
      float x[16];
#pragma unroll
      for (int q = 0; q < 16; ++q) x[q] = sM[(o+q)*STM + c];
#pragma unroll
      for (int j = 0; j < 16; ++j) {
        x[j] *= sDi[o+j];
#pragma unroll
        for (int i = j+1; i < 16; ++i) x[i] -= sPp[(o+i)*ST + o+j] * x[j];
      }
#pragma unroll
      for (int q = 0; q < 16; ++q) sM[(o+q)*STM + c] = x[q];
    }
    __syncthreads();
    const int nr = 48 - o;
    if (nr > 0) {
      for (int idx = tid; idx < nr*66; idx += 256) {
        const int r = o + 16 + idx/66, c = idx%66;
        float acc = sM[r*STM + c];
#pragma unroll
        for (int k = 0; k < 16; ++k) acc -= sPp[r*ST + o+k] * sM[(o+k)*STM + c];
        sM[r*STM + c] = acc;
      }
      __syncthreads();
    }
  }
  if (tid == 64 || tid == 65) {
    float a = 0.f;
    for (int i = 0; i < 64; ++i) { const float v = sM[i*STM+tid]; a += v*v; }
    sd1d2[tid-64] = a;
  }
  {
    float acc[4][4] = {{0.f}};
#pragma unroll 2
    for (int k = 0; k < 64; ++k) {
      float a[4], bb[4];
#pragma unroll
      for (int i = 0; i < 4; ++i) a[i] = sM[k*STM + rg*4+i];
#pragma unroll
      for (int j = 0; j < 4; ++j) bb[j] = sM[k*STM + cg*4+j];
#pragma unroll
      for (int i = 0; i < 4; ++i)
#pragma unroll
        for (int j = 0; j < 4; ++j) acc[i][j] += a[i]*bb[j];
    }
#pragma unroll
    for (int i = 0; i < 4; ++i)
#pragma unroll
      for (int j = 0; j < 4; ++j)
        sA[(rg*4+i)*ST + (cg*4+j)] -= acc[i][j];
  }
  __syncthreads();
  for (int idx = tid; idx < 4096; idx += 256) {
    const int i = idx>>6, j = idx&63;
    if (i >= j) Cpk[btn*PKN + PIDX(i,j)] = sA[i*ST+j];
  }
#pragma unroll
  for (int jb = 3; jb >= 0; --jb) {
    const int o = jb*16;
    if (tid < 64) {
      const int c = tid;
      float x[16];
#pragma unroll
      for (int q = 0; q < 16; ++q) x[q] = sM[(o+q)*STM + c];
#pragma unroll
      for (int j = 15; j >= 0; --j) {
        x[j] *= sDi[o+j];
#pragma unroll
        for (int i = 0; i < j; ++i) x[i] -= sPp[(o+j)*ST + o+i] * x[j];
      }
#pragma unroll
      for (int q = 0; q < 16; ++q) sM[(o+q)*STM + c] = x[q];
    }
    __syncthreads();
    if (o > 0) {
      for (int idx = tid; idx < o*64; idx += 256) {
        const int r = idx/64, c = idx%64;
        float acc = sM[r*STM + c];
#pragma unroll
        for (int k = 0; k < 16; ++k) acc -= sPp[(o+k)*ST + r] * sM[(o+k)*STM + c];
        sM[r*STM + c] = acc;
      }
      __syncthreads();
    }
  }
  for (int i = tid; i < 4096; i += 256)
    PfG_g[btm*4096 + i] = sM[(i&63)*STM + (i>>6)];
  if (tid < 64) {
    float a = smf1[tid];
    for (int j = 0; j < 64; ++j) a -= sM[j*STM+tid]*smp[j];
    d_g[btm*64 + tid] = a;
  }
  if (tid == 0)
    dpart_g[btn] = 0.5f*(sd1d2[0] - sd1d2[1] + dpart_g[btn]);
}

// ---------------- K4a: smoother segment compose ----------------
__global__ __launch_bounds__(256) void compose_kernel(
    const float* __restrict__ G_g, const float* __restrict__ Cpk,
    const float* __restrict__ d_g,
    float* __restrict__ Gseg, float* __restrict__ cseg, float* __restrict__ dseg)
{
  extern __shared__ char cm[];
  short* GMh = (short*)cm;
  short* GMl = GMh + 4096;
  short* cMh = GMl + 4096;
  short* cMl = cMh + 4096;
  short* Gth = cMl + 4096;
  short* Gtl = Gth + 4096;
  short* Xh  = Gtl + 4096;
  short* Xl  = Xh + 4096;
  float* cbuf = (float*)(cm + 65536);
  float* sRed = (float*)(cm + 65536 + 8320);
  float* sdv  = (float*)(cm + 65536 + 8320 + 1024);

  const int blk = blockIdx.x, tid = threadIdx.x;
  const int b = blk >> 3, s = blk & (NSEG-1);
  const int w = tid >> 6, l = tid & 63;
  const int lr = l & 15, lg = l >> 4;
  const int t0 = s*SEG;
  const int tend = (s == NSEG-1) ? (T_-2) : (t0 + SEG - 1);

  {
    const size_t bt = (size_t)b*T_ + tend;
#pragma unroll
    for (int q = 0; q < 4; ++q) {
      const int idx = q*1024 + tid*4;
      const int row = idx>>6, col = idx&63;
      float4 v = *(const float4*)&G_g[bt*4096 + idx];
      s16x4 h4, l4;
      splitbf4(v, h4, l4);
#pragma unroll
      for (int e = 0; e < 4; ++e) {
        GMh[(col+e)*64 + row] = h4[e];
        GMl[(col+e)*64 + row] = l4[e];
      }
    }
    for (int idx = tid; idx < 4096; idx += 256) {
      const int i = idx>>6, j = idx&63;
      const int pidx = (i >= j) ? PIDX(i,j) : PIDX(j,i);
      const float v = Cpk[(bt+1)*PKN + pidx];
      short h, lo; splitbf(v, h, lo);
      cMh[i*64+j] = h; cMl[i*64+j] = lo;
    }
    if (tid < 64) sdv[tid] = d_g[bt*64+tid];
  }
  __syncthreads();

  for (int t = tend-1; t >= t0; --t) {
    const size_t bt = (size_t)b*T_ + t;
#pragma unroll
    for (int q = 0; q < 4; ++q) {
      const int idx = q*1024 + tid*4;
      const int row = idx>>6, col = idx&63;
      float4 v = *(const float4*)&G_g[bt*4096 + idx];
      s16x4 h4, l4;
      splitbf4(v, h4, l4);
      *(s16x4*)&Gth[row*64+col] = h4;
      *(s16x4*)&Gtl[row*64+col] = l4;
    }
    for (int i2 = tid; i2 < PKN; i2 += 256) cbuf[i2] = Cpk[(bt+1)*PKN + i2];
    float dreg = 0.f;
    if (tid < 64) dreg = d_g[bt*64+tid];
    __syncthreads();
    f32x4 a1[4], a2[4];
#pragma unroll
    for (int ct = 0; ct < 4; ++ct) { a1[ct] = (f32x4){0,0,0,0}; a2[ct] = (f32x4){0,0,0,0}; }
    mfma_mm64<64>(Gth, Gtl, GMh, GMl, w, l, a1);
    mfma_mm64<64>(Gth, Gtl, cMh, cMl, w, l, a2);
    {
      const int i = tid & 63, jb = tid >> 6;
      float ss = 0.f;
      for (int j = 0; j < 16; ++j) {
        const int jj = jb*16 + j;
        ss += (bf2f(Gth[i*64+jj]) + bf2f(Gtl[i*64+jj])) * sdv[jj];
      }
      sRed[tid] = ss;
    }
    __syncthreads();
#pragma unroll
    for (int ct = 0; ct < 4; ++ct)
#pragma unroll
      for (int r = 0; r < 4; ++r) {
        const int row = w*16 + lg*4 + r, col = ct*16 + lr;
        short h, lo;
        splitbf(a1[ct][r], h, lo);
        GMh[col*64+row] = h; GMl[col*64+row] = lo;
        splitbf(a2[ct][r], h, lo);
        Xh[row*64+col] = h; Xl[row*64+col] = lo;
      }
    if (tid < 64)
      sdv[tid] = dreg + sRed[tid] + sRed[tid+64] + sRed[tid+128] + sRed[tid+192];
    __syncthreads();
    f32x4 a3[4];
#pragma unroll
    for (int ct = 0; ct < 4; ++ct) a3[ct] = (f32x4){0,0,0,0};
    mfma_mm64<64>(Xh, Xl, Gth, Gtl, w, l, a3);
#pragma unroll
    for (int ct = 0; ct < 4; ++ct)
#pragma unroll
      for (int r = 0; r < 4; ++r) {
        const int row = w*16 + lg*4 + r, col = ct*16 + lr;
        const int pidx = (row >= col) ? PIDX(row,col) : PIDX(col,row);
        const float cv = cbuf[pidx] + a3[ct][r];
        short h, lo; splitbf(cv, h, lo);
        cMh[row*64+col] = h; cMl[row*64+col] = lo;
      }
    __syncthreads();
  }
  for (int idx = tid; idx < 4096; idx += 256) {
    const int i = idx>>6, j = idx&63;
    Gseg[(size_t)blk*4096 + idx] = bf2f(GMh[j*64+i]) + bf2f(GMl[j*64+i]);
    if (i >= j)
      cseg[(size_t)blk*PKN + PIDX(i,j)] = bf2f(cMh[i*64+j]) + bf2f(cMl[i*64+j]);
  }
  if (tid < 64) dseg[(size_t)blk*64 + tid] = sdv[tid];
}

// ---------------- K4b: smoother boundary scan ----------------
__global__ __launch_bounds__(256) void boundary_kernel(
    const float* __restrict__ PfG_g, const float* __restrict__ mfT_g,
    const float* __restrict__ Gseg, const float* __restrict__ cseg,
    const float* __restrict__ dseg,
    float* __restrict__ InP, float* __restrict__ Inm)
{
  __shared__ short Gsh[4096], Gsl[4096], vh[4096], vl[4096], Wh[4096], Wl[4096];
  __shared__ float cb[PKN];
  __shared__ float svm[64];
  __shared__ float sRed[256];
  const int b = blockIdx.x, tid = threadIdx.x;
  const int w = tid >> 6, l = tid & 63;
  const int lr = l & 15, lg = l >> 4;

  {
    const size_t bl = ((size_t)b*T_ + (T_-1))*4096;
    for (int idx = tid; idx < 4096; idx += 256) {
      const int i = idx>>6, j = idx&63;
      const float v = PfG_g[bl + idx];
      short h, lo; splitbf(v, h, lo);
      vh[i*64+j] = h; vl[i*64+j] = lo;
      if (i >= j) InP[((size_t)b*NSEG + (NSEG-1))*PKN + PIDX(i,j)] = v;
    }
    if (tid < 64) {
      const float m = mfT_g[b*64+tid];
      svm[tid] = m;
      Inm[((size_t)b*NSEG + (NSEG-1))*64 + tid] = m;
    }
  }
  __syncthreads();
  for (int s = NSEG-1; s >= 1; --s) {
    const size_t seg = (size_t)b*NSEG + s;
    float dreg = 0.f;
#pragma unroll
    for (int q = 0; q < 4; ++q) {
      const int idx = q*1024 + tid*4;
      const int row = idx>>6, col = idx&63;
      float4 v = *(const float4*)&Gseg[seg*4096 + idx];
      s16x4 h4, l4;
      splitbf4(v, h4, l4);
      *(s16x4*)&Gsh[row*64+col] = h4;
      *(s16x4*)&Gsl[row*64+col] = l4;
    }
    for (int i2 = tid; i2 < PKN; i2 += 256) cb[i2] = cseg[seg*PKN + i2];
    if (tid < 64) dreg = dseg[seg*64+tid];
    __syncthreads();
    {
      const int i = tid & 63, jb = tid >> 6;
      float ss = 0.f;
      for (int j = 0; j < 16; ++j) {
        const int jj = jb*16 + j;
        ss += (bf2f(Gsh[i*64+jj]) + bf2f(Gsl[i*64+jj])) * svm[jj];
      }
      sRed[tid] = ss;
    }
    f32x4 a1[4];
#pragma unroll
    for (int ct = 0; ct < 4; ++ct) a1[ct] = (f32x4){0,0,0,0};
    mfma_mm64<64>(Gsh, Gsl, vh, vl, w, l, a1);
    __syncthreads();
#pragma unroll
    for (int ct = 0; ct < 4; ++ct)
#pragma unroll
      for (int r = 0; r < 4; ++r) {
        const int row = w*16 + lg*4 + r, col = ct*16 + lr;
        short h, lo; splitbf(a1[ct][r], h, lo);
        Wh[row*64+col] = h; Wl[row*64+col] = lo;
      }
    if (tid < 64)
      svm[tid] = dreg + sRed[tid] + sRed[tid+64] + sRed[tid+128] + sRed[tid+192];
    __syncthreads();
    f32x4 a2[4];
#pragma unroll
    for (int ct = 0; ct < 4; ++ct) a2[ct] = (f32x4){0,0,0,0};
    mfma_mm64<64>(Wh, Wl, Gsh, Gsl, w, l, a2);
#pragma unroll
    for (int ct = 0; ct < 4; ++ct)
#pragma unroll
      for (int r = 0; r < 4; ++r) {
        const int row = w*16 + lg*4 + r, col = ct*16 + lr;
        const int pidx = (row >= col) ? PIDX(row,col) : PIDX(col,row);
        const float vv = cb[pidx] + a2[ct][r];
        short h, lo; splitbf(vv, h, lo);
        vh[row*64+col] = h; vl[row*64+col] = lo;
        if (row >= col) InP[((size_t)b*NSEG + s - 1)*PKN + PIDX(row,col)] = vv;
      }
    if (tid < 64) Inm[((size_t)b*NSEG + s - 1)*64 + tid] = svm[tid];
    __syncthreads();
  }
}

// ---------------- K4c: smoother segment expand ----------------
__global__ __launch_bounds__(256) void expand_kernel(
    const float* __restrict__ GPs_g, float* __restrict__ Cpk,
    const float* __restrict__ d_g, const float* __restrict__ InP,
    const float* __restrict__ Inm, float* __restrict__ ms_g)
{
  __shared__ float sPs[64*STF];
  __shared__ short sGh[64*SBF], sGl[64*SBF];
  __shared__ short sPh[64*SBF], sPl[64*SBF];
  __shared__ float sms[64];
  __shared__ float sRed[256];
  const int blk = blockIdx.x, tid = threadIdx.x;
  const int b = blk >> 3, s = blk & (NSEG-1);
  const int w = tid >> 6, l = tid & 63;
  const int t0 = s*SEG;
  const int tend = (s == NSEG-1) ? (T_-2) : (t0 + SEG - 1);

  int ci[9], cj[9];
#pragma unroll
  for (int nn = 0; nn < 9; ++nn) {
    const int p = nn*256 + tid;
    int i = (int)((sqrtf(8.f*(float)p + 1.f) - 1.f)*0.5f);
    while ((i+1)*(i+2)/2 <= p) ++i;
    while (i*(i+1)/2 > p) --i;
    ci[nn] = i; cj[nn] = p - i*(i+1)/2;
  }

  for (int idx = tid; idx < 4096; idx += 256) {
    const int i = idx>>6, j = idx&63;
    const int pidx = (i >= j) ? PIDX(i,j) : PIDX(j,i);
    sPs[i*STF+j] = InP[((size_t)b*NSEG + s)*PKN + pidx];
  }
  if (tid < 64) sms[tid] = Inm[((size_t)b*NSEG + s)*64 + tid];
  __syncthreads();
  if (s == NSEG-1) {
#pragma unroll
    for (int nn = 0; nn < 9; ++nn) {
      const int p = nn*256 + tid;
      if (p < PKN) Cpk[(size_t)b*T_*PKN + p] = sPs[ci[nn]*STF + cj[nn]];
    }
    if (tid < 64) ms_g[((size_t)b*T_ + (T_-1))*64 + tid] = sms[tid];
  }
  float4 gf4[4];
  {
    const float4* Gp = (const float4*)(GPs_g + ((size_t)b*T_ + tend)*4096);
#pragma unroll
    for (int q = 0; q < 4; ++q) gf4[q] = Gp[q*256 + tid];
  }

  for (int t = tend; t >= t0; --t) {
    const size_t bt = (size_t)b*T_ + t;
    const size_t cslot = (bt+1)*PKN;
#pragma unroll
    for (int q = 0; q < 4; ++q) {
      const int row = q*16 + (tid>>4), col = (tid&15)*4;
      s16x4 h4, l4;
      splitbf4(gf4[q], h4, l4);
      *(s16x4*)&sGh[row*SBF+col] = h4;
      *(s16x4*)&sGl[row*SBF+col] = l4;
    }
#pragma unroll
    for (int q = 0; q < 4; ++q) {
      const int idx = q*1024 + tid*4;
      const int row = idx>>6, col = idx&63;
      float4 v = *(const float4*)&sPs[row*STF+col];
      s16x4 h4, l4;
      splitbf4(v, h4, l4);
      *(s16x4*)&sPh[row*SBF+col] = h4;
      *(s16x4*)&sPl[row*SBF+col] = l4;
    }
    float cr[9];
#pragma unroll
    for (int nn = 0; nn < 9; ++nn) {
      const int p = nn*256 + tid;
      cr[nn] = (p < PKN) ? Cpk[cslot + p] : 0.f;
    }
    float dreg = 0.f;
    if (tid < 64) dreg = d_g[bt*64+tid];
    {
      const size_t tprev = (t > t0) ? (bt-1) : bt;
      const float4* Gp = (const float4*)(GPs_g + tprev*4096);
#pragma unroll
      for (int q = 0; q < 4; ++q) gf4[q] = Gp[q*256 + tid];
    }
    __syncthreads();
    f32x4 acc[4];
#pragma unroll
    for (int ct = 0; ct < 4; ++ct) acc[ct] = (f32x4){0.f,0.f,0.f,0.f};
    mfma_mm64<SBF>(sGh, sGl, sPh, sPl, w, l, acc);
    {
      const int i = tid & 63, jb = tid >> 6;
      float ss = 0.f;
#pragma unroll
      for (int hq = 0; hq < 2; ++hq) {
        bf16x8 gh = *(const bf16x8*)&sGh[i*SBF + jb*16 + hq*8];
        bf16x8 gl = *(const bf16x8*)&sGl[i*SBF + jb*16 + hq*8];
#pragma unroll
        for (int j = 0; j < 8; ++j)
          ss += (bf2f(gh[j]) + bf2f(gl[j])) * sms[jb*16 + hq*8 + j];
      }
      sRed[tid] = ss;
    }
    __syncthreads();
    {
      const int lr = l & 15, lg = l >> 4;
#pragma unroll
      for (int ct = 0; ct < 4; ++ct)
#pragma unroll
        for (int r = 0; r < 4; ++r) {
          short hh, ll;
          splitbf(acc[ct][r], hh, ll);
          const int row = w*16 + lg*4 + r, col = ct*16 + lr;
          sPh[row*SBF+col] = hh; sPl[row*SBF+col] = ll;
        }
    }
    __syncthreads();
    float mval = 0.f;
    if (tid < 64) {
      mval = dreg + sRed[tid] + sRed[tid+64] + sRed[tid+128] + sRed[tid+192];
      sms[tid] = mval; ms_g[bt*64+tid] = mval;
    }
#pragma unroll
    for (int ct = 0; ct < 4; ++ct) acc[ct] = (f32x4){0.f,0.f,0.f,0.f};
    mfma_mm64<SBF>(sPh, sPl, sGh, sGl, w, l, acc);
    __syncthreads();
    {
      const int lr = l & 15, lg = l >> 4;
#pragma unroll
      for (int ct = 0; ct < 4; ++ct)
#pragma unroll
        for (int r = 0; r < 4; ++r) {
          const int row = w*16 + lg*4 + r, col = ct*16 + lr;
          sPs[row*STF+col] = acc[ct][r];
        }
    }
    __syncthreads();
#pragma unroll
    for (int nn = 0; nn < 9; ++nn) {
      const int p = nn*256 + tid;
      if (p < PKN) {
        const int i = ci[nn], j = cj[nn];
        float val;
        if (i == j) val = cr[nn] + sPs[i*STF+i];
        else        val = cr[nn] + 0.5f*(sPs[i*STF+j] + sPs[j*STF+i]);
        sPs[i*STF+j] = val;
        if (i != j) sPs[j*STF+i] = val;
        Cpk[cslot + p] = val;
      }
    }
    __syncthreads();
  }
}

// ---------------- K5: KL finalize + sampling + ELL ----------------
__global__ __launch_bounds__(256) void klell_kernel(
    const float* __restrict__ yg, const float* __restrict__ epsg,
    const float* __restrict__ kyg, const float* __restrict__ Kxg,
    const float* __restrict__ Cg, const float* __restrict__ brg,
    const float* __restrict__ Cpk, const float* __restrict__ ms_g,
    const float* __restrict__ dpart_g, float* __restrict__ val_g)
{
  const int bx = blockIdx.x;
  const int b = bx >> 8, t = bx & (T_-1);
  const size_t bt = (size_t)bx;
  const int tid = threadIdx.x;
  __shared__ float sPs[64*ST], sC[64*ST];
  __shared__ float sPA[64*17], sK[64*17];
  __shared__ float sZ[NS_*ST];
  __shared__ float sE[NS_*64];
  __shared__ float sy[256], sbr[256];
  __shared__ float skv[64], sms[64], sDi[64], sDg[64];
  __shared__ float sv[16];
  __shared__ float red[256];

  const size_t pslot = ((size_t)b*T_ + ((t+1) & (T_-1)))*PKN;
  for (int idx = tid; idx < 4096; idx += 256) {
    const int i = idx>>6, j = idx&63;
    const int pidx = (i >= j) ? PIDX(i,j) : PIDX(j,i);
    sPs[i*ST+j] = Cpk[pslot + pidx];
  }
  for (int i = tid; i < 1024; i += 256) sK[(i>>4)*17+(i&15)] = Kxg[bt*1024+i];
  if (tid < 64) { skv[tid] = kyg[bt*64+tid]; sms[tid] = ms_g[bt*64+tid]; }
  sy[tid]  = yg[bt*256+tid];
  sbr[tid] = brg[tid];
  for (int i = tid; i < NS_*64; i += 256) {
    const int s = i >> 6, j = i & 63;
    sE[i] = epsg[(((size_t)s*B_ + b)*T_ + t)*64 + j];
  }
  __syncthreads();
  {
    const int i = tid & 63, rq = tid >> 6;
    float u[4] = {0.f,0.f,0.f,0.f};
    for (int j = 0; j < 64; ++j) {
      const float p = sPs[i*ST+j];
#pragma unroll
      for (int r = 0; r < 4; ++r) u[r] += p * sK[j*17 + rq*4 + r];
    }
#pragma unroll
    for (int r = 0; r < 4; ++r) sPA[i*17 + rq*4 + r] = u[r];
  }
  __syncthreads();
  {
    const int i = tid & 63, rq = tid >> 6;
    float a = 0.f;
#pragma unroll
    for (int r = 0; r < 4; ++r) a += sK[i*17+rq*4+r]*sPA[i*17+rq*4+r];
    red[tid] = a;
  }
  if (tid < 16) {
    float a = 0.f;
    for (int i = 0; i < 64; ++i) a += sK[i*17+tid]*sms[i];
    sv[tid] = a;
  }
  __syncthreads();
  for (int s2 = 128; s2 > 0; s2 >>= 1) {
    if (tid < s2) red[tid] += red[tid+s2];
    __syncthreads();
  }
  float klv = 0.f;
  if (tid == 0) {
    const float tr = red[0];
    float ip1 = 0.f;
    for (int i = 0; i < 64; ++i) ip1 += skv[i]*sms[i];
    float s2s = 0.f;
#pragma unroll
    for (int r = 0; r < 16; ++r) s2s += sv[r]*sv[r];
    klv = (ip1 - 0.5f*s2s - 0.5f*tr) - dpart_g[bt];
  }
  if (tid < 64) sPs[tid*ST+tid] += 1e-5f;
  __syncthreads();
  chol64_blk<ST>(sPs, sDi, sDg, tid);
#pragma unroll
  for (int p = 0; p < 2; ++p) {
    const int s = (tid >> 6) + 4*p, ll = tid & 63;
    float a = sms[ll];
    for (int j = 0; j < ll; ++j) a += sPs[ll*ST+j]*sE[s*64+j];
    a += sDg[ll]*sE[s*64+ll];
    sZ[s*ST+ll] = a;
  }
  __syncthreads();
  float accel = 0.f;
  for (int nc = 0; nc < 4; ++nc) {
    for (int i = tid; i < 4096; i += 256) sC[(i>>6)*ST+(i&63)] = Cg[nc*4096+i];
    __syncthreads();
#pragma unroll
    for (int p = 0; p < 2; ++p) {
      const int idx = p*256 + tid;
      const int s = idx >> 6, rn = idx & 63;
      const int nn2 = nc*64 + rn;
      float lr = sbr[nn2];
      for (int ll = 0; ll < 64; ++ll) lr += sZ[s*ST+ll]*sC[rn*ST+ll];
      accel += sy[nn2]*lr - expf(lr);
    }
    __syncthreads();
  }
  red[tid] = accel;
  __syncthreads();
  for (int s2 = 128; s2 > 0; s2 >>= 1) {
    if (tid < s2) red[tid] += red[tid+s2];
    __syncthreads();
  }
  if (tid == 0) val_g[bt] = klv - red[0]*(1.0f/NS_);
}

// ---------------- K6: final reduction (+diag channel) ----------------
__global__ __launch_bounds__(256) void reduce_kernel(const float* __restrict__ val,
                                                     const float* __restrict__ diagv,
                                                     float* __restrict__ out)
{
  __shared__ float red[256];
  float acc = 0.f;
  for (int i = threadIdx.x; i < B_*T_; i += 256) acc += val[i];
  red[threadIdx.x] = acc;
  __syncthreads();
  for (int s2 = 128; s2 > 0; s2 >>= 1) {
    if (threadIdx.x < s2) red[threadIdx.x] += red[threadIdx.x+s2];
    __syncthreads();
  }
  if (threadIdx.x == 0) out[0] = red[0] / (float)B_ + diagv[0];
}

__global__ void diag_kernel(float* out, float v)
{
  if (threadIdx.x == 0) out[0] = v;
}

extern "C" void kernel_launch(void* const* d_in, const int* in_sizes, int n_in,
                              void* d_out, int out_size, void* d_ws, size_t ws_size,
                              hipStream_t stream)
{
  const float* y    = (const float*)d_in[0];
  const float* eps  = (const float*)d_in[1];
  const float* W1   = (const float*)d_in[2];
  const float* b1   = (const float*)d_in[3];
  const float* W2   = (const float*)d_in[4];
  const float* b2   = (const float*)d_in[5];
  const float* F    = (const float*)d_in[6];
  const float* logQ = (const float*)d_in[7];
  const float* logQ0= (const float*)d_in[8];
  const float* m0   = (const float*)d_in[9];
  const float* C    = (const float*)d_in[10];
  const float* br   = (const float*)d_in[11];
  (void)in_sizes; (void)n_in; (void)out_size;

  char* ws = (char*)d_ws;
  float* out = (float*)d_out;

  auto al = [](size_t x){ return (x + 255) & ~(size_t)255; };
  size_t o = 0;
  float* ky    = (float*)(ws + o); o = al(o + (size_t)B_*T_*64*4);
  float* mf    = (float*)(ws + o); o = al(o + (size_t)B_*T_*64*4);
  float* mp    = (float*)(ws + o); o = al(o + (size_t)B_*T_*64*4);
  float* msb   = (float*)(ws + o); o = al(o + (size_t)B_*T_*64*4);
  float* dv    = (float*)(ws + o); o = al(o + (size_t)B_*T_*64*4);
  float* dpart = (float*)(ws + o); o = al(o + (size_t)B_*T_*4);
  float* val   = (float*)(ws + o); o = al(o + (size_t)B_*T_*4);
  float* Kx    = (float*)(ws + o); o = al(o + (size_t)B_*T_*1024*4);
  float* A1    = (float*)(ws + o); o = al(o + (size_t)B_*T_*4096*4);   // Pf -> G
  float* Cpk   = (float*)(ws + o); o = al(o + (size_t)B_*T_*PKN*4);    // c -> Ps packed
  float* Gseg  = (float*)(ws + o); o = al(o + (size_t)B_*NSEG*4096*4);
  float* cseg  = (float*)(ws + o); o = al(o + (size_t)B_*NSEG*PKN*4);
  float* dseg  = (float*)(ws + o); o = al(o + (size_t)B_*NSEG*64*4);
  float* InP   = (float*)(ws + o); o = al(o + (size_t)B_*NSEG*PKN*4);
  float* Inm   = (float*)(ws + o); o = al(o + (size_t)B_*NSEG*64*4);
  float* mfT   = (float*)(ws + o); o = al(o + (size_t)B_*64*4);
  float* diagv = (float*)(ws + o); o = al(o + 256);
  float* h     = A1;   // MLP hidden aliases A1; dead before filter writes

  // Scan buffers ALIAS the Cpk region (Cpk first written by gains, which runs
  // after fcompose/fboundary/fdiag complete; stream-ordered -> no overlap).
  // Need 4*4096*B_*NSEG*4 + 3*64*B_*NSEG*4 ~= 16.2MB << 65MB Cpk region.
  {
    size_t oo = 0;
    (void)oo;
  }
  float* Aseg  = Cpk;
  float* Cseg2 = Aseg  + (size_t)B_*NSEG*4096;
  float* Jseg  = Cseg2 + (size_t)B_*NSEG*4096;
  float* BPC   = Jseg  + (size_t)B_*NSEG*4096;
  float* bsegA = BPC   + (size_t)B_*NSEG*4096;
  float* etaA  = bsegA + (size_t)B_*NSEG*64;
  float* BPm   = etaA  + (size_t)B_*NSEG*64;

  if (ws_size < o) {
    diag_kernel<<<1, 64, 0, stream>>>(out, (float)((double)ws_size / 1048576.0));
    return;
  }

  dim3 blk(256);
  gemm_kernel<true,false><<<dim3(H_/64, (B_*T_)/64), blk, 0, stream>>>(
      y, W1, b1, h, (float*)nullptr, B_*T_, H_, N_);
  gemm_kernel<false,true><<<dim3((L_+L_*R_)/64, (B_*T_)/64), blk, 0, stream>>>(
      h, W2, b2, ky, Kx, B_*T_, L_+L_*R_, H_);
  // proven sequential filter (authoritative outputs)
  filter_kernel<<<B_, blk, 0, stream>>>(ky, Kx, F, logQ, logQ0, m0,
                                        mf, mp, A1, dpart, mfT);
  // scan (diagnostic only; outputs live in Cpk region, dead before gains)
  fcompose_kernel<<<B_*NSEG, blk, FC_LDS, stream>>>(
      ky, Kx, F, logQ, logQ0, m0, Aseg, Cseg2, Jseg, bsegA, etaA, BPm, BPC);
  fboundary_kernel<<<B_, blk, FB_LDS, stream>>>(
      Aseg, Cseg2, Jseg, bsegA, etaA, BPm, BPC);
  fdiag_kernel<<<1, blk, 0, stream>>>(BPm, BPC, mf, A1, diagv);
  // downstream (round-8 proven) — gains overwrites the Cpk/scan region
  gains_kernel<<<B_*(T_-1), blk, 0, stream>>>(F, logQ, mf, mp, A1, Cpk, dv, dpart);
  compose_kernel<<<B_*NSEG, blk, 65536 + 8320 + 1024 + 256 + 64, stream>>>(
      A1, Cpk, dv, Gseg, cseg, dseg);
  boundary_kernel<<<B_, blk, 0, stream>>>(A1, mfT, Gseg, cseg, dseg, InP, Inm);
  expand_kernel<<<B_*NSEG, blk, 0, stream>>>(A1, Cpk, dv, InP, Inm, msb);
  klell_kernel<<<B_*T_, blk, 0, stream>>>(y, eps, ky, Kx, C, br, Cpk, msb, dpart, val);
  reduce_kernel<<<1, blk, 0, stream>>>(val, diagv, (float*)d_out);
}

// Round 13
// 5884.106 us; speedup vs baseline: 1.7259x; 1.7259x over previous
//
#include <hip/hip_runtime.h>
#include <math.h>

#define B_ 32
#define T_ 256
#define N_ 256
#define L_ 64
#define R_ 16
#define H_ 256
#define NS_ 8
#define SEG 32
#define NSEG 8
#define ST 65
#define STM 67
#define STF 68
#define SBF 72
#define SU 20
#define SU2 21
#define PKN 2080
#define PIDX(i,j) ((((i)*((i)+1))>>1) + (j))

using f32x4  = __attribute__((ext_vector_type(4))) float;
using bf16x8 = __attribute__((ext_vector_type(8))) short;
using s16x4  = __attribute__((ext_vector_type(4))) short;

__device__ __forceinline__ float softplus_f(float x) { return log1pf(expf(x)); }

__device__ __forceinline__ void splitbf(float x, short& h, short& l)
{
  unsigned u = __float_as_uint(x);
  unsigned hu = (u + 0x7FFFu + ((u>>16)&1u)) & 0xFFFF0000u;
  float hf = __uint_as_float(hu);
  float r = x - hf;
  unsigned ur = __float_as_uint(r);
  unsigned lu = (ur + 0x7FFFu + ((ur>>16)&1u)) >> 16;
  h = (short)(hu>>16); l = (short)lu;
}
__device__ __forceinline__ void splitbf4(const float4& v, s16x4& h4, s16x4& l4)
{
  short h, l;
  splitbf(v.x, h, l); h4[0] = h; l4[0] = l;
  splitbf(v.y, h, l); h4[1] = h; l4[1] = l;
  splitbf(v.z, h, l); h4[2] = h; l4[2] = l;
  splitbf(v.w, h, l); h4[3] = h; l4[3] = l;
}
__device__ __forceinline__ float bf2f(short s)
{ return __uint_as_float(((unsigned)(unsigned short)s)<<16); }

template<int SB>
__device__ __forceinline__ void mfma_mm64(const short* Ah, const short* Al,
                                          const short* Bh, const short* Bl,
                                          int w, int l, f32x4 acc[4])
{
  const int lr = l & 15, lg = l >> 4;
  const int arow = (w*16+lr)*SB;
#pragma unroll
  for (int ks = 0; ks < 2; ++ks) {
    const int ko = ks*32 + lg*8;
    bf16x8 ah = *(const bf16x8*)&Ah[arow + ko];
    bf16x8 al = *(const bf16x8*)&Al[arow + ko];
#pragma unroll
    for (int ct = 0; ct < 4; ++ct) {
      bf16x8 bh = *(const bf16x8*)&Bh[(ct*16+lr)*SB + ko];
      bf16x8 bl = *(const bf16x8*)&Bl[(ct*16+lr)*SB + ko];
      acc[ct] = __builtin_amdgcn_mfma_f32_16x16x32_bf16(ah, bh, acc[ct], 0,0,0);
      acc[ct] = __builtin_amdgcn_mfma_f32_16x16x32_bf16(ah, bl, acc[ct], 0,0,0);
      acc[ct] = __builtin_amdgcn_mfma_f32_16x16x32_bf16(al, bh, acc[ct], 0,0,0);
    }
  }
}

template<int LDA, int LDB, int LDC, bool TB>
__device__ __forceinline__ void mm64f(const float* A, const float* Bm, float* C, int tid)
{
  const int rg = tid >> 4, cg = tid & 15;
  float acc[4][4] = {{0.f}};
#pragma unroll 2
  for (int k = 0; k < 64; ++k) {
    float a[4], bb[4];
#pragma unroll
    for (int i = 0; i < 4; ++i) a[i] = A[(rg*4+i)*LDA + k];
#pragma unroll
    for (int j = 0; j < 4; ++j) bb[j] = TB ? Bm[(cg*4+j)*LDB + k] : Bm[k*LDB + (cg*4+j)];
#pragma unroll
    for (int i = 0; i < 4; ++i)
#pragma unroll
      for (int j = 0; j < 4; ++j) acc[i][j] += a[i]*bb[j];
  }
#pragma unroll
  for (int i = 0; i < 4; ++i)
#pragma unroll
    for (int j = 0; j < 4; ++j) C[(rg*4+i)*LDC + (cg*4+j)] = acc[i][j];
}

template<int SA>
__device__ __forceinline__ void chol64_blk(float* A, float* rdiag, float* dg, int tid)
{
#pragma unroll
  for (int kb = 0; kb < 4; ++kb) {
    const int o = kb*16;
    if (tid < 16) {
      const int ln = tid;
      float s[16];
#pragma unroll
      for (int j = 0; j < 16; ++j) s[j] = A[(o+ln)*SA + o + j];
#pragma unroll
      for (int k = 0; k < 16; ++k) {
        const float dk = fmaxf(__shfl(s[k], k, 64), 1e-30f);
        const float d = sqrtf(dk);
        const float rd = 1.f/d;
        const float lik = s[k]*rd;
        if (ln == k) { rdiag[o+k] = rd; if (dg) dg[o+k] = d; }
#pragma unroll
        for (int j = 0; j < 16; ++j) {
          const float ljk = __shfl(lik, j, 64);
          if (j > k && j <= ln) s[j] -= lik*ljk;
        }
        if (ln > k) s[k] = lik;
        else if (ln == k) s[k] = dk;
      }
#pragma unroll
      for (int j = 0; j < 16; ++j) A[(o+ln)*SA + o + j] = s[j];
    }
    __syncthreads();
    const int nr = 48 - o;
    if (nr > 0) {
      if (tid < nr) {
        const int r = o + 16 + tid;
        float x[16];
#pragma unroll
        for (int q = 0; q < 16; ++q) x[q] = A[r*SA + o + q];
#pragma unroll
        for (int j = 0; j < 16; ++j) {
          x[j] *= rdiag[o+j];
#pragma unroll
          for (int i2 = j+1; i2 < 16; ++i2) x[i2] -= A[(o+i2)*SA + o + j] * x[j];
        }
#pragma unroll
        for (int q = 0; q < 16; ++q) A[r*SA + o + q] = x[q];
      }
      __syncthreads();
      const int tot = nr*nr;
      for (int idx = tid; idx < tot; idx += 256) {
        const int i = o + 16 + idx / nr, j = o + 16 + idx % nr;
        float acc = A[i*SA + j];
#pragma unroll
        for (int k = 0; k < 16; ++k) acc -= A[i*SA + o + k] * A[j*SA + o + k];
        A[i*SA + j] = acc;
      }
      __syncthreads();
    }
  }
}

__device__ __forceinline__ void fwd16(float* x, const float* sS, const float* sSd)
{
#pragma unroll
  for (int a = 0; a < 16; ++a) {
    x[a] *= sSd[a];
#pragma unroll
    for (int i = a+1; i < 16; ++i) x[i] -= sS[i*17+a]*x[a];
  }
}
__device__ __forceinline__ void solve16(float* x, const float* sS, const float* sSd)
{
#pragma unroll
  for (int a = 0; a < 16; ++a) {
    x[a] *= sSd[a];
#pragma unroll
    for (int i = a+1; i < 16; ++i) x[i] -= sS[i*17+a]*x[a];
  }
#pragma unroll
  for (int a = 15; a >= 0; --a) {
    x[a] *= sSd[a];
#pragma unroll
    for (int i = 0; i < a; ++i) x[i] -= sS[a*17+i]*x[a];
  }
}
__device__ __forceinline__ void chol16_sh(float* sS, float* sSd, int tid)
{
  if (tid < 16) {
    const int ln = tid;
    float s[16];
#pragma unroll
    for (int j = 0; j < 16; ++j) s[j] = sS[ln*17+j];
#pragma unroll
    for (int k = 0; k < 16; ++k) {
      const float dk = fmaxf(__shfl(s[k], k, 64), 1e-30f);
      const float d = sqrtf(dk);
      const float rd = 1.f/d;
      const float lik = s[k]*rd;
      if (ln == k) sSd[k] = rd;
#pragma unroll
      for (int j = 0; j < 16; ++j) {
        const float ljk = __shfl(lik, j, 64);
        if (j > k && j <= ln) s[j] -= lik*ljk;
      }
      if (ln > k) s[k] = lik;
      else if (ln == k) s[k] = d;
    }
#pragma unroll
    for (int j = 0; j < 16; ++j) sS[ln*17+j] = s[j];
  }
}

// ---------------- K1: tiled fp32 GEMM ----------------
template<bool TANH, bool SPLIT>
__global__ __launch_bounds__(256) void gemm_kernel(
    const float* __restrict__ A, const float* __restrict__ Bw,
    const float* __restrict__ bias, float* __restrict__ C1,
    float* __restrict__ C2, int M, int Nn, int Kk)
{
  __shared__ float As[16][65];
  __shared__ float Bs[16][64];
  const int bm = blockIdx.y * 64, bn = blockIdx.x * 64;
  const int tid = threadIdx.x;
  const int rg = tid >> 4, cg = tid & 15;
  float acc[4][4] = {{0.f}};
  for (int k0 = 0; k0 < Kk; k0 += 16) {
    {
      const int kk = tid & 15, r0 = tid >> 4;
#pragma unroll
      for (int rr = 0; rr < 4; ++rr)
        As[kk][r0 + 16*rr] = A[(size_t)(bm + r0 + 16*rr) * Kk + k0 + kk];
    }
    {
      const int cc = tid & 63, kk = tid >> 6;
#pragma unroll
      for (int kr = 0; kr < 4; ++kr)
        Bs[kk + 4*kr][cc] = Bw[(size_t)(k0 + kk + 4*kr) * Nn + bn + cc];
    }
    __syncthreads();
#pragma unroll
    for (int k = 0; k < 16; ++k) {
      float a[4], bb[4];
#pragma unroll
      for (int i = 0; i < 4; ++i) a[i] = As[k][rg*4+i];
#pragma unroll
      for (int j = 0; j < 4; ++j) bb[j] = Bs[k][cg*4+j];
#pragma unroll
      for (int i = 0; i < 4; ++i)
#pragma unroll
        for (int j = 0; j < 4; ++j) acc[i][j] += a[i]*bb[j];
    }
    __syncthreads();
  }
#pragma unroll
  for (int i = 0; i < 4; ++i) {
    const int row = bm + rg*4 + i;
#pragma unroll
    for (int j = 0; j < 4; ++j) {
      const int col = bn + cg*4 + j;
      float v = acc[i][j] + bias[col];
      if (TANH) v = tanhf(v);
      if (SPLIT) {
        if (col < 64) C1[(size_t)row*64 + col] = v;
        else          C2[(size_t)row*1024 + (col-64)] = v;
      } else {
        C1[(size_t)row*Nn + col] = v;
      }
    }
  }
}

// ============ Parallel Kalman filter scan (PRODUCTION) ============
#define FC_LDS 132096
__global__ __launch_bounds__(256, 1) void fcompose_kernel(
    const float* __restrict__ kyg, const float* __restrict__ Kxg,
    const float* __restrict__ Fg, const float* __restrict__ logQ,
    const float* __restrict__ logQ0, const float* __restrict__ m0g,
    float* __restrict__ Aseg, float* __restrict__ Cseg, float* __restrict__ Jseg,
    float* __restrict__ bseg, float* __restrict__ etaseg,
    float* __restrict__ BPm, float* __restrict__ BPC)
{
  const int blk = blockIdx.x, tid = threadIdx.x;
  const int b = blk >> 3, s = blk & 7;
  if (s == 7) return;

  extern __shared__ __align__(16) char fcm[];
  float* F_  = (float*)fcm;
  float* mA  = F_  + 64*ST;
  float* mC  = mA  + 64*ST;
  float* mJ  = mC  + 64*ST;
  float* mT  = mJ  + 64*ST;
  float* sKf = mT  + 64*ST;
  float* sW  = sKf + 64*SU2;
  float* sP  = sW  + 64*SU2;
  float* sTb = sP  + 64*SU2;
  float* sK2 = sTb + 64*SU2;
  float* sR  = sK2 + 64*SU2;
  float* sZW = sR  + 64*SU2;
  float* sG  = sZW + 64*SU2;
  float* sS2 = sG  + 16*68;
  float* sS3 = sS2 + 16*17;
  float* sSd2= sS3 + 16*17;
  float* sSd3= sSd2 + 16;
  float* vq  = sSd3 + 16;
  float* vb  = vq  + 64;
  float* veta= vb  + 64;
  float* vk  = veta+ 64;
  float* vz1 = vk  + 64;
  float* vt1 = vz1 + 64;
  float* vt2 = vt1 + 64;
  float* vu  = vt2 + 64;
  float* vg  = vu  + 64;
  float* vhg = vg  + 64;
  float* vmu = vhg + 64;
  float* vg2 = vmu + 64;
  float* vet3= vg2 + 64;
  float* vb2 = vet3+ 64;
  float* vmp = vb2 + 64;
  float* v16 = vmp + 64;

  for (int i = tid; i < 4096; i += 256) F_[(i>>6)*ST + (i&63)] = Fg[i];
  if (tid < 64) vq[tid] = softplus_f(logQ[tid]);
  __syncthreads();

#define STAGE_K(bt)                                                        \
  { float4 k4 = ((const float4*)(Kxg + (bt)*1024))[tid];                   \
    const int row = tid>>2, c0 = (tid&3)*4;                                \
    sKf[row*SU2+c0+0]=k4.x; sKf[row*SU2+c0+1]=k4.y;                        \
    sKf[row*SU2+c0+2]=k4.z; sKf[row*SU2+c0+3]=k4.w;                        \
    if (tid < 64) { vk[tid] = kyg[(bt)*64+tid]; vz1[tid]=vq[tid]*vk[tid]; } }

  if (s == 0) {
    if (tid < 64) { vmp[tid] = m0g[tid]; vt1[tid] = softplus_f(logQ0[tid]); }
    __syncthreads();
    for (int t = 0; t < SEG; ++t) {
      const size_t bt = (size_t)b*T_ + t;
      if (t == 0) {
        for (int i = tid; i < 4096; i += 256) {
          const int r = i>>6, c = i&63;
          mC[r*ST+c] = (r==c) ? vt1[r] : 0.f;
        }
      } else {
        mm64f<ST,ST,ST,false>(F_, mC, mT, tid);
        __syncthreads();
        mm64f<ST,ST,ST,true>(mT, F_, mC, tid);
        if (tid < 64) {
          float a = 0.f;
          for (int j = 0; j < 64; ++j) a += F_[tid*ST+j]*vb[j];
          vmp[tid] = a;
        }
        __syncthreads();
        if (tid < 64) mC[tid*ST+tid] += vq[tid];
      }
      STAGE_K(bt);
      __syncthreads();
      { const int i6 = tid & 63, rq = tid >> 6;
        float u[4] = {0,0,0,0};
        for (int j = 0; j < 64; ++j) {
          const float p = mC[i6*ST+j];
#pragma unroll
          for (int r = 0; r < 4; ++r) u[r] += p*sKf[j*SU2+rq*4+r];
        }
#pragma unroll
        for (int r = 0; r < 4; ++r) sP[i6*SU2+rq*4+r] = u[r];
      }
      __syncthreads();
      { const int a = tid>>4, c = tid&15;
        float sv = (a==c) ? 1.f : 0.f;
        for (int i = 0; i < 64; ++i) sv += sKf[i*SU2+a]*sP[i*SU2+c];
        sS2[a*17+c] = sv;
      }
      __syncthreads();
      chol16_sh(sS2, sSd2, tid);
      if (tid >= 64 && tid < 80) {
        const int r = tid-64;
        float a = 0.f;
        for (int i = 0; i < 64; ++i) a += sKf[i*SU2+r]*vmp[i];
        v16[r] = a;
      }
      __syncthreads();
      if (tid < 64) {
        float x[16];
#pragma unroll
        for (int r = 0; r < 16; ++r) x[r] = sP[tid*SU2+r];
        fwd16(x, sS2, sSd2);
#pragma unroll
        for (int r = 0; r < 16; ++r) sTb[tid*SU2+r] = x[r];
      } else if (tid == 64) {
        float x[16];
#pragma unroll
        for (int r = 0; r < 16; ++r) x[r] = v16[r];
        fwd16(x, sS2, sSd2);
#pragma unroll
        for (int r = 0; r < 16; ++r) v16[r] = x[r];
      }
      __syncthreads();
      for (int idx = tid; idx < 4096; idx += 256) {
        const int i = idx>>6, j = idx&63;
        float a = mC[i*ST+j];
#pragma unroll
        for (int r = 0; r < 16; ++r) a -= sTb[i*SU2+r]*sTb[j*SU2+r];
        mC[i*ST+j] = a;
      }
      __syncthreads();
      if (tid < 64) {
        float a = vmp[tid];
#pragma unroll
        for (int r = 0; r < 16; ++r) a -= sTb[tid*SU2+r]*v16[r];
        for (int j = 0; j < 64; ++j) a += mC[tid*ST+j]*vk[j];
        vb[tid] = a;
      }
      __syncthreads();
    }
    if (tid < 64) BPm[((size_t)b*NSEG + 1)*64 + tid] = vb[tid];
    for (int i = tid; i < 4096; i += 256)
      BPC[((size_t)b*NSEG + 1)*4096 + i] = mC[(i>>6)*ST + (i&63)];
    return;
  }

  const int t0 = s*SEG;
  {
    const size_t bt = (size_t)b*T_ + t0;
    STAGE_K(bt);
    __syncthreads();
    { const int a = tid>>4, c = tid&15;
      float sv = (a==c) ? 1.f : 0.f;
      for (int j = 0; j < 64; ++j) sv += sKf[j*SU2+a]*vq[j]*sKf[j*SU2+c];
      sS2[a*17+c] = sv;
    }
    { const int i6 = tid & 63, rq = tid >> 6;
      float u[4] = {0,0,0,0};
      for (int j = 0; j < 64; ++j) {
        const float fv = F_[j*ST+i6];
#pragma unroll
        for (int r = 0; r < 4; ++r) u[r] += fv*sKf[j*SU2+rq*4+r];
      }
#pragma unroll
      for (int r = 0; r < 4; ++r) sW[i6*SU2+rq*4+r] = u[r];
    }
    __syncthreads();
    chol16_sh(sS2, sSd2, tid);
    __syncthreads();
    if (tid < 64) {
      float x[16];
#pragma unroll
      for (int r = 0; r < 16; ++r) x[r] = vq[tid]*sKf[tid*SU2+r];
      fwd16(x, sS2, sSd2);
#pragma unroll
      for (int r = 0; r < 16; ++r) sK2[tid*SU2+r] = x[r];
    } else if (tid < 128) {
      const int i = tid-64;
      float x[16];
#pragma unroll
      for (int r = 0; r < 16; ++r) x[r] = sW[i*SU2+r];
      fwd16(x, sS2, sSd2);
#pragma unroll
      for (int r = 0; r < 16; ++r) sR[i*SU2+r] = x[r];
    } else if (tid < 192) {
      const int i = tid-128;
      float x[16];
#pragma unroll
      for (int r = 0; r < 16; ++r) x[r] = sW[i*SU2+r];
      solve16(x, sS2, sSd2);
#pragma unroll
      for (int r = 0; r < 16; ++r) sTb[i*SU2+r] = x[r];
    } else if (tid < 208) {
      const int r = tid-192;
      float a = 0.f;
      for (int i = 0; i < 64; ++i) a += sKf[i*SU2+r]*vz1[i];
      v16[r] = a;
    }
    __syncthreads();
    for (int idx = tid; idx < 4096; idx += 256) {
      const int i = idx>>6, j = idx&63;
      float a1 = F_[i*ST+j];
      float a2 = (i==j) ? vq[i] : 0.f;
      float a3 = 0.f;
#pragma unroll
      for (int r = 0; r < 16; ++r) {
        a1 -= vq[i]*sKf[i*SU2+r]*sTb[j*SU2+r];
        a2 -= sK2[i*SU2+r]*sK2[j*SU2+r];
        a3 += sR[i*SU2+r]*sR[j*SU2+r];
      }
      mA[i*ST+j] = a1; mC[i*ST+j] = a2; mJ[i*ST+j] = a3;
    }
    if (tid == 0) {
      float x[16];
#pragma unroll
      for (int r = 0; r < 16; ++r) x[r] = v16[r];
      solve16(x, sS2, sSd2);
#pragma unroll
      for (int r = 0; r < 16; ++r) v16[r] = x[r];
    }
    __syncthreads();
    if (tid >= 64 && tid < 80) {
      const int r = tid-64;
      float a = 0.f;
      for (int i = 0; i < 64; ++i) a += sK2[i*SU2+r]*vk[i];
      v16[16+r] = a;
    }
    if (tid < 64) {
      float t = vk[tid];
#pragma unroll
      for (int r = 0; r < 16; ++r) t -= sKf[tid*SU2+r]*v16[r];
      vt1[tid] = t;
    }
    __syncthreads();
    if (tid < 64) {
      float e = 0.f;
      for (int i = 0; i < 64; ++i) e += F_[i*ST+tid]*vt1[i];
      veta[tid] = e;
      float bb = vz1[tid];
#pragma unroll
      for (int r = 0; r < 16; ++r) bb -= sK2[tid*SU2+r]*v16[16+r];
      vb[tid] = bb;
    }
    __syncthreads();
  }

  for (int tt = t0+1; tt < t0+SEG; ++tt) {
    const size_t bt = (size_t)b*T_ + tt;
    STAGE_K(bt);
    __syncthreads();
    { const int a = tid>>4, c = tid&15;
      float sv = (a==c) ? 1.f : 0.f;
      for (int j = 0; j < 64; ++j) sv += sKf[j*SU2+a]*vq[j]*sKf[j*SU2+c];
      sS2[a*17+c] = sv; sS3[a*17+c] = sv;
    }
    __syncthreads();
    { const int i6 = tid & 63, rq = tid >> 6;
      float u[4] = {0,0,0,0};
      for (int j = 0; j < 64; ++j) {
        const float fv = F_[j*ST+i6];
#pragma unroll
        for (int r = 0; r < 4; ++r) u[r] += fv*sKf[j*SU2+rq*4+r];
      }
#pragma unroll
      for (int r = 0; r < 4; ++r) sW[i6*SU2+rq*4+r] = u[r];
    }
    __syncthreads();
    chol16_sh(sS2, sSd2, tid);
    if (tid >= 64 && tid < 80) {
      const int r = tid-64;
      float a = 0.f;
      for (int i = 0; i < 64; ++i) a += sKf[i*SU2+r]*vz1[i];
      v16[r] = a;
    } else if (tid >= 80 && tid < 96) {
      const int r = tid-80;
      float a = 0.f;
      for (int i = 0; i < 64; ++i) a += sW[i*SU2+r]*vb[i];
      v16[16+r] = a;
    }
    __syncthreads();
    if (tid < 64) {
      float x[16];
#pragma unroll
      for (int r = 0; r < 16; ++r) x[r] = vq[tid]*sKf[tid*SU2+r];
      fwd16(x, sS2, sSd2);
#pragma unroll
      for (int r = 0; r < 16; ++r) sK2[tid*SU2+r] = x[r];
    } else if (tid == 64) {
      float x[16];
#pragma unroll
      for (int r = 0; r < 16; ++r) x[r] = v16[r];
      solve16(x, sS2, sSd2);
#pragma unroll
      for (int r = 0; r < 16; ++r) v16[r] = x[r];
    } else if (tid == 65) {
      float x[16];
#pragma unroll
      for (int r = 0; r < 16; ++r) x[r] = v16[16+r];
      solve16(x, sS2, sSd2);
#pragma unroll
      for (int r = 0; r < 16; ++r) v16[16+r] = x[r];
    }
    __syncthreads();
    { const int i6 = tid & 63, rq = tid >> 6;
      float u[4] = {0,0,0,0};
      for (int j = 0; j < 64; ++j) {
        const float p = mC[i6*ST+j];
#pragma unroll
        for (int r = 0; r < 4; ++r) u[r] += p*sW[j*SU2+rq*4+r];
      }
#pragma unroll
      for (int r = 0; r < 4; ++r) sP[i6*SU2+rq*4+r] = u[r];
    }
    __syncthreads();
    { const int i6 = tid & 63, rq = tid >> 6;
      float u[4] = {0,0,0,0};
      for (int i = 0; i < 64; ++i) {
        const float av = mA[i*ST+i6];
#pragma unroll
        for (int r = 0; r < 4; ++r) u[r] += av*sW[i*SU2+rq*4+r];
      }
#pragma unroll
      for (int r = 0; r < 4; ++r) sR[i6*SU2+rq*4+r] = u[r];
    }
    __syncthreads();
    { const int a = tid>>4, c = tid&15;
      float sv = 0.f;
      for (int i = 0; i < 64; ++i) sv += sW[i*SU2+a]*sP[i*SU2+c];
      sS3[a*17+c] += sv;
    }
    __syncthreads();
    chol16_sh(sS3, sSd3, tid);
    if (tid >= 64 && tid < 128) {
      const int i = tid-64;
      float t = vk[i];
#pragma unroll
      for (int r = 0; r < 16; ++r) t -= sKf[i*SU2+r]*v16[r];
      vt1[i] = t;
    } else if (tid >= 128 && tid < 144) {
      const int r = tid-128;
      float a = 0.f;
      for (int i = 0; i < 64; ++i) a += sK2[i*SU2+r]*vk[i];
      v16[32+r] = a;
    }
    __syncthreads();
    if (tid < 64) {
      float e = 0.f;
      for (int i = 0; i < 64; ++i) e += F_[i*ST+tid]*vt1[i];
      vt2[tid] = e;
    } else if (tid < 128) {
      const int i = tid-64;
      float bb = vz1[i];
#pragma unroll
      for (int r = 0; r < 16; ++r) bb -= sK2[i*SU2+r]*v16[32+r];
      vb2[i] = bb;
    }
    __syncthreads();
    if (tid < 64) {
      float a = vb[tid];
      for (int j = 0; j < 64; ++j) a += mC[tid*ST+j]*vt2[j];
      vu[tid] = a;
    } else if (tid < 128) {
      const int i = tid-64;
      float a = vt2[i];
#pragma unroll
      for (int r = 0; r < 16; ++r) a -= sW[i*SU2+r]*v16[16+r];
      vg[i] = a;
    }
    __syncthreads();
    if (tid < 64) {
      float a = 0.f;
      for (int j = 0; j < 64; ++j) a += mC[tid*ST+j]*vg[j];
      vhg[tid] = a;
    } else if (tid < 128) {
      const int i = tid-64;
      float x[16];
#pragma unroll
      for (int r = 0; r < 16; ++r) x[r] = sP[i*SU2+r];
      fwd16(x, sS3, sSd3);
#pragma unroll
      for (int r = 0; r < 16; ++r) sTb[i*SU2+r] = x[r];
    } else if (tid < 192) {
      const int i = tid-128;
      float x[16];
#pragma unroll
      for (int r = 0; r < 16; ++r) x[r] = sR[i*SU2+r];
      fwd16(x, sS3, sSd3);
#pragma unroll
      for (int r = 0; r < 16; ++r) sR[i*SU2+r] = x[r];
    } else if (tid < 208) {
      const int r = tid-192;
      float a = 0.f;
      for (int i = 0; i < 64; ++i) a += sW[i*SU2+r]*vu[i];
      v16[48+r] = a;
    }
    __syncthreads();
    if (tid == 0) {
      float x[16];
#pragma unroll
      for (int r = 0; r < 16; ++r) x[r] = v16[48+r];
      solve16(x, sS3, sSd3);
#pragma unroll
      for (int r = 0; r < 16; ++r) v16[48+r] = x[r];
    } else if (tid >= 64 && tid < 80) {
      const int r = tid-64;
      float a = 0.f;
      for (int i = 0; i < 64; ++i) a += sW[i*SU2+r]*vhg[i];
      v16[64+r] = a;
    }
    __syncthreads();
    if (tid == 0) {
      float x[16];
#pragma unroll
      for (int r = 0; r < 16; ++r) x[r] = v16[64+r];
      solve16(x, sS3, sSd3);
#pragma unroll
      for (int r = 0; r < 16; ++r) v16[64+r] = x[r];
    } else if (tid >= 64 && tid < 128) {
      const int i = tid-64;
      float a = vu[i];
#pragma unroll
      for (int r = 0; r < 16; ++r) a -= sP[i*SU2+r]*v16[48+r];
      vmu[i] = a;
    }
    __syncthreads();
    if (tid < 64) {
      float a = vg[tid];
#pragma unroll
      for (int r = 0; r < 16; ++r) a -= sW[tid*SU2+r]*v16[64+r];
      vg2[tid] = a;
    } else if (tid < 80) {
      const int r = tid-64;
      float a = 0.f;
      for (int i = 0; i < 64; ++i) a += sW[i*SU2+r]*vmu[i];
      v16[80+r] = a;
    }
    __syncthreads();
    if (tid < 64) {
      float a = veta[tid];
      for (int i = 0; i < 64; ++i) a += mA[i*ST+tid]*vg2[i];
      vet3[tid] = a;
    } else if (tid == 64) {
      float x[16];
#pragma unroll
      for (int r = 0; r < 16; ++r) x[r] = v16[80+r];
      solve16(x, sS2, sSd2);
#pragma unroll
      for (int r = 0; r < 16; ++r) v16[80+r] = x[r];
    }
    __syncthreads();
    if (tid < 64) {
      float a = vb2[tid];
      for (int j = 0; j < 64; ++j) a += F_[tid*ST+j]*vmu[j];
#pragma unroll
      for (int r = 0; r < 16; ++r) a -= vq[tid]*sKf[tid*SU2+r]*v16[80+r];
      vb[tid] = a;
    } else if (tid < 128) {
      veta[tid-64] = vet3[tid-64];
    }
    __syncthreads();
    for (int idx = tid; idx < 4096; idx += 256) {
      const int i = idx>>6, j = idx&63;
      float aj = 0.f, ac = 0.f;
#pragma unroll
      for (int r = 0; r < 16; ++r) {
        aj += sR[i*SU2+r]*sR[j*SU2+r];
        ac += sTb[i*SU2+r]*sTb[j*SU2+r];
      }
      mJ[i*ST+j] += aj;
      mC[i*ST+j] -= ac;
    }
    __syncthreads();
    for (int idx = tid; idx < 4096; idx += 256) {
      const int i = idx>>6, j = idx&63;
      float a = mA[i*ST+j];
#pragma unroll
      for (int r = 0; r < 16; ++r) a -= sTb[i*SU2+r]*sR[j*SU2+r];
      mA[i*ST+j] = a;
    }
    __syncthreads();
    mm64f<ST,ST,ST,false>(F_, mA, mT, tid);
    __syncthreads();
    { for (int e = 0; e < 4; ++e) {
        const int r = tid & 15, j = (tid>>4)*4 + e;
        float a = 0.f;
        for (int i = 0; i < 64; ++i) a += sW[i*SU2+r]*mA[i*ST+j];
        sG[r*68+j] = a;
      } }
    __syncthreads();
    if (tid < 64) {
      float x[16];
#pragma unroll
      for (int r = 0; r < 16; ++r) x[r] = sG[r*68+tid];
      solve16(x, sS2, sSd2);
#pragma unroll
      for (int r = 0; r < 16; ++r) sG[r*68+tid] = x[r];
    }
    __syncthreads();
    for (int idx = tid; idx < 4096; idx += 256) {
      const int i = idx>>6, j = idx&63;
      float a = mT[i*ST+j];
#pragma unroll
      for (int r = 0; r < 16; ++r) a -= vq[i]*sKf[i*SU2+r]*sG[r*68+j];
      mA[i*ST+j] = a;
    }
    __syncthreads();
    { for (int e = 0; e < 4; ++e) {
        const int r = tid & 15, j = (tid>>4)*4 + e;
        float a = 0.f;
        for (int i = 0; i < 64; ++i) a += sW[i*SU2+r]*mC[i*ST+j];
        sG[r*68+j] = a;
      } }
    __syncthreads();
    if (tid < 64) {
      float x[16];
#pragma unroll
      for (int r = 0; r < 16; ++r) x[r] = sG[r*68+tid];
      solve16(x, sS2, sSd2);
#pragma unroll
      for (int r = 0; r < 16; ++r) sG[r*68+tid] = x[r];
    }
    __syncthreads();
    mm64f<ST,ST,ST,false>(F_, mC, mT, tid);
    __syncthreads();
    for (int idx = tid; idx < 4096; idx += 256) {
      const int i = idx>>6, j = idx&63;
      float a = mT[i*ST+j];
#pragma unroll
      for (int r = 0; r < 16; ++r) a -= vq[i]*sKf[i*SU2+r]*sG[r*68+j];
      mT[i*ST+j] = a;
    }
    __syncthreads();
    mm64f<ST,ST,ST,true>(mT, F_, mC, tid);
    __syncthreads();
    { const int i6 = tid & 63, rq = tid >> 6;
      float u[4] = {0,0,0,0};
      for (int j = 0; j < 64; ++j) {
        const float z = mT[i6*ST+j];
#pragma unroll
        for (int r = 0; r < 4; ++r) u[r] += z*sW[j*SU2+rq*4+r];
      }
#pragma unroll
      for (int r = 0; r < 4; ++r) sZW[i6*SU2+rq*4+r] = u[r];
    }
    __syncthreads();
    if (tid < 64) {
      float x[16];
#pragma unroll
      for (int r = 0; r < 16; ++r) x[r] = sZW[tid*SU2+r];
      solve16(x, sS2, sSd2);
#pragma unroll
      for (int r = 0; r < 16; ++r) sZW[tid*SU2+r] = x[r];
    }
    __syncthreads();
    for (int idx = tid; idx < 4096; idx += 256) {
      const int i = idx>>6, j = idx&63;
      float a = mC[i*ST+j] + ((i==j) ? vq[i] : 0.f);
#pragma unroll
      for (int r = 0; r < 16; ++r) {
        a -= sZW[i*SU2+r]*vq[j]*sKf[j*SU2+r];
        a -= sK2[i*SU2+r]*sK2[j*SU2+r];
      }
      mC[i*ST+j] = a;
    }
    __syncthreads();
  }
  const size_t so = (size_t)b*NSEG + s;
  for (int i = tid; i < 4096; i += 256) {
    const int r = i>>6, c = i&63;
    Aseg[so*4096+i] = mA[r*ST+c];
    Cseg[so*4096+i] = mC[r*ST+c];
    Jseg[so*4096+i] = mJ[r*ST+c];
  }
  if (tid < 64) { bseg[so*64+tid] = vb[tid]; etaseg[so*64+tid] = veta[tid]; }
#undef STAGE_K
}

#define FB_LDS 103424
__global__ __launch_bounds__(256, 1) void fboundary_kernel(
    const float* __restrict__ Aseg, const float* __restrict__ Cseg,
    const float* __restrict__ Jseg, const float* __restrict__ bseg,
    const float* __restrict__ etaseg,
    float* __restrict__ BPm, float* __restrict__ BPC)
{
  const int b = blockIdx.x, tid = threadIdx.x;
  extern __shared__ __align__(16) char fbm[];
  float* mC1  = (float*)fbm;
  float* mJ2  = mC1 + 64*ST;
  float* mA2  = mJ2 + 64*ST;
  float* mP2T = mA2 + 64*ST;
  float* mS   = mP2T + 64*ST;
  float* mT1  = mS  + 64*ST;
  float* vb1  = mT1 + 64*ST;
  float* vb2  = vb1 + 64;
  float* vet2 = vb2 + 64;
  float* vu2  = vet2 + 64;
  float* zv   = vu2 + 64;
  float* vmu  = zv  + 64;
  float* sDi  = vmu + 64;
  float* vdg  = sDi + 64;
  float* sRed = vdg + 64;

  for (int i = tid; i < 4096; i += 256)
    mC1[(i>>6)*ST + (i&63)] = BPC[((size_t)b*NSEG + 1)*4096 + i];
  if (tid < 64) vb1[tid] = BPm[((size_t)b*NSEG + 1)*64 + tid];
  __syncthreads();

  for (int s = 1; s <= 6; ++s) {
    const size_t so = (size_t)b*NSEG + s;
    for (int i = tid; i < 4096; i += 256) {
      const int r = i>>6, c = i&63;
      mJ2[r*ST+c] = Jseg[so*4096+i];
      mA2[r*ST+c] = Aseg[so*4096+i];
    }
    if (tid < 64) { vb2[tid] = bseg[so*64+tid]; vet2[tid] = etaseg[so*64+tid]; }
    __syncthreads();
    if (tid < 64) {
      float a = vb1[tid];
      for (int j = 0; j < 64; ++j) a += mC1[tid*ST+j]*vet2[j];
      vu2[tid] = a;
      sRed[tid] = mJ2[tid*ST+tid];
    }
    __syncthreads();
    if (tid == 0) {
      float m = 0.f;
      for (int i = 0; i < 64; ++i) m = fmaxf(m, sRed[i]);
      sRed[0] = m;
    }
    __syncthreads();
    if (tid < 64) mJ2[tid*ST+tid] += 1e-5f*sRed[0] + 1e-20f;
    __syncthreads();
    chol64_blk<ST>(mJ2, sDi, vdg, tid);
    for (int idx = tid; idx < 4096; idx += 256) {
      const int i = idx>>6, j = idx&63;
      if (i < j) mJ2[i*ST+j] = 0.f;
      else if (i == j) mJ2[i*ST+i] = vdg[i];
    }
    __syncthreads();
    mm64f<ST,ST,ST,false>(mC1, mJ2, mT1, tid);
    __syncthreads();
    for (int idx = tid; idx < 4096; idx += 256) {
      const int i = idx>>6, j = idx&63;
      mP2T[j*ST+i] = mT1[i*ST+j];
    }
    __syncthreads();
    mm64f<ST,ST,ST,false>(mP2T, mJ2, mS, tid);
    __syncthreads();
    if (tid < 64) {
      mS[tid*ST+tid] += 1.f;
      float a = 0.f;
      for (int i = 0; i < 64; ++i) a += mJ2[i*ST+tid]*vu2[i];
      zv[tid] = a;
    }
    __syncthreads();
    chol64_blk<ST>(mS, sDi, (float*)nullptr, tid);
    // blocked fwd solve on [mP2T | zv]
#pragma unroll
    for (int jb = 0; jb < 4; ++jb) {
      const int o = jb*16;
      if (tid < 64) {
        const int c = tid;
        float x[16];
#pragma unroll
        for (int q = 0; q < 16; ++q) x[q] = mP2T[(o+q)*ST + c];
#pragma unroll
        for (int j = 0; j < 16; ++j) {
          x[j] *= sDi[o+j];
#pragma unroll
          for (int i = j+1; i < 16; ++i) x[i] -= mS[(o+i)*ST + o+j] * x[j];
        }
#pragma unroll
        for (int q = 0; q < 16; ++q) mP2T[(o+q)*ST + c] = x[q];
      } else if (tid == 64) {
        float x[16];
#pragma unroll
        for (int q = 0; q < 16; ++q) x[q] = zv[o+q];
#pragma unroll
        for (int j = 0; j < 16; ++j) {
          x[j] *= sDi[o+j];
#pragma unroll
          for (int i = j+1; i < 16; ++i) x[i] -= mS[(o+i)*ST + o+j] * x[j];
        }
#pragma unroll
        for (int q = 0; q < 16; ++q) zv[o+q] = x[q];
      }
      __syncthreads();
      const int nr = 48 - o;
      if (nr > 0) {
        for (int idx = tid; idx < nr*64; idx += 256) {
          const int r = o + 16 + idx/64, c = idx%64;
          float acc = mP2T[r*ST + c];
#pragma unroll
          for (int k = 0; k < 16; ++k) acc -= mS[r*ST + o+k] * mP2T[(o+k)*ST + c];
          mP2T[r*ST + c] = acc;
        }
        if (tid < nr) {
          const int r = o + 16 + tid;
          float acc = zv[r];
#pragma unroll
          for (int k = 0; k < 16; ++k) acc -= mS[r*ST + o+k] * zv[o+k];
          sRed[tid] = acc;
        }
        __syncthreads();
        if (tid < nr) zv[o + 16 + tid] = sRed[tid];
        __syncthreads();
      }
    }
    // blocked bwd solve on zv only (L^T zv2 = zv1)
#pragma unroll
    for (int jb = 3; jb >= 0; --jb) {
      const int o = jb*16;
      if (tid == 0) {
        float x[16];
#pragma unroll
        for (int q = 0; q < 16; ++q) x[q] = zv[o+q];
#pragma unroll
        for (int j = 15; j >= 0; --j) {
          x[j] *= sDi[o+j];
#pragma unroll
          for (int i = 0; i < j; ++i) x[i] -= mS[(o+j)*ST + o+i] * x[j];
        }
#pragma unroll
        for (int q = 0; q < 16; ++q) zv[o+q] = x[q];
      }
      __syncthreads();
      if (o > 0) {
        if (tid < o) {
          float acc = zv[tid];
#pragma unroll
          for (int k = 0; k < 16; ++k) acc -= mS[(o+k)*ST + tid] * zv[o+k];
          sRed[tid] = acc;
        }
        __syncthreads();
        if (tid < o) zv[tid] = sRed[tid];
        __syncthreads();
      }
    }
    // D = C1 - T2 T2^T
    for (int idx = tid; idx < 4096; idx += 256) {
      const int i = idx>>6, j = idx&63;
      float a = mC1[i*ST+j];
      for (int k = 0; k < 64; ++k) a -= mP2T[k*ST+i]*mP2T[k*ST+j];
      mC1[i*ST+j] = a;
    }
    __syncthreads();
    if (tid < 64) {
      float a = vu2[tid];
      for (int k = 0; k < 64; ++k) a -= mT1[tid*ST+k]*zv[k];
      vmu[tid] = a;
    }
    __syncthreads();
    mm64f<ST,ST,ST,false>(mA2, mC1, mT1, tid);
    __syncthreads();
    mm64f<ST,ST,ST,true>(mT1, mA2, mC1, tid);
    __syncthreads();
    for (int i = tid; i < 4096; i += 256)
      mC1[(i>>6)*ST + (i&63)] += Cseg[so*4096+i];
    if (tid < 64) {
      float a = vb2[tid];
      for (int j = 0; j < 64; ++j) a += mA2[tid*ST+j]*vmu[j];
      sRed[tid] = a;
    }
    __syncthreads();
    if (tid < 64) vb1[tid] = sRed[tid];
    __syncthreads();
    if (tid < 64) BPm[((size_t)b*NSEG + s + 1)*64 + tid] = vb1[tid];
    for (int i = tid; i < 4096; i += 256)
      BPC[((size_t)b*NSEG + s + 1)*4096 + i] = mC1[(i>>6)*ST + (i&63)];
    __syncthreads();
  }
}

// -------- fexpand = proven round-8 MFMA filter, seeded per segment (AUTHORITATIVE) --------
__global__ __launch_bounds__(256, 1) void fexpand_kernel(
    const float* __restrict__ kyg, const float* __restrict__ Kxg,
    const float* __restrict__ Fg, const float* __restrict__ logQ,
    const float* __restrict__ logQ0, const float* __restrict__ m0g,
    const float* __restrict__ BPm, const float* __restrict__ BPC,
    float* __restrict__ mf_g, float* __restrict__ mp_g,
    float* __restrict__ Pf_g, float* __restrict__ dpart_g,
    float* __restrict__ mfT_g)
{
  __shared__ float sB[64*STF];
  __shared__ __align__(16) char sPool[18432];
  __shared__ short sFh[64*SBF], sFl[64*SBF];
  __shared__ float sS[16*17], sSd[16];
  __shared__ float sQ[64], sQ0[64], skv[64], smf[64], smp[64], sv[16], sw[16];
  __shared__ float sldv;
  __shared__ f32x4 sRed4[256];
  float* sRed = (float*)sRed4;
  short* sXh = (short*)sPool;
  short* sXl = (short*)(sPool + 9216);
  float* sU  = (float*)sPool;
  float* sK  = (float*)(sPool + 5120);

  const int blk = blockIdx.x, tid = threadIdx.x;
  const int b = blk >> 3, sgi = blk & 7;
  const int w = tid >> 6, l = tid & 63;

#pragma unroll
  for (int q = 0; q < 4; ++q) {
    const int idx = q*1024 + tid*4;
    const int row = idx>>6, col = idx&63;
    float4 v = *(const float4*)&Fg[idx];
    s16x4 h4, l4;
    splitbf4(v, h4, l4);
    *(s16x4*)&sFh[row*SBF+col] = h4;
    *(s16x4*)&sFl[row*SBF+col] = l4;
  }
  if (tid < 64) {
    sQ[tid]  = softplus_f(logQ[tid]);
    sQ0[tid] = softplus_f(logQ0[tid]);
    smf[tid] = m0g[tid];
  }
  __syncthreads();
  if (sgi > 0) {
    for (int i = tid; i < 4096; i += 256)
      sB[(i>>6)*STF + (i&63)] = BPC[((size_t)b*NSEG + sgi)*4096 + i];
    if (tid < 64) smf[tid] = BPm[((size_t)b*NSEG + sgi)*64 + tid];
  }
  __syncthreads();

  const int tstart = sgi*SEG, tstop = tstart + SEG;
  for (int t = tstart; t < tstop; ++t) {
    const size_t bt = (size_t)b*T_ + t;
    if (t == 0) {
      for (int i = tid; i < 4096; i += 256) {
        const int r = i>>6, c = i&63;
        sB[r*STF+c] = (r==c) ? sQ0[r] : 0.f;
      }
      const float4 kreg = ((const float4*)(Kxg + bt*1024))[tid];
      *(float4*)&sK[(tid>>2)*SU + (tid&3)*4] = kreg;
      if (tid < 64) { smp[tid] = smf[tid]; skv[tid] = kyg[bt*64 + tid]; mp_g[bt*64+tid] = smp[tid]; }
      __syncthreads();
    } else {
#pragma unroll
      for (int q = 0; q < 4; ++q) {
        const int idx = q*1024 + tid*4;
        const int row = idx>>6, col = idx&63;
        float4 v = *(const float4*)&sB[row*STF+col];
        s16x4 h4, l4;
        splitbf4(v, h4, l4);
        *(s16x4*)&sXh[row*SBF+col] = h4;
        *(s16x4*)&sXl[row*SBF+col] = l4;
      }
      __syncthreads();
      const float4 kreg = ((const float4*)(Kxg + bt*1024))[tid];
      float kvreg = 0.f;
      if (tid < 64) kvreg = kyg[bt*64 + tid];
      f32x4 acc[4];
#pragma unroll
      for (int ct = 0; ct < 4; ++ct) acc[ct] = (f32x4){0.f,0.f,0.f,0.f};
      mfma_mm64<SBF>(sFh, sFl, sXh, sXl, w, l, acc);
      {
        const int i = tid & 63, jb = tid >> 6;
        float s2 = 0.f;
#pragma unroll
        for (int hq = 0; hq < 2; ++hq) {
          bf16x8 fh = *(const bf16x8*)&sFh[i*SBF + jb*16 + hq*8];
          bf16x8 fl = *(const bf16x8*)&sFl[i*SBF + jb*16 + hq*8];
#pragma unroll
          for (int j = 0; j < 8; ++j)
            s2 += (bf2f(fh[j]) + bf2f(fl[j])) * smf[jb*16 + hq*8 + j];
        }
        sRed[tid] = s2;
      }
      __syncthreads();
      {
        const int lr = l & 15, lg = l >> 4;
#pragma unroll
        for (int ct = 0; ct < 4; ++ct)
#pragma unroll
          for (int r = 0; r < 4; ++r) {
            short hh, ll;
            splitbf(acc[ct][r], hh, ll);
            const int row = w*16 + lg*4 + r, col = ct*16 + lr;
            sXh[row*SBF+col] = hh; sXl[row*SBF+col] = ll;
          }
      }
      if (tid < 64) {
        const float mpv = sRed[tid] + sRed[tid+64] + sRed[tid+128] + sRed[tid+192];
        smp[tid] = mpv; mp_g[bt*64+tid] = mpv;
      }
      __syncthreads();
#pragma unroll
      for (int ct = 0; ct < 4; ++ct) acc[ct] = (f32x4){0.f,0.f,0.f,0.f};
      mfma_mm64<SBF>(sXh, sXl, sFh, sFl, w, l, acc);
      __syncthreads();
      {
        const int lr = l & 15, lg = l >> 4;
#pragma unroll
        for (int ct = 0; ct < 4; ++ct)
#pragma unroll
          for (int r = 0; r < 4; ++r) {
            const int row = w*16 + lg*4 + r, col = ct*16 + lr;
            sB[row*STF+col] = acc[ct][r] + ((row==col) ? sQ[row] : 0.f);
          }
      }
      *(float4*)&sK[(tid>>2)*SU + (tid&3)*4] = kreg;
      if (tid < 64) skv[tid] = kvreg;
      __syncthreads();
    }
    {
      const int i = tid & 63, rq = tid >> 6;
      float4 u = {0.f,0.f,0.f,0.f};
      for (int jb = 0; jb < 16; ++jb) {
        const float4 p4 = *(const float4*)&sB[i*STF + jb*4];
#pragma unroll
        for (int dj = 0; dj < 4; ++dj) {
          const float4 k4 = *(const float4*)&sK[(jb*4+dj)*SU + rq*4];
          const float pv = (dj==0) ? p4.x : (dj==1) ? p4.y : (dj==2) ? p4.z : p4.w;
          u.x += pv*k4.x; u.y += pv*k4.y; u.z += pv*k4.z; u.w += pv*k4.w;
        }
      }
      *(float4*)&sU[i*SU + rq*4] = u;
    }
    __syncthreads();
    {
      const int ib = tid >> 6, r1 = (tid >> 2) & 15, r2b = tid & 3;
      float4 part = {0.f,0.f,0.f,0.f};
      for (int ii = 0; ii < 16; ++ii) {
        const int i = ib*16 + ii;
        const float kv = sK[i*SU + r1];
        const float4 u4 = *(const float4*)&sU[i*SU + r2b*4];
        part.x += kv*u4.x; part.y += kv*u4.y; part.z += kv*u4.z; part.w += kv*u4.w;
      }
      sRed4[tid] = (f32x4){part.x, part.y, part.z, part.w};
    }
    __syncthreads();
    if (tid < 64) {
      const int r1 = tid >> 2, r2b = tid & 3;
      f32x4 s4 = sRed4[tid];
      s4 += sRed4[tid+64]; s4 += sRed4[tid+128]; s4 += sRed4[tid+192];
#pragma unroll
      for (int dj = 0; dj < 4; ++dj)
        sS[r1*17 + r2b*4 + dj] = s4[dj] + ((r1 == r2b*4+dj) ? 1.f : 0.f);
    }
    __syncthreads();
    if (tid < 16) {
      const int ln = tid;
      float s2[16];
#pragma unroll
      for (int j = 0; j < 16; ++j) s2[j] = sS[ln*17+j];
      float pd = 1.f;
#pragma unroll
      for (int k = 0; k < 16; ++k) {
        const float dk = fmaxf(__shfl(s2[k], k, 64), 1e-30f);
        const float d = sqrtf(dk);
        const float rd = 1.f/d;
        pd *= dk;
        const float lik = s2[k]*rd;
        if (ln == k) sSd[k] = rd;
#pragma unroll
        for (int j = 0; j < 16; ++j) {
          const float ljk = __shfl(lik, j, 64);
          if (j > k && j <= ln) s2[j] -= lik*ljk;
        }
        if (ln > k) s2[k] = lik;
        else if (ln == k) s2[k] = d;
      }
#pragma unroll
      for (int j = 0; j < 16; ++j) sS[ln*17+j] = s2[j];
      if (ln == 0) sldv = logf(pd);
    } else if (tid >= 64 && tid < 80) {
      const int r = tid - 64;
      float a = 0.f;
      for (int i = 0; i < 64; ++i) a += sK[i*SU+r] * smp[i];
      sv[r] = a;
    }
    __syncthreads();
    if (tid < 64) {
      float x[16];
#pragma unroll
      for (int q = 0; q < 4; ++q) {
        const float4 u4 = *(const float4*)&sU[tid*SU + q*4];
        x[q*4+0]=u4.x; x[q*4+1]=u4.y; x[q*4+2]=u4.z; x[q*4+3]=u4.w;
      }
      fwd16(x, sS, sSd);
#pragma unroll
      for (int q = 0; q < 4; ++q) {
        float4 u4 = {x[q*4+0], x[q*4+1], x[q*4+2], x[q*4+3]};
        *(float4*)&sU[tid*SU + q*4] = u4;
      }
    } else if (tid == 64) {
      float x[16];
#pragma unroll
      for (int r = 0; r < 16; ++r) x[r] = sv[r];
      fwd16(x, sS, sSd);
#pragma unroll
      for (int r = 0; r < 16; ++r) sw[r] = x[r];
    }
    __syncthreads();
    {
      const int rg = tid >> 4, cg = tid & 15;
      float acc2[4][4] = {{0.f}};
#pragma unroll
      for (int rb = 0; rb < 4; ++rb) {
        float4 a4[4], b4[4];
#pragma unroll
        for (int i = 0; i < 4; ++i) a4[i] = *(const float4*)&sU[(rg*4+i)*SU + rb*4];
#pragma unroll
        for (int jj = 0; jj < 4; ++jj) b4[jj] = *(const float4*)&sU[(cg+16*jj)*SU + rb*4];
#pragma unroll
        for (int i = 0; i < 4; ++i)
#pragma unroll
          for (int jj = 0; jj < 4; ++jj)
            acc2[i][jj] += a4[i].x*b4[jj].x + a4[i].y*b4[jj].y
                         + a4[i].z*b4[jj].z + a4[i].w*b4[jj].w;
      }
#pragma unroll
      for (int i = 0; i < 4; ++i)
#pragma unroll
        for (int jj = 0; jj < 4; ++jj) {
          const int r = rg*4+i, c = cg+16*jj;
          sB[r*STF+c] -= acc2[i][jj];
        }
    }
    __syncthreads();
    {
      const int i = tid & 63, jb = tid >> 6;
      float s2 = 0.f;
#pragma unroll
      for (int q = 0; q < 4; ++q) {
        const float4 p4 = *(const float4*)&sB[i*STF + jb*16 + q*4];
        s2 += p4.x*skv[jb*16+q*4+0] + p4.y*skv[jb*16+q*4+1]
            + p4.z*skv[jb*16+q*4+2] + p4.w*skv[jb*16+q*4+3];
      }
      sRed[tid] = s2;
    }
    for (int i2 = tid; i2 < 4096; i2 += 256)
      Pf_g[bt*4096+i2] = sB[(i2>>6)*STF+(i2&63)];
    __syncthreads();
    if (tid < 64) {
      float a = smp[tid];
#pragma unroll
      for (int q = 0; q < 4; ++q) {
        const float4 u4 = *(const float4*)&sU[tid*SU + q*4];
        a -= u4.x*sw[q*4+0] + u4.y*sw[q*4+1] + u4.z*sw[q*4+2] + u4.w*sw[q*4+3];
      }
      a += sRed[tid] + sRed[tid+64] + sRed[tid+128] + sRed[tid+192];
      smf[tid] = a;
      mf_g[bt*64+tid] = a;
      if (t == T_-1) mfT_g[b*64+tid] = a;
    }
    __syncthreads();
    if (tid < 16) {
      float a = 0.f;
      for (int i = 0; i < 64; ++i) a += sK[i*SU+tid]*smf[i];
      float aa = a*a;
      aa += __shfl_xor(aa, 1, 64);
      aa += __shfl_xor(aa, 2, 64);
      aa += __shfl_xor(aa, 4, 64);
      aa += __shfl_xor(aa, 8, 64);
      if (tid == 0) {
        float dp = aa - sldv;
        if (t == 0) {
          float d1 = 0.f, d2 = 0.f;
          for (int i = 0; i < 64; ++i) {
            d1 += smf[i]*smf[i]/sQ0[i];
            d2 += smp[i]*smp[i]/sQ0[i];
          }
          dp = 0.5f*(d1 - d2 + dp);
        }
        dpart_g[bt] = dp;
      }
    }
    __syncthreads();
  }
}

// ---------------- gains (round-8) ----------------
__global__ __launch_bounds__(256) void gains_kernel(
    const float* __restrict__ Fg, const float* __restrict__ logQ,
    const float* __restrict__ mf_g, const float* __restrict__ mp_g,
    float* __restrict__ PfG_g, float* __restrict__ Cpk,
    float* __restrict__ d_g, float* __restrict__ dpart_g)
{
  const int blk = blockIdx.x;
  const int b = blk / (T_-1);
  const int n = 1 + (blk % (T_-1));
  const size_t btn = (size_t)b*T_ + n;
  const size_t btm = btn - 1;
  const int tid = threadIdx.x;
  const int rg = tid >> 4, cg = tid & 15;
  __shared__ float sA[64*ST];
  __shared__ float sM[64*STM];
  __shared__ float sPp[64*ST];
  __shared__ float sDi[64], sQd[64];
  __shared__ float smf1[64], smp[64];
  __shared__ float sd1d2[2];

  for (int i = tid; i < 4096; i += 256) sA[(i>>6)*ST + (i&63)] = PfG_g[btm*4096+i];
  if (tid < 64) {
    sM[tid*STM+64] = mf_g[btn*64+tid];
    sM[tid*STM+65] = mp_g[btn*64+tid];
    smf1[tid] = mf_g[btm*64+tid];
    smp[tid]  = mp_g[btn*64+tid];
    sQd[tid]  = softplus_f(logQ[tid]);
  }
  __syncthreads();
  {
    float acc[4][4] = {{0.f}};
#pragma unroll 4
    for (int k = 0; k < 64; ++k) {
      float a[4], bb[4];
#pragma unroll
      for (int i = 0; i < 4; ++i) a[i] = Fg[(rg*4+i)*64 + k];
#pragma unroll
      for (int j = 0; j < 4; ++j) bb[j] = sA[k*ST + cg*4+j];
#pragma unroll
      for (int i = 0; i < 4; ++i)
#pragma unroll
        for (int j = 0; j < 4; ++j) acc[i][j] += a[i]*bb[j];
    }
#pragma unroll
    for (int i = 0; i < 4; ++i)
#pragma unroll
      for (int j = 0; j < 4; ++j) sM[(rg*4+i)*STM + cg*4+j] = acc[i][j];
  }
  __syncthreads();
  {
    float acc[4][4] = {{0.f}};
#pragma unroll 4
    for (int k = 0; k < 64; ++k) {
      float a[4], bb[4];
#pragma unroll
      for (int i = 0; i < 4; ++i) a[i] = sM[(rg*4+i)*STM + k];
#pragma unroll
      for (int j = 0; j < 4; ++j) bb[j] = Fg[(cg*4+j)*64 + k];
#pragma unroll
      for (int i = 0; i < 4; ++i)
#pragma unroll
        for (int j = 0; j < 4; ++j) acc[i][j] += a[i]*bb[j];
    }
#pragma unroll
    for (int i = 0; i < 4; ++i)
#pragma unroll
      for (int j = 0; j < 4; ++j) {
        const int r = rg*4+i, c = cg*4+j;
        sPp[r*ST+c] = acc[i][j] + ((r==c) ? sQd[r] : 0.f);
      }
  }
  __syncthreads();
  chol64_blk<ST>(sPp, sDi, (float*)nullptr, tid);
#pragma unroll
  for (int jb = 0; jb < 4; ++jb) {
    const int o = jb*16;
    if (tid < 66) {
      const int c = tid;
      float x[16];
#pragma unroll
      for (int q = 0; q < 16; ++q) x[q] = sM[(o+q)*STM + c];
#pragma unroll
      for (int j = 0; j < 16; ++j) {
        x[j] *= sDi[o+j];
#pragma unroll
        for (int i = j+1; i < 16; ++i) x[i] -= sPp[(o+i)*ST + o+j] * x[j];
      }
#pragma unroll
      for (int q = 0; q < 16; ++q) sM[(o+q)*STM + c] = x[q];
    }
    __syncthreads();
    const int nr = 48 - o;
    if (nr > 0) {
      for (int idx = tid; idx < nr*66; idx += 256) {
        const int r = o + 16 + idx/66, c = idx%66;
        float acc = sM[r*STM + c];
#pragma unroll
        for (int k = 0; k < 16; ++k) acc -= sPp[r*ST + o+k] * sM[(o+k)*STM + c];
        sM[r*STM + c] = acc;
      }
      __syncthreads();
    }
  }
  if (tid == 64 || tid == 65) {
    float a = 0.f;
    for (int i = 0; i < 64; ++i) { const float v = sM[i*STM+tid]; a += v*v; }
    sd1d2[tid-64] = a;
  }
  {
    float acc[4][4] = {{0.f}};
#pragma unroll 2
    for (int k = 0; k < 64; ++k) {
      float a[4], bb[4];
#pragma unroll
      for (int i = 0; i < 4; ++i) a[i] = sM[k*STM + rg*4+i];
#pragma unroll
      for (int j = 0; j < 4; ++j) bb[j] = sM[k*STM + cg*4+j];
#pragma unroll
      for (int i = 0; i < 4; ++i)
#pragma unroll
        for (int j = 0; j < 4; ++j) acc[i][j] += a[i]*bb[j];
    }
#pragma unroll
    for (int i = 0; i < 4; ++i)
#pragma unroll
      for (int j = 0; j < 4; ++j)
        sA[(rg*4+i)*ST + (cg*4+j)] -= acc[i][j];
  }
  __syncthreads();
  for (int idx = tid; idx < 4096; idx += 256) {
    const int i = idx>>6, j = idx&63;
    if (i >= j) Cpk[btn*PKN + PIDX(i,j)] = sA[i*ST+j];
  }
#pragma unroll
  for (int jb = 3; jb >= 0; --jb) {
    const int o = jb*16;
    if (tid < 64) {
      const int c = tid;
      float x[16];
#pragma unroll
      for (int q = 0; q < 16; ++q) x[q] = sM[(o+q)*STM + c];
#pragma unroll
      for (int j = 15; j >= 0; --j) {
        x[j] *= sDi[o+j];
#pragma unroll
        for (int i = 0; i < j; ++i) x[i] -= sPp[(o+j)*ST + o+i] * x[j];
      }
#pragma unroll
      for (int q = 0; q < 16; ++q) sM[(o+q)*STM + c] = x[q];
    }
    __syncthreads();
    if (o > 0) {
      for (int idx = tid; idx < o*64; idx += 256) {
        const int r = idx/64, c = idx%64;
        float acc = sM[r*STM + c];
#pragma unroll
        for (int k = 0; k < 16; ++k) acc -= sPp[(o+k)*ST + r] * sM[(o+k)*STM + c];
        sM[r*STM + c] = acc;
      }
      __syncthreads();
    }
  }
  for (int i = tid; i < 4096; i += 256)
    PfG_g[btm*4096 + i] = sM[(i&63)*STM + (i>>6)];
  if (tid < 64) {
    float a = smf1[tid];
    for (int j = 0; j < 64; ++j) a -= sM[j*STM+tid]*smp[j];
    d_g[btm*64 + tid] = a;
  }
  if (tid == 0)
    dpart_g[btn] = 0.5f*(sd1d2[0] - sd1d2[1] + dpart_g[btn]);
}

// ---------------- smoother segment compose ----------------
__global__ __launch_bounds__(256) void compose_kernel(
    const float* __restrict__ G_g, const float* __restrict__ Cpk,
    const float* __restrict__ d_g,
    float* __restrict__ Gseg, float* __restrict__ cseg, float* __restrict__ dseg)
{
  extern __shared__ char cm[];
  short* GMh = (short*)cm;
  short* GMl = GMh + 4096;
  short* cMh = GMl + 4096;
  short* cMl = cMh + 4096;
  short* Gth = cMl + 4096;
  short* Gtl = Gth + 4096;
  short* Xh  = Gtl + 4096;
  short* Xl  = Xh + 4096;
  float* cbuf = (float*)(cm + 65536);
  float* sRed = (float*)(cm + 65536 + 8320);
  float* sdv  = (float*)(cm + 65536 + 8320 + 1024);

  const int blk = blockIdx.x, tid = threadIdx.x;
  const int b = blk >> 3, s = blk & (NSEG-1);
  const int w = tid >> 6, l = tid & 63;
  const int lr = l & 15, lg = l >> 4;
  const int t0 = s*SEG;
  const int tend = (s == NSEG-1) ? (T_-2) : (t0 + SEG - 1);

  {
    const size_t bt = (size_t)b*T_ + tend;
#pragma unroll
    for (int q = 0; q < 4; ++q) {
      const int idx = q*1024 + tid*4;
      const int row = idx>>6, col = idx&63;
      float4 v = *(const float4*)&G_g[bt*4096 + idx];
      s16x4 h4, l4;
      splitbf4(v, h4, l4);
#pragma unroll
      for (int e = 0; e < 4; ++e) {
        GMh[(col+e)*64 + row] = h4[e];
        GMl[(col+e)*64 + row] = l4[e];
      }
    }
    for (int idx = tid; idx < 4096; idx += 256) {
      const int i = idx>>6, j = idx&63;
      const int pidx = (i >= j) ? PIDX(i,j) : PIDX(j,i);
      const float v = Cpk[(bt+1)*PKN + pidx];
      short h, lo; splitbf(v, h, lo);
      cMh[i*64+j] = h; cMl[i*64+j] = lo;
    }
    if (tid < 64) sdv[tid] = d_g[bt*64+tid];
  }
  __syncthreads();

  for (int t = tend-1; t >= t0; --t) {
    const size_t bt = (size_t)b*T_ + t;
#pragma unroll
    for (int q = 0; q < 4; ++q) {
      const int idx = q*1024 + tid*4;
      const int row = idx>>6, col = idx&63;
      float4 v = *(const float4*)&G_g[bt*4096 + idx];
      s16x4 h4, l4;
      splitbf4(v, h4, l4);
      *(s16x4*)&Gth[row*64+col] = h4;
      *(s16x4*)&Gtl[row*64+col] = l4;
    }
    for (int i2 = tid; i2 < PKN; i2 += 256) cbuf[i2] = Cpk[(bt+1)*PKN + i2];
    float dreg = 0.f;
    if (tid < 64) dreg = d_g[bt*64+tid];
    __syncthreads();
    f32x4 a1[4], a2[4];
#pragma unroll
    for (int ct = 0; ct < 4; ++ct) { a1[ct] = (f32x4){0,0,0,0}; a2[ct] = (f32x4){0,0,0,0}; }
    mfma_mm64<64>(Gth, Gtl, GMh, GMl, w, l, a1);
    mfma_mm64<64>(Gth, Gtl, cMh, cMl, w, l, a2);
    {
      const int i = tid & 63, jb = tid >> 6;
      float ss = 0.f;
      for (int j = 0; j < 16; ++j) {
        const int jj = jb*16 + j;
        ss += (bf2f(Gth[i*64+jj]) + bf2f(Gtl[i*64+jj])) * sdv[jj];
      }
      sRed[tid] = ss;
    }
    __syncthreads();
#pragma unroll
    for (int ct = 0; ct < 4; ++ct)
#pragma unroll
      for (int r = 0; r < 4; ++r) {
        const int row = w*16 + lg*4 + r, col = ct*16 + lr;
        short h, lo;
        splitbf(a1[ct][r], h, lo);
        GMh[col*64+row] = h; GMl[col*64+row] = lo;
        splitbf(a2[ct][r], h, lo);
        Xh[row*64+col] = h; Xl[row*64+col] = lo;
      }
    if (tid < 64)
      sdv[tid] = dreg + sRed[tid] + sRed[tid+64] + sRed[tid+128] + sRed[tid+192];
    __syncthreads();
    f32x4 a3[4];
#pragma unroll
    for (int ct = 0; ct < 4; ++ct) a3[ct] = (f32x4){0,0,0,0};
    mfma_mm64<64>(Xh, Xl, Gth, Gtl, w, l, a3);
#pragma unroll
    for (int ct = 0; ct < 4; ++ct)
#pragma unroll
      for (int r = 0; r < 4; ++r) {
        const int row = w*16 + lg*4 + r, col = ct*16 + lr;
        const int pidx = (row >= col) ? PIDX(row,col) : PIDX(col,row);
        const float cv = cbuf[pidx] + a3[ct][r];
        short h, lo; splitbf(cv, h, lo);
        cMh[row*64+col] = h; cMl[row*64+col] = lo;
      }
    __syncthreads();
  }
  for (int idx = tid; idx < 4096; idx += 256) {
    const int i = idx>>6, j = idx&63;
    Gseg[(size_t)blk*4096 + idx] = bf2f(GMh[j*64+i]) + bf2f(GMl[j*64+i]);
    if (i >= j)
      cseg[(size_t)blk*PKN + PIDX(i,j)] = bf2f(cMh[i*64+j]) + bf2f(cMl[i*64+j]);
  }
  if (tid < 64) dseg[(size_t)blk*64 + tid] = sdv[tid];
}

// ---------------- smoother boundary scan ----------------
__global__ __launch_bounds__(256) void boundary_kernel(
    const float* __restrict__ PfG_g, const float* __restrict__ mfT_g,
    const float* __restrict__ Gseg, const float* __restrict__ cseg,
    const float* __restrict__ dseg,
    float* __restrict__ InP, float* __restrict__ Inm)
{
  __shared__ short Gsh[4096], Gsl[4096], vh[4096], vl[4096], Wh[4096], Wl[4096];
  __shared__ float cb[PKN];
  __shared__ float svm[64];
  __shared__ float sRed[256];
  const int b = blockIdx.x, tid = threadIdx.x;
  const int w = tid >> 6, l = tid & 63;
  const int lr = l & 15, lg = l >> 4;

  {
    const size_t bl = ((size_t)b*T_ + (T_-1))*4096;
    for (int idx = tid; idx < 4096; idx += 256) {
      const int i = idx>>6, j = idx&63;
      const float v = PfG_g[bl + idx];
      short h, lo; splitbf(v, h, lo);
      vh[i*64+j] = h; vl[i*64+j] = lo;
      if (i >= j) InP[((size_t)b*NSEG + (NSEG-1))*PKN + PIDX(i,j)] = v;
    }
    if (tid < 64) {
      const float m = mfT_g[b*64+tid];
      svm[tid] = m;
      Inm[((size_t)b*NSEG + (NSEG-1))*64 + tid] = m;
    }
  }
  __syncthreads();
  for (int s = NSEG-1; s >= 1; --s) {
    const size_t seg = (size_t)b*NSEG + s;
    float dreg = 0.f;
#pragma unroll
    for (int q = 0; q < 4; ++q) {
      const int idx = q*1024 + tid*4;
      const int row = idx>>6, col = idx&63;
      float4 v = *(const float4*)&Gseg[seg*4096 + idx];
      s16x4 h4, l4;
      splitbf4(v, h4, l4);
      *(s16x4*)&Gsh[row*64+col] = h4;
      *(s16x4*)&Gsl[row*64+col] = l4;
    }
    for (int i2 = tid; i2 < PKN; i2 += 256) cb[i2] = cseg[seg*PKN + i2];
    if (tid < 64) dreg = dseg[seg*64+tid];
    __syncthreads();
    {
      const int i = tid & 63, jb = tid >> 6;
      float ss = 0.f;
      for (int j = 0; j < 16; ++j) {
        const int jj = jb*16 + j;
        ss += (bf2f(Gsh[i*64+jj]) + bf2f(Gsl[i*64+jj])) * svm[jj];
      }
      sRed[tid] = ss;
    }
    f32x4 a1[4];
#pragma unroll
    for (int ct = 0; ct < 4; ++ct) a1[ct] = (f32x4){0,0,0,0};
    mfma_mm64<64>(Gsh, Gsl, vh, vl, w, l, a1);
    __syncthreads();
#pragma unroll
    for (int ct = 0; ct < 4; ++ct)
#pragma unroll
      for (int r = 0; r < 4; ++r) {
        const int row = w*16 + lg*4 + r, col = ct*16 + lr;
        short h, lo; splitbf(a1[ct][r], h, lo);
        Wh[row*64+col] = h; Wl[row*64+col] = lo;
      }
    if (tid < 64)
      svm[tid] = dreg + sRed[tid] + sRed[tid+64] + sRed[tid+128] + sRed[tid+192];
    __syncthreads();
    f32x4 a2[4];
#pragma unroll
    for (int ct = 0; ct < 4; ++ct) a2[ct] = (f32x4){0,0,0,0};
    mfma_mm64<64>(Wh, Wl, Gsh, Gsl, w, l, a2);
#pragma unroll
    for (int ct = 0; ct < 4; ++ct)
#pragma unroll
      for (int r = 0; r < 4; ++r) {
        const int row = w*16 + lg*4 + r, col = ct*16 + lr;
        const int pidx = (row >= col) ? PIDX(row,col) : PIDX(col,row);
        const float vv = cb[pidx] + a2[ct][r];
        short h, lo; splitbf(vv, h, lo);
        vh[row*64+col] = h; vl[row*64+col] = lo;
        if (row >= col) InP[((size_t)b*NSEG + s - 1)*PKN + PIDX(row,col)] = vv;
      }
    if (tid < 64) Inm[((size_t)b*NSEG + s - 1)*64 + tid] = svm[tid];
    __syncthreads();
  }
}

// ---------------- smoother segment expand ----------------
__global__ __launch_bounds__(256) void expand_kernel(
    const float* __restrict__ GPs_g, float* __restrict__ Cpk,
    const float* __restrict__ d_g, const float* __restrict__ InP,
    const float* __restrict__ Inm, float* __restrict__ ms_g)
{
  __shared__ float sPs[64*STF];
  __shared__ short sGh[64*SBF], sGl[64*SBF];
  __shared__ short sPh[64*SBF], sPl[64*SBF];
  __shared__ float sms[64];
  __shared__ float sRed[256];
  const int blk = blockIdx.x, tid = threadIdx.x;
  const int b = blk >> 3, s = blk & (NSEG-1);
  const int w = tid >> 6, l = tid & 63;
  const int t0 = s*SEG;
  const int tend = (s == NSEG-1) ? (T_-2) : (t0 + SEG - 1);

  int ci[9], cj[9];
#pragma unroll
  for (int nn = 0; nn < 9; ++nn) {
    const int p = nn*256 + tid;
    int i = (int)((sqrtf(8.f*(float)p + 1.f) - 1.f)*0.5f);
    while ((i+1)*(i+2)/2 <= p) ++i;
    while (i*(i+1)/2 > p) --i;
    ci[nn] = i; cj[nn] = p - i*(i+1)/2;
  }

  for (int idx = tid; idx < 4096; idx += 256) {
    const int i = idx>>6, j = idx&63;
    const int pidx = (i >= j) ? PIDX(i,j) : PIDX(j,i);
    sPs[i*STF+j] = InP[((size_t)b*NSEG + s)*PKN + pidx];
  }
  if (tid < 64) sms[tid] = Inm[((size_t)b*NSEG + s)*64 + tid];
  __syncthreads();
  if (s == NSEG-1) {
#pragma unroll
    for (int nn = 0; nn < 9; ++nn) {
      const int p = nn*256 + tid;
      if (p < PKN) Cpk[(size_t)b*T_*PKN + p] = sPs[ci[nn]*STF + cj[nn]];
    }
    if (tid < 64) ms_g[((size_t)b*T_ + (T_-1))*64 + tid] = sms[tid];
  }
  float4 gf4[4];
  {
    const float4* Gp = (const float4*)(GPs_g + ((size_t)b*T_ + tend)*4096);
#pragma unroll
    for (int q = 0; q < 4; ++q) gf4[q] = Gp[q*256 + tid];
  }

  for (int t = tend; t >= t0; --t) {
    const size_t bt = (size_t)b*T_ + t;
    const size_t cslot = (bt+1)*PKN;
#pragma unroll
    for (int q = 0; q < 4; ++q) {
      const int row = q*16 + (tid>>4), col = (tid&15)*4;
      s16x4 h4, l4;
      splitbf4(gf4[q], h4, l4);
      *(s16x4*)&sGh[row*SBF+col] = h4;
      *(s16x4*)&sGl[row*SBF+col] = l4;
    }
#pragma unroll
    for (int q = 0; q < 4; ++q) {
      const int idx = q*1024 + tid*4;
      const int row = idx>>6, col = idx&63;
      float4 v = *(const float4*)&sPs[row*STF+col];
      s16x4 h4, l4;
      splitbf4(v, h4, l4);
      *(s16x4*)&sPh[row*SBF+col] = h4;
      *(s16x4*)&sPl[row*SBF+col] = l4;
    }
    float cr[9];
#pragma unroll
    for (int nn = 0; nn < 9; ++nn) {
      const int p = nn*256 + tid;
      cr[nn] = (p < PKN) ? Cpk[cslot + p] : 0.f;
    }
    float dreg = 0.f;
    if (tid < 64) dreg = d_g[bt*64+tid];
    {
      const size_t tprev = (t > t0) ? (bt-1) : bt;
      const float4* Gp = (const float4*)(GPs_g + tprev*4096);
#pragma unroll
      for (int q = 0; q < 4; ++q) gf4[q] = Gp[q*256 + tid];
    }
    __syncthreads();
    f32x4 acc[4];
#pragma unroll
    for (int ct = 0; ct < 4; ++ct) acc[ct] = (f32x4){0.f,0.f,0.f,0.f};
    mfma_mm64<SBF>(sGh, sGl, sPh, sPl, w, l, acc);
    {
      const int i = tid & 63, jb = tid >> 6;
      float ss = 0.f;
#pragma unroll
      for (int hq = 0; hq < 2; ++hq) {
        bf16x8 gh = *(const bf16x8*)&sGh[i*SBF + jb*16 + hq*8];
        bf16x8 gl = *(const bf16x8*)&sGl[i*SBF + jb*16 + hq*8];
#pragma unroll
        for (int j = 0; j < 8; ++j)
          ss += (bf2f(gh[j]) + bf2f(gl[j])) * sms[jb*16 + hq*8 + j];
      }
      sRed[tid] = ss;
    }
    __syncthreads();
    {
      const int lr = l & 15, lg = l >> 4;
#pragma unroll
      for (int ct = 0; ct < 4; ++ct)
#pragma unroll
        for (int r = 0; r < 4; ++r) {
          short hh, ll;
          splitbf(acc[ct][r], hh, ll);
          const int row = w*16 + lg*4 + r, col = ct*16 + lr;
          sPh[row*SBF+col] = hh; sPl[row*SBF+col] = ll;
        }
    }
    __syncthreads();
    float mval = 0.f;
    if (tid < 64) {
      mval = dreg + sRed[tid] + sRed[tid+64] + sRed[tid+128] + sRed[tid+192];
      sms[tid] = mval; ms_g[bt*64+tid] = mval;
    }
#pragma unroll
    for (int ct = 0; ct < 4; ++ct) acc[ct] = (f32x4){0.f,0.f,0.f,0.f};
    mfma_mm64<SBF>(sPh, sPl, sGh, sGl, w, l, acc);
    __syncthreads();
    {
      const int lr = l & 15, lg = l >> 4;
#pragma unroll
      for (int ct = 0; ct < 4; ++ct)
#pragma unroll
        for (int r = 0; r < 4; ++r) {
          const int row = w*16 + lg*4 + r, col = ct*16 + lr;
          sPs[row*STF+col] = acc[ct][r];
        }
    }
    __syncthreads();
#pragma unroll
    for (int nn = 0; nn < 9; ++nn) {
      const int p = nn*256 + tid;
      if (p < PKN) {
        const int i = ci[nn], j = cj[nn];
        float val;
        if (i == j) val = cr[nn] + sPs[i*STF+i];
        else        val = cr[nn] + 0.5f*(sPs[i*STF+j] + sPs[j*STF+i]);
        sPs[i*STF+j] = val;
        if (i != j) sPs[j*STF+i] = val;
        Cpk[cslot + p] = val;
      }
    }
    __syncthreads();
  }
}

// ---------------- klell ----------------
__global__ __launch_bounds__(256) void klell_kernel(
    const float* __restrict__ yg, const float* __restrict__ epsg,
    const float* __restrict__ kyg, const float* __restrict__ Kxg,
    const float* __restrict__ Cg, const float* __restrict__ brg,
    const float* __restrict__ Cpk, const float* __restrict__ ms_g,
    const float* __restrict__ dpart_g, float* __restrict__ val_g)
{
  const int bx = blockIdx.x;
  const int b = bx >> 8, t = bx & (T_-1);
  const size_t bt = (size_t)bx;
  const int tid = threadIdx.x;
  __shared__ float sPs[64*ST], sC[64*ST];
  __shared__ float sPA[64*17], sK[64*17];
  __shared__ float sZ[NS_*ST];
  __shared__ float sE[NS_*64];
  __shared__ float sy[256], sbr[256];
  __shared__ float skv[64], sms[64], sDi[64], sDg[64];
  __shared__ float sv[16];
  __shared__ float red[256];

  const size_t pslot = ((size_t)b*T_ + ((t+1) & (T_-1)))*PKN;
  for (int idx = tid; idx < 4096; idx += 256) {
    const int i = idx>>6, j = idx&63;
    const int pidx = (i >= j) ? PIDX(i,j) : PIDX(j,i);
    sPs[i*ST+j] = Cpk[pslot + pidx];
  }
  for (int i = tid; i < 1024; i += 256) sK[(i>>4)*17+(i&15)] = Kxg[bt*1024+i];
  if (tid < 64) { skv[tid] = kyg[bt*64+tid]; sms[tid] = ms_g[bt*64+tid]; }
  sy[tid]  = yg[bt*256+tid];
  sbr[tid] = brg[tid];
  for (int i = tid; i < NS_*64; i += 256) {
    const int s = i >> 6, j = i & 63;
    sE[i] = epsg[(((size_t)s*B_ + b)*T_ + t)*64 + j];
  }
  __syncthreads();
  {
    const int i = tid & 63, rq = tid >> 6;
    float u[4] = {0.f,0.f,0.f,0.f};
    for (int j = 0; j < 64; ++j) {
      const float p = sPs[i*ST+j];
#pragma unroll
      for (int r = 0; r < 4; ++r) u[r] += p * sK[j*17 + rq*4 + r];
    }
#pragma unroll
    for (int r = 0; r < 4; ++r) sPA[i*17 + rq*4 + r] = u[r];
  }
  __syncthreads();
  {
    const int i = tid & 63, rq = tid >> 6;
    float a = 0.f;
#pragma unroll
    for (int r = 0; r < 4; ++r) a += sK[i*17+rq*4+r]*sPA[i*17+rq*4+r];
    red[tid] = a;
  }
  if (tid < 16) {
    float a = 0.f;
    for (int i = 0; i < 64; ++i) a += sK[i*17+tid]*sms[i];
    sv[tid] = a;
  }
  __syncthreads();
  for (int s2 = 128; s2 > 0; s2 >>= 1) {
    if (tid < s2) red[tid] += red[tid+s2];
    __syncthreads();
  }
  float klv = 0.f;
  if (tid == 0) {
    const float tr = red[0];
    float ip1 = 0.f;
    for (int i = 0; i < 64; ++i) ip1 += skv[i]*sms[i];
    float s2s = 0.f;
#pragma unroll
    for (int r = 0; r < 16; ++r) s2s += sv[r]*sv[r];
    klv = (ip1 - 0.5f*s2s - 0.5f*tr) - dpart_g[bt];
  }
  if (tid < 64) sPs[tid*ST+tid] += 1e-5f;
  __syncthreads();
  chol64_blk<ST>(sPs, sDi, sDg, tid);
#pragma unroll
  for (int p = 0; p < 2; ++p) {
    const int s = (tid >> 6) + 4*p, ll = tid & 63;
    float a = sms[ll];
    for (int j = 0; j < ll; ++j) a += sPs[ll*ST+j]*sE[s*64+j];
    a += sDg[ll]*sE[s*64+ll];
    sZ[s*ST+ll] = a;
  }
  __syncthreads();
  float accel = 0.f;
  for (int nc = 0; nc < 4; ++nc) {
    for (int i = tid; i < 4096; i += 256) sC[(i>>6)*ST+(i&63)] = Cg[nc*4096+i];
    __syncthreads();
#pragma unroll
    for (int p = 0; p < 2; ++p) {
      const int idx = p*256 + tid;
      const int s = idx >> 6, rn = idx & 63;
      const int nn2 = nc*64 + rn;
      float lr = sbr[nn2];
      for (int ll = 0; ll < 64; ++ll) lr += sZ[s*ST+ll]*sC[rn*ST+ll];
      accel += sy[nn2]*lr - expf(lr);
    }
    __syncthreads();
  }
  red[tid] = accel;
  __syncthreads();
  for (int s2 = 128; s2 > 0; s2 >>= 1) {
    if (tid < s2) red[tid] += red[tid+s2];
    __syncthreads();
  }
  if (tid == 0) val_g[bt] = klv - red[0]*(1.0f/NS_);
}

// ---------------- final reduction ----------------
__global__ __launch_bounds__(256) void reduce_kernel(const float* __restrict__ val,
                                                     float* __restrict__ out)
{
  __shared__ float red[256];
  float acc = 0.f;
  for (int i = threadIdx.x; i < B_*T_; i += 256) acc += val[i];
  red[threadIdx.x] = acc;
  __syncthreads();
  for (int s2 = 128; s2 > 0; s2 >>= 1) {
    if (threadIdx.x < s2) red[threadIdx.x] += red[threadIdx.x+s2];
    __syncthreads();
  }
  if (threadIdx.x == 0) out[0] = red[0] / (float)B_;
}

__global__ void diag_kernel(float* out, float v)
{
  if (threadIdx.x == 0) out[0] = v;
}

extern "C" void kernel_launch(void* const* d_in, const int* in_sizes, int n_in,
                              void* d_out, int out_size, void* d_ws, size_t ws_size,
                              hipStream_t stream)
{
  const float* y    = (const float*)d_in[0];
  const float* eps  = (const float*)d_in[1];
  const float* W1   = (const float*)d_in[2];
  const float* b1   = (const float*)d_in[3];
  const float* W2   = (const float*)d_in[4];
  const float* b2   = (const float*)d_in[5];
  const float* F    = (const float*)d_in[6];
  const float* logQ = (const float*)d_in[7];
  const float* logQ0= (const float*)d_in[8];
  const float* m0   = (const float*)d_in[9];
  const float* C    = (const float*)d_in[10];
  const float* br   = (const float*)d_in[11];
  (void)in_sizes; (void)n_in; (void)out_size;

  char* ws = (char*)d_ws;
  float* out = (float*)d_out;

  auto al = [](size_t x){ return (x + 255) & ~(size_t)255; };
  size_t o = 0;
  float* ky    = (float*)(ws + o); o = al(o + (size_t)B_*T_*64*4);
  float* mf    = (float*)(ws + o); o = al(o + (size_t)B_*T_*64*4);
  float* mp    = (float*)(ws + o); o = al(o + (size_t)B_*T_*64*4);
  float* msb   = (float*)(ws + o); o = al(o + (size_t)B_*T_*64*4);
  float* dv    = (float*)(ws + o); o = al(o + (size_t)B_*T_*64*4);
  float* dpart = (float*)(ws + o); o = al(o + (size_t)B_*T_*4);
  float* val   = (float*)(ws + o); o = al(o + (size_t)B_*T_*4);
  float* Kx    = (float*)(ws + o); o = al(o + (size_t)B_*T_*1024*4);
  float* A1    = (float*)(ws + o); o = al(o + (size_t)B_*T_*4096*4);   // Pf -> G
  float* Cpk   = (float*)(ws + o); o = al(o + (size_t)B_*T_*PKN*4);    // c -> Ps packed
  float* Gseg  = (float*)(ws + o); o = al(o + (size_t)B_*NSEG*4096*4);
  float* cseg  = (float*)(ws + o); o = al(o + (size_t)B_*NSEG*PKN*4);
  float* dseg  = (float*)(ws + o); o = al(o + (size_t)B_*NSEG*64*4);
  float* InP   = (float*)(ws + o); o = al(o + (size_t)B_*NSEG*PKN*4);
  float* Inm   = (float*)(ws + o); o = al(o + (size_t)B_*NSEG*64*4);
  float* mfT   = (float*)(ws + o); o = al(o + (size_t)B_*64*4);
  float* h     = A1;   // MLP hidden aliases A1; dead before fexpand writes

  // Filter-scan buffers ALIAS the Cpk region (Cpk first written by gains,
  // which runs after fexpand; stream-ordered -> no overlap). ~16.2MB << 65MB.
  float* Aseg  = Cpk;
  float* Cseg2 = Aseg  + (size_t)B_*NSEG*4096;
  float* Jseg  = Cseg2 + (size_t)B_*NSEG*4096;
  float* BPC   = Jseg  + (size_t)B_*NSEG*4096;
  float* bsegA = BPC   + (size_t)B_*NSEG*4096;
  float* etaA  = bsegA + (size_t)B_*NSEG*64;
  float* BPm   = etaA  + (size_t)B_*NSEG*64;

  if (ws_size < o) {
    diag_kernel<<<1, 64, 0, stream>>>(out, (float)((double)ws_size / 1048576.0));
    return;
  }

  dim3 blk(256);
  gemm_kernel<true,false><<<dim3(H_/64, (B_*T_)/64), blk, 0, stream>>>(
      y, W1, b1, h, (float*)nullptr, B_*T_, H_, N_);
  gemm_kernel<false,true><<<dim3((L_+L_*R_)/64, (B_*T_)/64), blk, 0, stream>>>(
      h, W2, b2, ky, Kx, B_*T_, L_+L_*R_, H_);
  // parallel filter scan (authoritative)
  fcompose_kernel<<<B_*NSEG, blk, FC_LDS, stream>>>(
      ky, Kx, F, logQ, logQ0, m0, Aseg, Cseg2, Jseg, bsegA, etaA, BPm, BPC);
  fboundary_kernel<<<B_, blk, FB_LDS, stream>>>(
      Aseg, Cseg2, Jseg, bsegA, etaA, BPm, BPC);
  fexpand_kernel<<<B_*NSEG, blk, 0, stream>>>(
      ky, Kx, F, logQ, logQ0, m0, BPm, BPC, mf, mp, A1, dpart, mfT);
  // downstream (round-8 proven) — gains overwrites the scan region
  gains_kernel<<<B_*(T_-1), blk, 0, stream>>>(F, logQ, mf, mp, A1, Cpk, dv, dpart);
  compose_kernel<<<B_*NSEG, blk, 65536 + 8320 + 1024 + 256 + 64, stream>>>(
      A1, Cpk, dv, Gseg, cseg, dseg);
  boundary_kernel<<<B_, blk, 0, stream>>>(A1, mfT, Gseg, cseg, dseg, InP, Inm);
  expand_kernel<<<B_*NSEG, blk, 0, stream>>>(A1, Cpk, dv, InP, Inm, msb);
  klell_kernel<<<B_*T_, blk, 0, stream>>>(y, eps, ky, Kx, C, br, Cpk, msb, dpart, val);
  reduce_kernel<<<1, blk, 0, stream>>>(val, (float*)d_out);
}

// Round 14
// 5304.270 us; speedup vs baseline: 1.9146x; 1.1093x over previous
//
#include <hip/hip_runtime.h>
#include <math.h>

#define B_ 32
#define T_ 256
#define N_ 256
#define L_ 64
#define R_ 16
#define H_ 256
#define NS_ 8
#define SEG 32
#define NSEG 8
#define ST 65
#define STM 67
#define STF 68
#define SBF 72
#define SU 20
#define PKN 2080
#define PIDX(i,j) ((((i)*((i)+1))>>1) + (j))

using f32x4  = __attribute__((ext_vector_type(4))) float;
using bf16x8 = __attribute__((ext_vector_type(8))) short;
using s16x4  = __attribute__((ext_vector_type(4))) short;

__device__ __forceinline__ float softplus_f(float x) { return log1pf(expf(x)); }

__device__ __forceinline__ void splitbf(float x, short& h, short& l)
{
  unsigned u = __float_as_uint(x);
  unsigned hu = (u + 0x7FFFu + ((u>>16)&1u)) & 0xFFFF0000u;
  float hf = __uint_as_float(hu);
  float r = x - hf;
  unsigned ur = __float_as_uint(r);
  unsigned lu = (ur + 0x7FFFu + ((ur>>16)&1u)) >> 16;
  h = (short)(hu>>16); l = (short)lu;
}
__device__ __forceinline__ void splitbf4(const float4& v, s16x4& h4, s16x4& l4)
{
  short h, l;
  splitbf(v.x, h, l); h4[0] = h; l4[0] = l;
  splitbf(v.y, h, l); h4[1] = h; l4[1] = l;
  splitbf(v.z, h, l); h4[2] = h; l4[2] = l;
  splitbf(v.w, h, l); h4[3] = h; l4[3] = l;
}
__device__ __forceinline__ float bf2f(short s)
{ return __uint_as_float(((unsigned)(unsigned short)s)<<16); }

template<int SB>
__device__ __forceinline__ void mfma_mm64(const short* Ah, const short* Al,
                                          const short* Bh, const short* Bl,
                                          int w, int l, f32x4 acc[4])
{
  const int lr = l & 15, lg = l >> 4;
  const int arow = (w*16+lr)*SB;
#pragma unroll
  for (int ks = 0; ks < 2; ++ks) {
    const int ko = ks*32 + lg*8;
    bf16x8 ah = *(const bf16x8*)&Ah[arow + ko];
    bf16x8 al = *(const bf16x8*)&Al[arow + ko];
#pragma unroll
    for (int ct = 0; ct < 4; ++ct) {
      bf16x8 bh = *(const bf16x8*)&Bh[(ct*16+lr)*SB + ko];
      bf16x8 bl = *(const bf16x8*)&Bl[(ct*16+lr)*SB + ko];
      acc[ct] = __builtin_amdgcn_mfma_f32_16x16x32_bf16(ah, bh, acc[ct], 0,0,0);
      acc[ct] = __builtin_amdgcn_mfma_f32_16x16x32_bf16(ah, bl, acc[ct], 0,0,0);
      acc[ct] = __builtin_amdgcn_mfma_f32_16x16x32_bf16(al, bh, acc[ct], 0,0,0);
    }
  }
}

template<int SA>
__device__ __forceinline__ void chol64_blk(float* A, float* rdiag, float* dg, int tid)
{
#pragma unroll
  for (int kb = 0; kb < 4; ++kb) {
    const int o = kb*16;
    if (tid < 16) {
      const int ln = tid;
      float s[16];
#pragma unroll
      for (int j = 0; j < 16; ++j) s[j] = A[(o+ln)*SA + o + j];
#pragma unroll
      for (int k = 0; k < 16; ++k) {
        const float dk = fmaxf(__shfl(s[k], k, 64), 1e-30f);
        const float d = sqrtf(dk);
        const float rd = 1.f/d;
        const float lik = s[k]*rd;
        if (ln == k) { rdiag[o+k] = rd; if (dg) dg[o+k] = d; }
#pragma unroll
        for (int j = 0; j < 16; ++j) {
          const float ljk = __shfl(lik, j, 64);
          if (j > k && j <= ln) s[j] -= lik*ljk;
        }
        if (ln > k) s[k] = lik;
        else if (ln == k) s[k] = dk;
      }
#pragma unroll
      for (int j = 0; j < 16; ++j) A[(o+ln)*SA + o + j] = s[j];
    }
    __syncthreads();
    const int nr = 48 - o;
    if (nr > 0) {
      if (tid < nr) {
        const int r = o + 16 + tid;
        float x[16];
#pragma unroll
        for (int q = 0; q < 16; ++q) x[q] = A[r*SA + o + q];
#pragma unroll
        for (int j = 0; j < 16; ++j) {
          x[j] *= rdiag[o+j];
#pragma unroll
          for (int i2 = j+1; i2 < 16; ++i2) x[i2] -= A[(o+i2)*SA + o + j] * x[j];
        }
#pragma unroll
        for (int q = 0; q < 16; ++q) A[r*SA + o + q] = x[q];
      }
      __syncthreads();
      const int tot = nr*nr;
      for (int idx = tid; idx < tot; idx += 256) {
        const int i = o + 16 + idx / nr, j = o + 16 + idx % nr;
        float acc = A[i*SA + j];
#pragma unroll
        for (int k = 0; k < 16; ++k) acc -= A[i*SA + o + k] * A[j*SA + o + k];
        A[i*SA + j] = acc;
      }
      __syncthreads();
    }
  }
}

__device__ __forceinline__ void fwd16(float* x, const float* sS, const float* sSd)
{
#pragma unroll
  for (int a = 0; a < 16; ++a) {
    x[a] *= sSd[a];
#pragma unroll
    for (int i = a+1; i < 16; ++i) x[i] -= sS[i*17+a]*x[a];
  }
}

// ---------------- K1: tiled fp32 GEMM ----------------
template<bool TANH, bool SPLIT>
__global__ __launch_bounds__(256) void gemm_kernel(
    const float* __restrict__ A, const float* __restrict__ Bw,
    const float* __restrict__ bias, float* __restrict__ C1,
    float* __restrict__ C2, int M, int Nn, int Kk)
{
  __shared__ float As[16][65];
  __shared__ float Bs[16][64];
  const int bm = blockIdx.y * 64, bn = blockIdx.x * 64;
  const int tid = threadIdx.x;
  const int rg = tid >> 4, cg = tid & 15;
  float acc[4][4] = {{0.f}};
  for (int k0 = 0; k0 < Kk; k0 += 16) {
    {
      const int kk = tid & 15, r0 = tid >> 4;
#pragma unroll
      for (int rr = 0; rr < 4; ++rr)
        As[kk][r0 + 16*rr] = A[(size_t)(bm + r0 + 16*rr) * Kk + k0 + kk];
    }
    {
      const int cc = tid & 63, kk = tid >> 6;
#pragma unroll
      for (int kr = 0; kr < 4; ++kr)
        Bs[kk + 4*kr][cc] = Bw[(size_t)(k0 + kk + 4*kr) * Nn + bn + cc];
    }
    __syncthreads();
#pragma unroll
    for (int k = 0; k < 16; ++k) {
      float a[4], bb[4];
#pragma unroll
      for (int i = 0; i < 4; ++i) a[i] = As[k][rg*4+i];
#pragma unroll
      for (int j = 0; j < 4; ++j) bb[j] = Bs[k][cg*4+j];
#pragma unroll
      for (int i = 0; i < 4; ++i)
#pragma unroll
        for (int j = 0; j < 4; ++j) acc[i][j] += a[i]*bb[j];
    }
    __syncthreads();
  }
#pragma unroll
  for (int i = 0; i < 4; ++i) {
    const int row = bm + rg*4 + i;
#pragma unroll
    for (int j = 0; j < 4; ++j) {
      const int col = bn + cg*4 + j;
      float v = acc[i][j] + bias[col];
      if (TANH) v = tanhf(v);
      if (SPLIT) {
        if (col < 64) C1[(size_t)row*64 + col] = v;
        else          C2[(size_t)row*1024 + (col-64)] = v;
      } else {
        C1[(size_t)row*Nn + col] = v;
      }
    }
  }
}

// ---------------- K2: Kalman filter (sequential, Woodbury, MFMA mms) ----------------
__global__ __launch_bounds__(256, 1) void filter_kernel(
    const float* __restrict__ kyg, const float* __restrict__ Kxg,
    const float* __restrict__ Fg, const float* __restrict__ logQ,
    const float* __restrict__ logQ0, const float* __restrict__ m0g,
    float* __restrict__ mf_g, float* __restrict__ mp_g,
    float* __restrict__ Pf_g, float* __restrict__ dpart_g,
    float* __restrict__ mfT_g)
{
  __shared__ float sB[64*STF];
  __shared__ __align__(16) char sPool[18432];
  __shared__ short sFh[64*SBF], sFl[64*SBF];
  __shared__ float sS[16*17], sSd[16];
  __shared__ float sQ[64], sQ0[64], skv[64], smf[64], smp[64], sv[16], sw[16];
  __shared__ float sldv;
  __shared__ f32x4 sRed4[256];
  float* sRed = (float*)sRed4;
  short* sXh = (short*)sPool;
  short* sXl = (short*)(sPool + 9216);
  float* sU  = (float*)sPool;
  float* sK  = (float*)(sPool + 5120);

  const int b = blockIdx.x, tid = threadIdx.x;
  const int w = tid >> 6, l = tid & 63;

#pragma unroll
  for (int q = 0; q < 4; ++q) {
    const int idx = q*1024 + tid*4;
    const int row = idx>>6, col = idx&63;
    float4 v = *(const float4*)&Fg[idx];
    s16x4 h4, l4;
    splitbf4(v, h4, l4);
    *(s16x4*)&sFh[row*SBF+col] = h4;
    *(s16x4*)&sFl[row*SBF+col] = l4;
  }
  if (tid < 64) {
    sQ[tid]  = softplus_f(logQ[tid]);
    sQ0[tid] = softplus_f(logQ0[tid]);
    smf[tid] = m0g[tid];
  }
  __syncthreads();

  for (int t = 0; t < T_; ++t) {
    const size_t bt = (size_t)b*T_ + t;
    if (t == 0) {
      for (int i = tid; i < 4096; i += 256) {
        const int r = i>>6, c = i&63;
        sB[r*STF+c] = (r==c) ? sQ0[r] : 0.f;
      }
      const float4 kreg = ((const float4*)(Kxg + bt*1024))[tid];
      *(float4*)&sK[(tid>>2)*SU + (tid&3)*4] = kreg;
      if (tid < 64) { smp[tid] = smf[tid]; skv[tid] = kyg[bt*64 + tid]; mp_g[bt*64+tid] = smp[tid]; }
      __syncthreads();
    } else {
#pragma unroll
      for (int q = 0; q < 4; ++q) {
        const int idx = q*1024 + tid*4;
        const int row = idx>>6, col = idx&63;
        float4 v = *(const float4*)&sB[row*STF+col];
        s16x4 h4, l4;
        splitbf4(v, h4, l4);
        *(s16x4*)&sXh[row*SBF+col] = h4;
        *(s16x4*)&sXl[row*SBF+col] = l4;
      }
      __syncthreads();
      const float4 kreg = ((const float4*)(Kxg + bt*1024))[tid];
      float kvreg = 0.f;
      if (tid < 64) kvreg = kyg[bt*64 + tid];
      f32x4 acc[4];
#pragma unroll
      for (int ct = 0; ct < 4; ++ct) acc[ct] = (f32x4){0.f,0.f,0.f,0.f};
      mfma_mm64<SBF>(sFh, sFl, sXh, sXl, w, l, acc);
      {
        const int i = tid & 63, jb = tid >> 6;
        float s = 0.f;
#pragma unroll
        for (int hq = 0; hq < 2; ++hq) {
          bf16x8 fh = *(const bf16x8*)&sFh[i*SBF + jb*16 + hq*8];
          bf16x8 fl = *(const bf16x8*)&sFl[i*SBF + jb*16 + hq*8];
#pragma unroll
          for (int j = 0; j < 8; ++j)
            s += (bf2f(fh[j]) + bf2f(fl[j])) * smf[jb*16 + hq*8 + j];
        }
        sRed[tid] = s;
      }
      __syncthreads();
      {
        const int lr = l & 15, lg = l >> 4;
#pragma unroll
        for (int ct = 0; ct < 4; ++ct)
#pragma unroll
          for (int r = 0; r < 4; ++r) {
            short hh, ll;
            splitbf(acc[ct][r], hh, ll);
            const int row = w*16 + lg*4 + r, col = ct*16 + lr;
            sXh[row*SBF+col] = hh; sXl[row*SBF+col] = ll;
          }
      }
      if (tid < 64) {
        const float mpv = sRed[tid] + sRed[tid+64] + sRed[tid+128] + sRed[tid+192];
        smp[tid] = mpv; mp_g[bt*64+tid] = mpv;
      }
      __syncthreads();
#pragma unroll
      for (int ct = 0; ct < 4; ++ct) acc[ct] = (f32x4){0.f,0.f,0.f,0.f};
      mfma_mm64<SBF>(sXh, sXl, sFh, sFl, w, l, acc);
      __syncthreads();
      {
        const int lr = l & 15, lg = l >> 4;
#pragma unroll
        for (int ct = 0; ct < 4; ++ct)
#pragma unroll
          for (int r = 0; r < 4; ++r) {
            const int row = w*16 + lg*4 + r, col = ct*16 + lr;
            sB[row*STF+col] = acc[ct][r] + ((row==col) ? sQ[row] : 0.f);
          }
      }
      *(float4*)&sK[(tid>>2)*SU + (tid&3)*4] = kreg;
      if (tid < 64) skv[tid] = kvreg;
      __syncthreads();
    }
    {
      const int i = tid & 63, rq = tid >> 6;
      float4 u = {0.f,0.f,0.f,0.f};
      for (int jb = 0; jb < 16; ++jb) {
        const float4 p4 = *(const float4*)&sB[i*STF + jb*4];
#pragma unroll
        for (int dj = 0; dj < 4; ++dj) {
          const float4 k4 = *(const float4*)&sK[(jb*4+dj)*SU + rq*4];
          const float pv = (dj==0) ? p4.x : (dj==1) ? p4.y : (dj==2) ? p4.z : p4.w;
          u.x += pv*k4.x; u.y += pv*k4.y; u.z += pv*k4.z; u.w += pv*k4.w;
        }
      }
      *(float4*)&sU[i*SU + rq*4] = u;
    }
    __syncthreads();
    {
      const int ib = tid >> 6, r1 = (tid >> 2) & 15, r2b = tid & 3;
      float4 part = {0.f,0.f,0.f,0.f};
      for (int ii = 0; ii < 16; ++ii) {
        const int i = ib*16 + ii;
        const float kv = sK[i*SU + r1];
        const float4 u4 = *(const float4*)&sU[i*SU + r2b*4];
        part.x += kv*u4.x; part.y += kv*u4.y; part.z += kv*u4.z; part.w += kv*u4.w;
      }
      sRed4[tid] = (f32x4){part.x, part.y, part.z, part.w};
    }
    __syncthreads();
    if (tid < 64) {
      const int r1 = tid >> 2, r2b = tid & 3;
      f32x4 s4 = sRed4[tid];
      s4 += sRed4[tid+64]; s4 += sRed4[tid+128]; s4 += sRed4[tid+192];
#pragma unroll
      for (int dj = 0; dj < 4; ++dj)
        sS[r1*17 + r2b*4 + dj] = s4[dj] + ((r1 == r2b*4+dj) ? 1.f : 0.f);
    }
    __syncthreads();
    if (tid < 16) {
      const int ln = tid;
      float s[16];
#pragma unroll
      for (int j = 0; j < 16; ++j) s[j] = sS[ln*17+j];
      float pd = 1.f;
#pragma unroll
      for (int k = 0; k < 16; ++k) {
        const float dk = fmaxf(__shfl(s[k], k, 64), 1e-30f);
        const float d = sqrtf(dk);
        const float rd = 1.f/d;
        pd *= dk;
        const float lik = s[k]*rd;
        if (ln == k) sSd[k] = rd;
#pragma unroll
        for (int j = 0; j < 16; ++j) {
          const float ljk = __shfl(lik, j, 64);
          if (j > k && j <= ln) s[j] -= lik*ljk;
        }
        if (ln > k) s[k] = lik;
        else if (ln == k) s[k] = d;
      }
#pragma unroll
      for (int j = 0; j < 16; ++j) sS[ln*17+j] = s[j];
      if (ln == 0) sldv = logf(pd);
    } else if (tid >= 64 && tid < 80) {
      const int r = tid - 64;
      float a = 0.f;
      for (int i = 0; i < 64; ++i) a += sK[i*SU+r] * smp[i];
      sv[r] = a;
    }
    __syncthreads();
    if (tid < 64) {
      float x[16];
#pragma unroll
      for (int q = 0; q < 4; ++q) {
        const float4 u4 = *(const float4*)&sU[tid*SU + q*4];
        x[q*4+0]=u4.x; x[q*4+1]=u4.y; x[q*4+2]=u4.z; x[q*4+3]=u4.w;
      }
      fwd16(x, sS, sSd);
#pragma unroll
      for (int q = 0; q < 4; ++q) {
        float4 u4 = {x[q*4+0], x[q*4+1], x[q*4+2], x[q*4+3]};
        *(float4*)&sU[tid*SU + q*4] = u4;
      }
    } else if (tid == 64) {
      float x[16];
#pragma unroll
      for (int r = 0; r < 16; ++r) x[r] = sv[r];
      fwd16(x, sS, sSd);
#pragma unroll
      for (int r = 0; r < 16; ++r) sw[r] = x[r];
    }
    __syncthreads();
    {
      const int rg = tid >> 4, cg = tid & 15;
      float acc2[4][4] = {{0.f}};
#pragma unroll
      for (int rb = 0; rb < 4; ++rb) {
        float4 a4[4], b4[4];
#pragma unroll
        for (int i = 0; i < 4; ++i) a4[i] = *(const float4*)&sU[(rg*4+i)*SU + rb*4];
#pragma unroll
        for (int jj = 0; jj < 4; ++jj) b4[jj] = *(const float4*)&sU[(cg+16*jj)*SU + rb*4];
#pragma unroll
        for (int i = 0; i < 4; ++i)
#pragma unroll
          for (int jj = 0; jj < 4; ++jj)
            acc2[i][jj] += a4[i].x*b4[jj].x + a4[i].y*b4[jj].y
                         + a4[i].z*b4[jj].z + a4[i].w*b4[jj].w;
      }
#pragma unroll
      for (int i = 0; i < 4; ++i)
#pragma unroll
        for (int jj = 0; jj < 4; ++jj) {
          const int r = rg*4+i, c = cg+16*jj;
          sB[r*STF+c] -= acc2[i][jj];
        }
    }
    __syncthreads();
    {
      const int i = tid & 63, jb = tid >> 6;
      float s = 0.f;
#pragma unroll
      for (int q = 0; q < 4; ++q) {
        const float4 p4 = *(const float4*)&sB[i*STF + jb*16 + q*4];
        s += p4.x*skv[jb*16+q*4+0] + p4.y*skv[jb*16+q*4+1]
           + p4.z*skv[jb*16+q*4+2] + p4.w*skv[jb*16+q*4+3];
      }
      sRed[tid] = s;
    }
    for (int i2 = tid; i2 < 4096; i2 += 256)
      Pf_g[bt*4096+i2] = sB[(i2>>6)*STF+(i2&63)];
    __syncthreads();
    if (tid < 64) {
      float a = smp[tid];
#pragma unroll
      for (int q = 0; q < 4; ++q) {
        const float4 u4 = *(const float4*)&sU[tid*SU + q*4];
        a -= u4.x*sw[q*4+0] + u4.y*sw[q*4+1] + u4.z*sw[q*4+2] + u4.w*sw[q*4+3];
      }
      a += sRed[tid] + sRed[tid+64] + sRed[tid+128] + sRed[tid+192];
      smf[tid] = a;
      mf_g[bt*64+tid] = a;
      if (t == T_-1) mfT_g[b*64+tid] = a;
    }
    __syncthreads();
    if (tid < 16) {
      float a = 0.f;
      for (int i = 0; i < 64; ++i) a += sK[i*SU+tid]*smf[i];
      float aa = a*a;
      aa += __shfl_xor(aa, 1, 64);
      aa += __shfl_xor(aa, 2, 64);
      aa += __shfl_xor(aa, 4, 64);
      aa += __shfl_xor(aa, 8, 64);
      if (tid == 0) {
        float dp = aa - sldv;
        if (t == 0) {
          float d1 = 0.f, d2 = 0.f;
          for (int i = 0; i < 64; ++i) {
            d1 += smf[i]*smf[i]/sQ0[i];
            d2 += smp[i]*smp[i]/sQ0[i];
          }
          dp = 0.5f*(d1 - d2 + dp);
        }
        dpart_g[bt] = dp;
      }
    }
    __syncthreads();
  }
}

// ---------------- K3: gains + c,d + P_p-dependent KL scalars ----------------
__global__ __launch_bounds__(256) void gains_kernel(
    const float* __restrict__ Fg, const float* __restrict__ logQ,
    const float* __restrict__ mf_g, const float* __restrict__ mp_g,
    float* __restrict__ PfG_g, float* __restrict__ Cpk,
    float* __restrict__ d_g, float* __restrict__ dpart_g)
{
  const int blk = blockIdx.x;
  const int b = blk / (T_-1);
  const int n = 1 + (blk % (T_-1));
  const size_t btn = (size_t)b*T_ + n;
  const size_t btm = btn - 1;
  const int tid = threadIdx.x;
  const int rg = tid >> 4, cg = tid & 15;
  __shared__ float sA[64*ST];
  __shared__ float sM[64*STM];
  __shared__ float sPp[64*ST];
  __shared__ float sDi[64], sQd[64];
  __shared__ float smf1[64], smp[64];
  __shared__ float sd1d2[2];

  for (int i = tid; i < 4096; i += 256) sA[(i>>6)*ST + (i&63)] = PfG_g[btm*4096+i];
  if (tid < 64) {
    sM[tid*STM+64] = mf_g[btn*64+tid];
    sM[tid*STM+65] = mp_g[btn*64+tid];
    smf1[tid] = mf_g[btm*64+tid];
    smp[tid]  = mp_g[btn*64+tid];
    sQd[tid]  = softplus_f(logQ[tid]);
  }
  __syncthreads();
  {
    float acc[4][4] = {{0.f}};
#pragma unroll 4
    for (int k = 0; k < 64; ++k) {
      float a[4], bb[4];
#pragma unroll
      for (int i = 0; i < 4; ++i) a[i] = Fg[(rg*4+i)*64 + k];
#pragma unroll
      for (int j = 0; j < 4; ++j) bb[j] = sA[k*ST + cg*4+j];
#pragma unroll
      for (int i = 0; i < 4; ++i)
#pragma unroll
        for (int j = 0; j < 4; ++j) acc[i][j] += a[i]*bb[j];
    }
#pragma unroll
    for (int i = 0; i < 4; ++i)
#pragma unroll
      for (int j = 0; j < 4; ++j) sM[(rg*4+i)*STM + cg*4+j] = acc[i][j];
  }
  __syncthreads();
  {
    float acc[4][4] = {{0.f}};
#pragma unroll 4
    for (int k = 0; k < 64; ++k) {
      float a[4], bb[4];
#pragma unroll
      for (int i = 0; i < 4; ++i) a[i] = sM[(rg*4+i)*STM + k];
#pragma unroll
      for (int j = 0; j < 4; ++j) bb[j] = Fg[(cg*4+j)*64 + k];
#pragma unroll
      for (int i = 0; i < 4; ++i)
#pragma unroll
        for (int j = 0; j < 4; ++j) acc[i][j] += a[i]*bb[j];
    }
#pragma unroll
    for (int i = 0; i < 4; ++i)
#pragma unroll
      for (int j = 0; j < 4; ++j) {
        const int r = rg*4+i, c = cg*4+j;
        sPp[r*ST+c] = acc[i][j] + ((r==c) ? sQd[r] : 0.f);
      }
  }
  __syncthreads();
  chol64_blk<ST>(sPp, sDi, (float*)nullptr, tid);
#pragma unroll
  for (int jb = 0; jb < 4; ++jb) {
    const int o = jb*16;
    if (tid < 66) {
      const int c = tid;
      float x[16];
#pragma unroll
      for (int q = 0; q < 16; ++q) x[q] = sM[(o+q)*STM + c];
#pragma unroll
      for (int j = 0; j < 16; ++j) {
        x[j] *= sDi[o+j];
#pragma unroll
        for (int i = j+1; i < 16; ++i) x[i] -= sPp[(o+i)*ST + o+j] * x[j];
      }
#pragma unroll
      for (int q = 0; q < 16; ++q) sM[(o+q)*STM + c] = x[q];
    }
    __syncthreads();
    const int nr = 48 - o;
    if (nr > 0) {
      for (int idx = tid; idx < nr*66; idx += 256) {
        const int r = o + 16 + idx/66, c = idx%66;
        float acc = sM[r*STM + c];
#pragma unroll
        for (int k = 0; k < 16; ++k) acc -= sPp[r*ST + o+k] * sM[(o+k)*STM + c];
        sM[r*STM + c] = acc;
      }
      __syncthreads();
    }
  }
  if (tid == 64 || tid == 65) {
    float a = 0.f;
    for (int i = 0; i < 64; ++i) { const float v = sM[i*STM+tid]; a += v*v; }
    sd1d2[tid-64] = a;
  }
  {
    float acc[4][4] = {{0.f}};
#pragma unroll 2
    for (int k = 0; k < 64; ++k) {
      float a[4], bb[4];
#pragma unroll
      for (int i = 0; i < 4; ++i) a[i] = sM[k*STM + rg*4+i];
#pragma unroll
      for (int j = 0; j < 4; ++j) bb[j] = sM[k*STM + cg*4+j];
#pragma unroll
      for (int i = 0; i < 4; ++i)
#pragma unroll
        for (int j = 0; j < 4; ++j) acc[i][j] += a[i]*bb[j];
    }
#pragma unroll
    for (int i = 0; i < 4; ++i)
#pragma unroll
      for (int j = 0; j < 4; ++j)
        sA[(rg*4+i)*ST + (cg*4+j)] -= acc[i][j];
  }
  __syncthreads();
  for (int idx = tid; idx < 4096; idx += 256) {
    const int i = idx>>6, j = idx&63;
    if (i >= j) Cpk[btn*PKN + PIDX(i,j)] = sA[i*ST+j];
  }
#pragma unroll
  for (int jb = 3; jb >= 0; --jb) {
    const int o = jb*16;
    if (tid < 64) {
      const int c = tid;
      float x[16];
#pragma unroll
      for (int q = 0; q < 16; ++q) x[q] = sM[(o+q)*STM + c];
#pragma unroll
      for (int j = 15; j >= 0; --j) {
        x[j] *= sDi[o+j];
#pragma unroll
        for (int i = 0; i < j; ++i) x[i] -= sPp[(o+j)*ST + o+i] * x[j];
      }
#pragma unroll
      for (int q = 0; q < 16; ++q) sM[(o+q)*STM + c] = x[q];
    }
    __syncthreads();
    if (o > 0) {
      for (int idx = tid; idx < o*64; idx += 256) {
        const int r = idx/64, c = idx%64;
        float acc = sM[r*STM + c];
#pragma unroll
        for (int k = 0; k < 16; ++k) acc -= sPp[(o+k)*ST + r] * sM[(o+k)*STM + c];
        sM[r*STM + c] = acc;
      }
      __syncthreads();
    }
  }
  for (int i = tid; i < 4096; i += 256)
    PfG_g[btm*4096 + i] = sM[(i&63)*STM + (i>>6)];
  if (tid < 64) {
    float a = smf1[tid];
    for (int j = 0; j < 64; ++j) a -= sM[j*STM+tid]*smp[j];
    d_g[btm*64 + tid] = a;
  }
  if (tid == 0)
    dpart_g[btn] = 0.5f*(sd1d2[0] - sd1d2[1] + dpart_g[btn]);
}

// ---------------- K4a: smoother segment compose ----------------
__global__ __launch_bounds__(256) void compose_kernel(
    const float* __restrict__ G_g, const float* __restrict__ Cpk,
    const float* __restrict__ d_g,
    float* __restrict__ Gseg, float* __restrict__ cseg, float* __restrict__ dseg)
{
  extern __shared__ char cm[];
  short* GMh = (short*)cm;
  short* GMl = GMh + 4096;
  short* cMh = GMl + 4096;
  short* cMl = cMh + 4096;
  short* Gth = cMl + 4096;
  short* Gtl = Gth + 4096;
  short* Xh  = Gtl + 4096;
  short* Xl  = Xh + 4096;
  float* cbuf = (float*)(cm + 65536);
  float* sRed = (float*)(cm + 65536 + 8320);
  float* sdv  = (float*)(cm + 65536 + 8320 + 1024);

  const int blk = blockIdx.x, tid = threadIdx.x;
  const int b = blk >> 3, s = blk & (NSEG-1);
  const int w = tid >> 6, l = tid & 63;
  const int lr = l & 15, lg = l >> 4;
  const int t0 = s*SEG;
  const int tend = (s == NSEG-1) ? (T_-2) : (t0 + SEG - 1);

  {
    const size_t bt = (size_t)b*T_ + tend;
#pragma unroll
    for (int q = 0; q < 4; ++q) {
      const int idx = q*1024 + tid*4;
      const int row = idx>>6, col = idx&63;
      float4 v = *(const float4*)&G_g[bt*4096 + idx];
      s16x4 h4, l4;
      splitbf4(v, h4, l4);
#pragma unroll
      for (int e = 0; e < 4; ++e) {
        GMh[(col+e)*64 + row] = h4[e];
        GMl[(col+e)*64 + row] = l4[e];
      }
    }
    for (int idx = tid; idx < 4096; idx += 256) {
      const int i = idx>>6, j = idx&63;
      const int pidx = (i >= j) ? PIDX(i,j) : PIDX(j,i);
      const float v = Cpk[(bt+1)*PKN + pidx];
      short h, lo; splitbf(v, h, lo);
      cMh[i*64+j] = h; cMl[i*64+j] = lo;
    }
    if (tid < 64) sdv[tid] = d_g[bt*64+tid];
  }
  __syncthreads();

  for (int t = tend-1; t >= t0; --t) {
    const size_t bt = (size_t)b*T_ + t;
#pragma unroll
    for (int q = 0; q < 4; ++q) {
      const int idx = q*1024 + tid*4;
      const int row = idx>>6, col = idx&63;
      float4 v = *(const float4*)&G_g[bt*4096 + idx];
      s16x4 h4, l4;
      splitbf4(v, h4, l4);
      *(s16x4*)&Gth[row*64+col] = h4;
      *(s16x4*)&Gtl[row*64+col] = l4;
    }
    for (int i2 = tid; i2 < PKN; i2 += 256) cbuf[i2] = Cpk[(bt+1)*PKN + i2];
    float dreg = 0.f;
    if (tid < 64) dreg = d_g[bt*64+tid];
    __syncthreads();
    f32x4 a1[4], a2[4];
#pragma unroll
    for (int ct = 0; ct < 4; ++ct) { a1[ct] = (f32x4){0,0,0,0}; a2[ct] = (f32x4){0,0,0,0}; }
    mfma_mm64<64>(Gth, Gtl, GMh, GMl, w, l, a1);
    mfma_mm64<64>(Gth, Gtl, cMh, cMl, w, l, a2);
    {
      const int i = tid & 63, jb = tid >> 6;
      float ss = 0.f;
      for (int j = 0; j < 16; ++j) {
        const int jj = jb*16 + j;
        ss += (bf2f(Gth[i*64+jj]) + bf2f(Gtl[i*64+jj])) * sdv[jj];
      }
      sRed[tid] = ss;
    }
    __syncthreads();
#pragma unroll
    for (int ct = 0; ct < 4; ++ct)
#pragma unroll
      for (int r = 0; r < 4; ++r) {
        const int row = w*16 + lg*4 + r, col = ct*16 + lr;
        short h, lo;
        splitbf(a1[ct][r], h, lo);
        GMh[col*64+row] = h; GMl[col*64+row] = lo;
        splitbf(a2[ct][r], h, lo);
        Xh[row*64+col] = h; Xl[row*64+col] = lo;
      }
    if (tid < 64)
      sdv[tid] = dreg + sRed[tid] + sRed[tid+64] + sRed[tid+128] + sRed[tid+192];
    __syncthreads();
    f32x4 a3[4];
#pragma unroll
    for (int ct = 0; ct < 4; ++ct) a3[ct] = (f32x4){0,0,0,0};
    mfma_mm64<64>(Xh, Xl, Gth, Gtl, w, l, a3);
#pragma unroll
    for (int ct = 0; ct < 4; ++ct)
#pragma unroll
      for (int r = 0; r < 4; ++r) {
        const int row = w*16 + lg*4 + r, col = ct*16 + lr;
        const int pidx = (row >= col) ? PIDX(row,col) : PIDX(col,row);
        const float cv = cbuf[pidx] + a3[ct][r];
        short h, lo; splitbf(cv, h, lo);
        cMh[row*64+col] = h; cMl[row*64+col] = lo;
      }
    __syncthreads();
  }
  for (int idx = tid; idx < 4096; idx += 256) {
    const int i = idx>>6, j = idx&63;
    Gseg[(size_t)blk*4096 + idx] = bf2f(GMh[j*64+i]) + bf2f(GMl[j*64+i]);
    if (i >= j)
      cseg[(size_t)blk*PKN + PIDX(i,j)] = bf2f(cMh[i*64+j]) + bf2f(cMl[i*64+j]);
  }
  if (tid < 64) dseg[(size_t)blk*64 + tid] = sdv[tid];
}

// ---------------- K4b: smoother boundary scan ----------------
__global__ __launch_bounds__(256) void boundary_kernel(
    const float* __restrict__ PfG_g, const float* __restrict__ mfT_g,
    const float* __restrict__ Gseg, const float* __restrict__ cseg,
    const float* __restrict__ dseg,
    float* __restrict__ InP, float* __restrict__ Inm)
{
  __shared__ short Gsh[4096], Gsl[4096], vh[4096], vl[4096], Wh[4096], Wl[4096];
  __shared__ float cb[PKN];
  __shared__ float svm[64];
  __shared__ float sRed[256];
  const int b = blockIdx.x, tid = threadIdx.x;
  const int w = tid >> 6, l = tid & 63;
  const int lr = l & 15, lg = l >> 4;

  {
    const size_t bl = ((size_t)b*T_ + (T_-1))*4096;
    for (int idx = tid; idx < 4096; idx += 256) {
      const int i = idx>>6, j = idx&63;
      const float v = PfG_g[bl + idx];
      short h, lo; splitbf(v, h, lo);
      vh[i*64+j] = h; vl[i*64+j] = lo;
      if (i >= j) InP[((size_t)b*NSEG + (NSEG-1))*PKN + PIDX(i,j)] = v;
    }
    if (tid < 64) {
      const float m = mfT_g[b*64+tid];
      svm[tid] = m;
      Inm[((size_t)b*NSEG + (NSEG-1))*64 + tid] = m;
    }
  }
  __syncthreads();
  for (int s = NSEG-1; s >= 1; --s) {
    const size_t seg = (size_t)b*NSEG + s;
    float dreg = 0.f;
#pragma unroll
    for (int q = 0; q < 4; ++q) {
      const int idx = q*1024 + tid*4;
      const int row = idx>>6, col = idx&63;
      float4 v = *(const float4*)&Gseg[seg*4096 + idx];
      s16x4 h4, l4;
      splitbf4(v, h4, l4);
      *(s16x4*)&Gsh[row*64+col] = h4;
      *(s16x4*)&Gsl[row*64+col] = l4;
    }
    for (int i2 = tid; i2 < PKN; i2 += 256) cb[i2] = cseg[seg*PKN + i2];
    if (tid < 64) dreg = dseg[seg*64+tid];
    __syncthreads();
    {
      const int i = tid & 63, jb = tid >> 6;
      float ss = 0.f;
      for (int j = 0; j < 16; ++j) {
        const int jj = jb*16 + j;
        ss += (bf2f(Gsh[i*64+jj]) + bf2f(Gsl[i*64+jj])) * svm[jj];
      }
      sRed[tid] = ss;
    }
    f32x4 a1[4];
#pragma unroll
    for (int ct = 0; ct < 4; ++ct) a1[ct] = (f32x4){0,0,0,0};
    mfma_mm64<64>(Gsh, Gsl, vh, vl, w, l, a1);
    __syncthreads();
#pragma unroll
    for (int ct = 0; ct < 4; ++ct)
#pragma unroll
      for (int r = 0; r < 4; ++r) {
        const int row = w*16 + lg*4 + r, col = ct*16 + lr;
        short h, lo; splitbf(a1[ct][r], h, lo);
        Wh[row*64+col] = h; Wl[row*64+col] = lo;
      }
    if (tid < 64)
      svm[tid] = dreg + sRed[tid] + sRed[tid+64] + sRed[tid+128] + sRed[tid+192];
    __syncthreads();
    f32x4 a2[4];
#pragma unroll
    for (int ct = 0; ct < 4; ++ct) a2[ct] = (f32x4){0,0,0,0};
    mfma_mm64<64>(Wh, Wl, Gsh, Gsl, w, l, a2);
#pragma unroll
    for (int ct = 0; ct < 4; ++ct)
#pragma unroll
      for (int r = 0; r < 4; ++r) {
        const int row = w*16 + lg*4 + r, col = ct*16 + lr;
        const int pidx = (row >= col) ? PIDX(row,col) : PIDX(col,row);
        const float vv = cb[pidx] + a2[ct][r];
        short h, lo; splitbf(vv, h, lo);
        vh[row*64+col] = h; vl[row*64+col] = lo;
        if (row >= col) InP[((size_t)b*NSEG + s - 1)*PKN + PIDX(row,col)] = vv;
      }
    if (tid < 64) Inm[((size_t)b*NSEG + s - 1)*64 + tid] = svm[tid];
    __syncthreads();
  }
}

// ---------------- K4c: smoother segment expand ----------------
__global__ __launch_bounds__(256) void expand_kernel(
    const float* __restrict__ GPs_g, float* __restrict__ Cpk,
    const float* __restrict__ d_g, const float* __restrict__ InP,
    const float* __restrict__ Inm, float* __restrict__ ms_g)
{
  __shared__ float sPs[64*STF];
  __shared__ short sGh[64*SBF], sGl[64*SBF];
  __shared__ short sPh[64*SBF], sPl[64*SBF];
  __shared__ float sms[64];
  __shared__ float sRed[256];
  const int blk = blockIdx.x, tid = threadIdx.x;
  const int b = blk >> 3, s = blk & (NSEG-1);
  const int w = tid >> 6, l = tid & 63;
  const int t0 = s*SEG;
  const int tend = (s == NSEG-1) ? (T_-2) : (t0 + SEG - 1);

  int ci[9], cj[9];
#pragma unroll
  for (int nn = 0; nn < 9; ++nn) {
    const int p = nn*256 + tid;
    int i = (int)((sqrtf(8.f*(float)p + 1.f) - 1.f)*0.5f);
    while ((i+1)*(i+2)/2 <= p) ++i;
    while (i*(i+1)/2 > p) --i;
    ci[nn] = i; cj[nn] = p - i*(i+1)/2;
  }

  for (int idx = tid; idx < 4096; idx += 256) {
    const int i = idx>>6, j = idx&63;
    const int pidx = (i >= j) ? PIDX(i,j) : PIDX(j,i);
    sPs[i*STF+j] = InP[((size_t)b*NSEG + s)*PKN + pidx];
  }
  if (tid < 64) sms[tid] = Inm[((size_t)b*NSEG + s)*64 + tid];
  __syncthreads();
  if (s == NSEG-1) {
#pragma unroll
    for (int nn = 0; nn < 9; ++nn) {
      const int p = nn*256 + tid;
      if (p < PKN) Cpk[(size_t)b*T_*PKN + p] = sPs[ci[nn]*STF + cj[nn]];
    }
    if (tid < 64) ms_g[((size_t)b*T_ + (T_-1))*64 + tid] = sms[tid];
  }
  float4 gf4[4];
  {
    const float4* Gp = (const float4*)(GPs_g + ((size_t)b*T_ + tend)*4096);
#pragma unroll
    for (int q = 0; q < 4; ++q) gf4[q] = Gp[q*256 + tid];
  }

  for (int t = tend; t >= t0; --t) {
    const size_t bt = (size_t)b*T_ + t;
    const size_t cslot = (bt+1)*PKN;
#pragma unroll
    for (int q = 0; q < 4; ++q) {
      const int row = q*16 + (tid>>4), col = (tid&15)*4;
      s16x4 h4, l4;
      splitbf4(gf4[q], h4, l4);
      *(s16x4*)&sGh[row*SBF+col] = h4;
      *(s16x4*)&sGl[row*SBF+col] = l4;
    }
#pragma unroll
    for (int q = 0; q < 4; ++q) {
      const int idx = q*1024 + tid*4;
      const int row = idx>>6, col = idx&63;
      float4 v = *(const float4*)&sPs[row*STF+col];
      s16x4 h4, l4;
      splitbf4(v, h4, l4);
      *(s16x4*)&sPh[row*SBF+col] = h4;
      *(s16x4*)&sPl[row*SBF+col] = l4;
    }
    float cr[9];
#pragma unroll
    for (int nn = 0; nn < 9; ++nn) {
      const int p = nn*256 + tid;
      cr[nn] = (p < PKN) ? Cpk[cslot + p] : 0.f;
    }
    float dreg = 0.f;
    if (tid < 64) dreg = d_g[bt*64+tid];
    {
      const size_t tprev = (t > t0) ? (bt-1) : bt;
      const float4* Gp = (const float4*)(GPs_g + tprev*4096);
#pragma unroll
      for (int q = 0; q < 4; ++q) gf4[q] = Gp[q*256 + tid];
    }
    __syncthreads();
    f32x4 acc[4];
#pragma unroll
    for (int ct = 0; ct < 4; ++ct) acc[ct] = (f32x4){0.f,0.f,0.f,0.f};
    mfma_mm64<SBF>(sGh, sGl, sPh, sPl, w, l, acc);
    {
      const int i = tid & 63, jb = tid >> 6;
      float ss = 0.f;
#pragma unroll
      for (int hq = 0; hq < 2; ++hq) {
        bf16x8 gh = *(const bf16x8*)&sGh[i*SBF + jb*16 + hq*8];
        bf16x8 gl = *(const bf16x8*)&sGl[i*SBF + jb*16 + hq*8];
#pragma unroll
        for (int j = 0; j < 8; ++j)
          ss += (bf2f(gh[j]) + bf2f(gl[j])) * sms[jb*16 + hq*8 + j];
      }
      sRed[tid] = ss;
    }
    __syncthreads();
    {
      const int lr = l & 15, lg = l >> 4;
#pragma unroll
      for (int ct = 0; ct < 4; ++ct)
#pragma unroll
        for (int r = 0; r < 4; ++r) {
          short hh, ll;
          splitbf(acc[ct][r], hh, ll);
          const int row = w*16 + lg*4 + r, col = ct*16 + lr;
          sPh[row*SBF+col] = hh; sPl[row*SBF+col] = ll;
        }
    }
    __syncthreads();
    float mval = 0.f;
    if (tid < 64) {
      mval = dreg + sRed[tid] + sRed[tid+64] + sRed[tid+128] + sRed[tid+192];
      sms[tid] = mval; ms_g[bt*64+tid] = mval;
    }
#pragma unroll
    for (int ct = 0; ct < 4; ++ct) acc[ct] = (f32x4){0.f,0.f,0.f,0.f};
    mfma_mm64<SBF>(sPh, sPl, sGh, sGl, w, l, acc);
    __syncthreads();
    {
      const int lr = l & 15, lg = l >> 4;
#pragma unroll
      for (int ct = 0; ct < 4; ++ct)
#pragma unroll
        for (int r = 0; r < 4; ++r) {
          const int row = w*16 + lg*4 + r, col = ct*16 + lr;
          sPs[row*STF+col] = acc[ct][r];
        }
    }
    __syncthreads();
#pragma unroll
    for (int nn = 0; nn < 9; ++nn) {
      const int p = nn*256 + tid;
      if (p < PKN) {
        const int i = ci[nn], j = cj[nn];
        float val;
        if (i == j) val = cr[nn] + sPs[i*STF+i];
        else        val = cr[nn] + 0.5f*(sPs[i*STF+j] + sPs[j*STF+i]);
        sPs[i*STF+j] = val;
        if (i != j) sPs[j*STF+i] = val;
        Cpk[cslot + p] = val;
      }
    }
    __syncthreads();
  }
}

// ---------------- K5: KL finalize + sampling + ELL ----------------
__global__ __launch_bounds__(256) void klell_kernel(
    const float* __restrict__ yg, const float* __restrict__ epsg,
    const float* __restrict__ kyg, const float* __restrict__ Kxg,
    const float* __restrict__ Cg, const float* __restrict__ brg,
    const float* __restrict__ Cpk, const float* __restrict__ ms_g,
    const float* __restrict__ dpart_g, float* __restrict__ val_g)
{
  const int bx = blockIdx.x;
  const int b = bx >> 8, t = bx & (T_-1);
  const size_t bt = (size_t)bx;
  const int tid = threadIdx.x;
  __shared__ float sPs[64*ST], sC[64*ST];
  __shared__ float sPA[64*17], sK[64*17];
  __shared__ float sZ[NS_*ST];
  __shared__ float sE[NS_*64];
  __shared__ float sy[256], sbr[256];
  __shared__ float skv[64], sms[64], sDi[64], sDg[64];
  __shared__ float sv[16];
  __shared__ float red[256];

  const size_t pslot = ((size_t)b*T_ + ((t+1) & (T_-1)))*PKN;
  for (int idx = tid; idx < 4096; idx += 256) {
    const int i = idx>>6, j = idx&63;
    const int pidx = (i >= j) ? PIDX(i,j) : PIDX(j,i);
    sPs[i*ST+j] = Cpk[pslot + pidx];
  }
  for (int i = tid; i < 1024; i += 256) sK[(i>>4)*17+(i&15)] = Kxg[bt*1024+i];
  if (tid < 64) { skv[tid] = kyg[bt*64+tid]; sms[tid] = ms_g[bt*64+tid]; }
  sy[tid]  = yg[bt*256+tid];
  sbr[tid] = brg[tid];
  for (int i = tid; i < NS_*64; i += 256) {
    const int s = i >> 6, j = i & 63;
    sE[i] = epsg[(((size_t)s*B_ + b)*T_ + t)*64 + j];
  }
  __syncthreads();
  {
    const int i = tid & 63, rq = tid >> 6;
    float u[4] = {0.f,0.f,0.f,0.f};
    for (int j = 0; j < 64; ++j) {
      const float p = sPs[i*ST+j];
#pragma unroll
      for (int r = 0; r < 4; ++r) u[r] += p * sK[j*17 + rq*4 + r];
    }
#pragma unroll
    for (int r = 0; r < 4; ++r) sPA[i*17 + rq*4 + r] = u[r];
  }
  __syncthreads();
  {
    const int i = tid & 63, rq = tid >> 6;
    float a = 0.f;
#pragma unroll
    for (int r = 0; r < 4; ++r) a += sK[i*17+rq*4+r]*sPA[i*17+rq*4+r];
    red[tid] = a;
  }
  if (tid < 16) {
    float a = 0.f;
    for (int i = 0; i < 64; ++i) a += sK[i*17+tid]*sms[i];
    sv[tid] = a;
  }
  __syncthreads();
  for (int s2 = 128; s2 > 0; s2 >>= 1) {
    if (tid < s2) red[tid] += red[tid+s2];
    __syncthreads();
  }
  float klv = 0.f;
  if (tid == 0) {
    const float tr = red[0];
    float ip1 = 0.f;
    for (int i = 0; i < 64; ++i) ip1 += skv[i]*sms[i];
    float s2s = 0.f;
#pragma unroll
    for (int r = 0; r < 16; ++r) s2s += sv[r]*sv[r];
    klv = (ip1 - 0.5f*s2s - 0.5f*tr) - dpart_g[bt];
  }
  if (tid < 64) sPs[tid*ST+tid] += 1e-5f;
  __syncthreads();
  chol64_blk<ST>(sPs, sDi, sDg, tid);
#pragma unroll
  for (int p = 0; p < 2; ++p) {
    const int s = (tid >> 6) + 4*p, ll = tid & 63;
    float a = sms[ll];
    for (int j = 0; j < ll; ++j) a += sPs[ll*ST+j]*sE[s*64+j];
    a += sDg[ll]*sE[s*64+ll];
    sZ[s*ST+ll] = a;
  }
  __syncthreads();
  float accel = 0.f;
  for (int nc = 0; nc < 4; ++nc) {
    for (int i = tid; i < 4096; i += 256) sC[(i>>6)*ST+(i&63)] = Cg[nc*4096+i];
    __syncthreads();
#pragma unroll
    for (int p = 0; p < 2; ++p) {
      const int idx = p*256 + tid;
      const int s = idx >> 6, rn = idx & 63;
      const int nn2 = nc*64 + rn;
      float lr = sbr[nn2];
      for (int ll = 0; ll < 64; ++ll) lr += sZ[s*ST+ll]*sC[rn*ST+ll];
      accel += sy[nn2]*lr - expf(lr);
    }
    __syncthreads();
  }
  red[tid] = accel;
  __syncthreads();
  for (int s2 = 128; s2 > 0; s2 >>= 1) {
    if (tid < s2) red[tid] += red[tid+s2];
    __syncthreads();
  }
  if (tid == 0) val_g[bt] = klv - red[0]*(1.0f/NS_);
}

// ---------------- K6: final reduction ----------------
__global__ __launch_bounds__(256) void reduce_kernel(const float* __restrict__ val,
                                                     float* __restrict__ out)
{
  __shared__ float red[256];
  float acc = 0.f;
  for (int i = threadIdx.x; i < B_*T_; i += 256) acc += val[i];
  red[threadIdx.x] = acc;
  __syncthreads();
  for (int s2 = 128; s2 > 0; s2 >>= 1) {
    if (threadIdx.x < s2) red[threadIdx.x] += red[threadIdx.x+s2];
    __syncthreads();
  }
  if (threadIdx.x == 0) out[0] = red[0] / (float)B_;
}

__global__ void diag_kernel(float* out, float v)
{
  if (threadIdx.x == 0) out[0] = v;
}

extern "C" void kernel_launch(void* const* d_in, const int* in_sizes, int n_in,
                              void* d_out, int out_size, void* d_ws, size_t ws_size,
                              hipStream_t stream)
{
  const float* y    = (const float*)d_in[0];
  const float* eps  = (const float*)d_in[1];
  const float* W1   = (const float*)d_in[2];
  const float* b1   = (const float*)d_in[3];
  const float* W2   = (const float*)d_in[4];
  const float* b2   = (const float*)d_in[5];
  const float* F    = (const float*)d_in[6];
  const float* logQ = (const float*)d_in[7];
  const float* logQ0= (const float*)d_in[8];
  const float* m0   = (const float*)d_in[9];
  const float* C    = (const float*)d_in[10];
  const float* br   = (const float*)d_in[11];
  (void)in_sizes; (void)n_in; (void)out_size;

  char* ws = (char*)d_ws;
  float* out = (float*)d_out;

  auto al = [](size_t x){ return (x + 255) & ~(size_t)255; };
  size_t o = 0;
  float* ky    = (float*)(ws + o); o = al(o + (size_t)B_*T_*64*4);
  float* mf    = (float*)(ws + o); o = al(o + (size_t)B_*T_*64*4);
  float* mp    = (float*)(ws + o); o = al(o + (size_t)B_*T_*64*4);
  float* msb   = (float*)(ws + o); o = al(o + (size_t)B_*T_*64*4);
  float* dv    = (float*)(ws + o); o = al(o + (size_t)B_*T_*64*4);
  float* dpart = (float*)(ws + o); o = al(o + (size_t)B_*T_*4);
  float* val   = (float*)(ws + o); o = al(o + (size_t)B_*T_*4);
  float* Kx    = (float*)(ws + o); o = al(o + (size_t)B_*T_*1024*4);
  float* A1    = (float*)(ws + o); o = al(o + (size_t)B_*T_*4096*4);   // Pf -> G
  float* Cpk   = (float*)(ws + o); o = al(o + (size_t)B_*T_*PKN*4);    // c -> Ps packed
  float* Gseg  = (float*)(ws + o); o = al(o + (size_t)B_*NSEG*4096*4);
  float* cseg  = (float*)(ws + o); o = al(o + (size_t)B_*NSEG*PKN*4);
  float* dseg  = (float*)(ws + o); o = al(o + (size_t)B_*NSEG*64*4);
  float* InP   = (float*)(ws + o); o = al(o + (size_t)B_*NSEG*PKN*4);
  float* Inm   = (float*)(ws + o); o = al(o + (size_t)B_*NSEG*64*4);
  float* mfT   = (float*)(ws + o); o = al(o + (size_t)B_*64*4);
  float* h     = A1;   // MLP hidden aliases A1; dead before filter writes

  if (ws_size < o) {
    diag_kernel<<<1, 64, 0, stream>>>(out, (float)((double)ws_size / 1048576.0));
    return;
  }

  dim3 blk(256);
  gemm_kernel<true,false><<<dim3(H_/64, (B_*T_)/64), blk, 0, stream>>>(
      y, W1, b1, h, (float*)nullptr, B_*T_, H_, N_);
  gemm_kernel<false,true><<<dim3((L_+L_*R_)/64, (B_*T_)/64), blk, 0, stream>>>(
      h, W2, b2, ky, Kx, B_*T_, L_+L_*R_, H_);
  filter_kernel<<<B_, blk, 0, stream>>>(ky, Kx, F, logQ, logQ0, m0,
                                        mf, mp, A1, dpart, mfT);
  gains_kernel<<<B_*(T_-1), blk, 0, stream>>>(F, logQ, mf, mp, A1, Cpk, dv, dpart);
  compose_kernel<<<B_*NSEG, blk, 65536 + 8320 + 1024 + 256 + 64, stream>>>(
      A1, Cpk, dv, Gseg, cseg, dseg);
  boundary_kernel<<<B_, blk, 0, stream>>>(A1, mfT, Gseg, cseg, dseg, InP, Inm);
  expand_kernel<<<B_*NSEG, blk, 0, stream>>>(A1, Cpk, dv, InP, Inm, msb);
  klell_kernel<<<B_*T_, blk, 0, stream>>>(y, eps, ky, Kx, C, br, Cpk, msb, dpart, val);
  reduce_kernel<<<1, blk, 0, stream>>>(val, (float*)d_out);
}